// Round 12
// baseline (596.026 us; speedup 1.0000x reference)
//
#include <hip/hip_runtime.h>
#include <cstdint>

#define N_PRED 1200
#define M_TGT  400
#define KDIM   25600   // 160*160
#define NCLS   81
#define MPAD   448     // padded target count (28 x 16)
#define KZN    25      // split-K factor
#define NBLK   38      // row blocks of 32 (1216 >= 1200)
#define STEPS  32      // K-steps (BK=32) per block
#define TSLICE 14336   // BYTES per BK=32 step: 4(kq) * 448 * 8 fp8

typedef __attribute__((ext_vector_type(8)))  short bf16x8;
typedef __attribute__((ext_vector_type(4)))  float f32x4;
typedef unsigned char uchar;

__device__ __forceinline__ ushort f2bf(float f) {
  union { float f; uint32_t u; } v; v.f = f;
  uint32_t u = v.u + 0x7fffu + ((v.u >> 16) & 1u);
  return (ushort)(u >> 16);
}

__device__ __forceinline__ float bf2f(ushort s) {
  union { uint32_t u; float f; } v; v.u = ((uint32_t)s) << 16;
  return v.f;
}

// pack 4 f32 -> 4 fp8 e4m3 (OCP, saturating) in one u32
__device__ __forceinline__ uint32_t pk_fp8(float a, float b, float c, float d) {
  uint32_t v = (uint32_t)__builtin_amdgcn_cvt_pk_fp8_f32(a, b, 0, false);
  v = (uint32_t)__builtin_amdgcn_cvt_pk_fp8_f32(c, d, (int)v, true);
  return v;
}

__device__ __forceinline__ void gll16(const void* g, void* l) {
  __builtin_amdgcn_global_load_lds(
      (const __attribute__((address_space(1))) void*)g,
      (__attribute__((address_space(3))) void*)l, 16, 0, 0);
}

// =====================================================================
// Resize tgt_masks [400,256,256] -> T fp8 fragment-major: [kt(800)][kq(4)][m(448)][8]
__global__ __launch_bounds__(256) void resize2(const float* __restrict__ tm,
                                               uchar* __restrict__ T,
                                               float* __restrict__ tsum) {
  __shared__ float rows[16][256];
  __shared__ float vbuf[8][256];

  int m = blockIdx.x, yt = blockIdx.y;  // yt 0..19
  int y0 = yt * 8;
  int t = threadIdx.x;

  int jbase = (int)ceilf((y0 + 0.5f) * 1.6f - 2.1f);

  const float* base = tm + (size_t)m * 65536;
  {
    int r = t >> 4;
    int c0 = (t & 15) * 16;
    int jr = min(max(jbase + r, 0), 255);
    const float4* src = reinterpret_cast<const float4*>(base + jr * 256 + c0);
#pragma unroll
    for (int i = 0; i < 4; ++i)
      *reinterpret_cast<float4*>(&rows[r][c0 + i * 4]) = src[i];
  }
  __syncthreads();

#pragma unroll
  for (int yy = 0; yy < 8; ++yy) {
    int y = y0 + yy;
    float s = (y + 0.5f) * 1.6f - 0.5f;
    int j0 = (int)ceilf(s - 1.6f);
    float w[4]; float wsum = 0.f;
#pragma unroll
    for (int a = 0; a < 4; ++a) {
      int j = j0 + a;
      float wv = fmaxf(0.f, 1.f - fabsf((float)j - s) * 0.625f);
      if (j < 0 || j > 255) wv = 0.f;
      w[a] = wv; wsum += wv;
    }
    float winv = __builtin_amdgcn_rcpf(wsum);
    float acc = 0.f;
    int rbase = j0 - jbase;
#pragma unroll
    for (int a = 0; a < 4; ++a) acc += w[a] * rows[rbase + a][t];
    vbuf[yy][t] = acc * winv;
  }
  __syncthreads();

  float bsum = 0.f;
  if (t < 160) {
    int yy = t / 20, ch = t - yy * 20;
    float o[8];
#pragma unroll
    for (int j = 0; j < 8; ++j) {
      int x = ch * 8 + j;
      float sx = (x + 0.5f) * 1.6f - 0.5f;
      int jx0 = (int)ceilf(sx - 1.6f);
      float wsum = 0.f, h = 0.f;
#pragma unroll
      for (int b = 0; b < 4; ++b) {
        int jj = jx0 + b;
        float wv = fmaxf(0.f, 1.f - fabsf((float)jj - sx) * 0.625f);
        if (jj < 0 || jj > 255) wv = 0.f;
        wsum += wv;
        h += wv * vbuf[yy][min(max(jj, 0), 255)];
      }
      h *= __builtin_amdgcn_rcpf(wsum);
      o[j] = h; bsum += h;
    }
    int p0 = (y0 + yy) * 160 + ch * 8;
    int kt = p0 >> 5, kq = (p0 >> 3) & 3;
    size_t a = ((size_t)(kt * 4 + kq) * MPAD + m) * 8;
    uint2 pk;
    pk.x = pk_fp8(o[0], o[1], o[2], o[3]);
    pk.y = pk_fp8(o[4], o[5], o[6], o[7]);
    *reinterpret_cast<uint2*>(&T[a]) = pk;
  }
#pragma unroll
  for (int o2 = 32; o2 > 0; o2 >>= 1) bsum += __shfl_down(bsum, o2, 64);
  __shared__ float red[4];
  int wid = t >> 6;
  if ((t & 63) == 0) red[wid] = bsum;
  __syncthreads();
  if (t == 0) atomicAdd(&tsum[m], red[0] + red[1] + red[2] + red[3]);
}

// =====================================================================
// Fused dual GEMM (fp8 e4m3 MFMA) + one-shot conversion + row stats.
// 2-phase role-split pipeline (R10 skeleton, fp8 datapath).
// __launch_bounds__(512,8): 8 waves/SIMD -> 4 blocks/CU (33 KB LDS, 48 VGPR)
// => entire 950-block grid co-resident (no second residency round), and
// 4 independent barrier groups per SIMD hide the per-step convoy.
__global__ __launch_bounds__(512, 8) void gemm_mega(
    const float* __restrict__ pm, const uchar* __restrict__ Tg,
    ushort* __restrict__ part, float* __restrict__ SP, float* __restrict__ sump) {
  __shared__ uchar buf[2][TSLICE];        // 28,672 B
  __shared__ uchar abuf[2][2][32 * 40];   //  5,120 B (40-byte padded rows)

  // bijective XCD swizzle (m204): nwg=950, q=118, r=6; kz-major chunks
  int orig = blockIdx.x;
  int xcd = orig & 7, base = orig >> 3;
  int wgid = (xcd < 6 ? xcd * 119 : 714 + (xcd - 6) * 118) + base;
  int kz = wgid / NBLK;
  int bn = wgid - kz * NBLK;

  int t = threadIdx.x, lane = t & 63, w = t >> 6;
  int rg = w >> 2, cg = w & 3;
  int l15 = lane & 15, kq = lane >> 4;

  bool is_b = (t < 256);
  bool is_a = (t >= 256);

  int at = t & 255;
  int arow = at >> 3, kf = at & 7;       // row 0..31, float4 chunk 0..7
  int rowA = bn * 32 + arow;
  int rowAc = min(rowA, N_PRED - 1);
  const float* apf = pm + (size_t)rowAc * KDIM + kz * (STEPS * 32) + kf * 4;
  int awoff = arow * 40 + kf * 4;        // BYTES within abuf[ni][arr]

  const uchar* tsrc = Tg + (size_t)(kz * STEPS) * TSLICE;
  int bbase = (kq * MPAD + cg * 112 + l15) * 8;      // B frag (byte idx)
  int afoff = (rg * 16 + l15) * 40 + kq * 8;         // A frag (byte idx)

  f32x4 z = {0.f, 0.f, 0.f, 0.f};
  f32x4 acc1[7], acc2[7];
#pragma unroll
  for (int j = 0; j < 7; ++j) { acc1[j] = z; acc2[j] = z; }
  float stx = 0.f, stp = 0.f;

  union fragu { uint2 u; long long l; };

#define WAITV(N) asm volatile("s_waitcnt vmcnt(" #N ")" ::: "memory")

#define STAGE_B(BI, ST)                                                        \
  do {                                                                         \
    const uchar* s_ = tsrc + (size_t)(ST) * TSLICE;                            \
    _Pragma("unroll")                                                          \
    for (int i_ = 0; i_ < 4; ++i_) {                                           \
      int c_ = w * 4 + i_;                                                     \
      if (c_ < 14)                                                             \
        gll16(s_ + c_ * 1024 + lane * 16, &buf[BI][c_ * 1024]);                \
    }                                                                          \
  } while (0)

#define CONVERT(NI, V)                                                         \
  do {                                                                         \
    float e0_ = __expf(-fabsf(V.x)), e1_ = __expf(-fabsf(V.y));                \
    float e2_ = __expf(-fabsf(V.z)), e3_ = __expf(-fabsf(V.w));                \
    float o0_ = 1.f + e0_, o1_ = 1.f + e1_, o2_ = 1.f + e2_, o3_ = 1.f + e3_;  \
    float i0_ = __builtin_amdgcn_rcpf(o0_), i1_ = __builtin_amdgcn_rcpf(o1_);  \
    float i2_ = __builtin_amdgcn_rcpf(o2_), i3_ = __builtin_amdgcn_rcpf(o3_);  \
    float s0_ = (V.x >= 0.f) ? i0_ : e0_ * i0_;                                \
    float s1_ = (V.y >= 0.f) ? i1_ : e1_ * i1_;                                \
    float s2_ = (V.z >= 0.f) ? i2_ : e2_ * i2_;                                \
    float s3_ = (V.w >= 0.f) ? i3_ : e3_ * i3_;                                \
    stp += s0_ + s1_ + s2_ + s3_;                                              \
    stx += fmaxf(V.x, 0.f) + fmaxf(V.y, 0.f) + fmaxf(V.z, 0.f) +              \
           fmaxf(V.w, 0.f) + __logf(o0_) + __logf(o1_) + __logf(o2_) +        \
           __logf(o3_);                                                        \
    *reinterpret_cast<uint32_t*>(&abuf[NI][0][awoff]) =                        \
        pk_fp8(V.x, V.y, V.z, V.w);                                            \
    *reinterpret_cast<uint32_t*>(&abuf[NI][1][awoff]) =                        \
        pk_fp8(s0_, s1_, s2_, s3_);                                            \
  } while (0)

// f(k) lives in fA when k is even, fB when k is odd.
#define ITER(CUR, S)                                                           \
  do {                                                                         \
    if (is_a && (S) + 2 < STEPS) {  /* issue A load for S+2 (same parity) */   \
      float4 nv_ = *reinterpret_cast<const float4*>(apf + ((S) + 2) * 32);     \
      if (CUR) fB = nv_; else fA = nv_;                                        \
    }                                                                          \
    if (is_b) WAITV(0);             /* stage(S) issued a full step ago */      \
    __builtin_amdgcn_s_barrier();                                              \
    __builtin_amdgcn_sched_barrier(0);                                         \
    if ((S) + 1 < STEPS) {                                                     \
      if (is_b) STAGE_B(CUR ^ 1, (S) + 1);  /* buf[CUR^1] free since S-1 */    \
      if (is_a) CONVERT(CUR ^ 1, (CUR ? fA : fB));                             \
    }                                                                          \
    {                                                                          \
      fragu ax_, ap_;                                                          \
      ax_.u = *reinterpret_cast<const uint2*>(&abuf[CUR][0][afoff]);           \
      ap_.u = *reinterpret_cast<const uint2*>(&abuf[CUR][1][afoff]);           \
      __builtin_amdgcn_s_setprio(1);                                           \
      _Pragma("unroll")                                                        \
      for (int j_ = 0; j_ < 7; ++j_) {                                         \
        fragu bv_;                                                             \
        bv_.u = *reinterpret_cast<const uint2*>(&buf[CUR][bbase + j_ * 128]);  \
        acc1[j_] = __builtin_amdgcn_mfma_f32_16x16x32_fp8_fp8(ax_.l, bv_.l, acc1[j_], 0, 0, 0); \
        acc2[j_] = __builtin_amdgcn_mfma_f32_16x16x32_fp8_fp8(ap_.l, bv_.l, acc2[j_], 0, 0, 0); \
      }                                                                        \
      __builtin_amdgcn_s_setprio(0);                                           \
    }                                                                          \
    asm volatile("s_waitcnt lgkmcnt(0)" ::: "memory");                         \
  } while (0)

  // ---- prologue: stage(0); A: f(0) converted, f(1) -> fB ----
  float4 fA, fB;
  if (is_b) STAGE_B(0, 0);
  if (is_a) {
    float4 f0 = *reinterpret_cast<const float4*>(apf);
    fB = *reinterpret_cast<const float4*>(apf + 32);
    CONVERT(0, f0);
  }
  asm volatile("s_waitcnt lgkmcnt(0)" ::: "memory");

  for (int s = 0; s < STEPS; s += 2) {
    ITER(0, s);
    ITER(1, s + 1);
  }
#undef ITER
#undef CONVERT
#undef STAGE_B
#undef WAITV

  // ---- row stats: 8 A-threads per row, xor-reduce width 8 ----
  if (is_a) {
    stx += __shfl_xor(stx, 1, 8); stx += __shfl_xor(stx, 2, 8); stx += __shfl_xor(stx, 4, 8);
    stp += __shfl_xor(stp, 1, 8); stp += __shfl_xor(stp, 2, 8); stp += __shfl_xor(stp, 4, 8);
    if ((at & 7) == 0 && rowA < N_PRED) {
      atomicAdd(SP + rowA, stx);
      atomicAdd(sump + rowA, stp);
    }
  }

  // ---- store bf16 partials: part[arr][n][kz][MPAD] ----
  ushort* p1 = part;
  ushort* p2 = part + (size_t)KZN * 1200 * MPAD;
#pragma unroll
  for (int j = 0; j < 7; ++j)
#pragma unroll
    for (int rr = 0; rr < 4; ++rr) {
      int gn = bn * 32 + rg * 16 + kq * 4 + rr;   // C/D: row=(lane>>4)*4+reg
      if (gn < N_PRED) {
        int gm = cg * 112 + j * 16 + l15;         // col=lane&15
        size_t o = ((size_t)gn * KZN + kz) * MPAD + gm;
        p1[o] = f2bf(acc1[j][rr]);
        p2[o] = f2bf(acc2[j][rr]);
      }
    }
}

// ---------------- softmax probs [1200,81] ----------------
__global__ void probs_kernel(const float* __restrict__ logits, float* __restrict__ probs) {
  int n = blockIdx.x;
  int l = threadIdx.x;
  const float* row = logits + n * NCLS;
  float v0 = row[l];
  bool has2 = (l + 64) < NCLS;
  float v1 = has2 ? row[l + 64] : -3.4e38f;
  float mx = fmaxf(v0, v1);
#pragma unroll
  for (int o = 1; o < 64; o <<= 1) mx = fmaxf(mx, __shfl_xor(mx, o, 64));
  float e0 = expf(v0 - mx);
  float e1 = has2 ? expf(v1 - mx) : 0.f;
  float sm = e0 + e1;
#pragma unroll
  for (int o = 1; o < 64; o <<= 1) sm += __shfl_xor(sm, o, 64);
  float inv = 1.f / sm;
  probs[n * NCLS + l] = e0 * inv;
  if (has2) probs[n * NCLS + l + 64] = e1 * inv;
}

// ---------------- final combine (bf16 partials, [n][kz][MPAD] layout) ----------------
__global__ void combine2(const ushort* __restrict__ part,
                         const float* __restrict__ SP, const float* __restrict__ sump,
                         const float* __restrict__ tsum, const float* __restrict__ probs,
                         const float* __restrict__ pboxes, const float* __restrict__ tboxes,
                         const int* __restrict__ tids, float* __restrict__ out) {
  int idx = blockIdx.x * 256 + threadIdx.x;   // < 480000
  int n = idx / M_TGT;
  int m = idx - n * M_TGT;

  const ushort* p1 = part + (size_t)n * (KZN * MPAD) + m;
  const ushort* p2 = p1 + (size_t)KZN * 1200 * MPAD;
  float A1 = 0.f, A2 = 0.f;
  for (int kz = 0; kz < KZN; ++kz) {
    A1 += bf2f(p1[kz * MPAD]);
    A2 += bf2f(p2[kz * MPAD]);
  }
  float cm = (SP[n] - A1) * (1.0f / (float)KDIM);
  float cd = 1.f - (2.f * A2 + 1e-5f) / (sump[n] + tsum[m] + 1e-5f);
  float cc = -probs[n * NCLS + tids[m]];

  float4 pb = reinterpret_cast<const float4*>(pboxes)[n];
  float4 tb = reinterpret_cast<const float4*>(tboxes)[m];
  float l1 = fabsf(pb.x - tb.x) + fabsf(pb.y - tb.y) + fabsf(pb.z - tb.z) + fabsf(pb.w - tb.w);
  float px1 = pb.x - 0.5f * pb.z, py1 = pb.y - 0.5f * pb.w;
  float px2 = pb.x + 0.5f * pb.z, py2 = pb.y + 0.5f * pb.w;
  float tx1 = tb.x - 0.5f * tb.z, ty1 = tb.y - 0.5f * tb.w;
  float tx2 = tb.x + 0.5f * tb.z, ty2 = tb.y + 0.5f * tb.w;
  float a1 = (px2 - px1) * (py2 - py1);
  float a2 = (tx2 - tx1) * (ty2 - ty1);
  float iw = fmaxf(fminf(px2, tx2) - fmaxf(px1, tx1), 0.f);
  float ih = fmaxf(fminf(py2, ty2) - fmaxf(py1, ty1), 0.f);
  float inter = iw * ih;
  float uni = a1 + a2 - inter;
  float iou = inter / uni;
  float ew = fmaxf(fmaxf(px2, tx2) - fminf(px1, tx1), 0.f);
  float eh = fmaxf(fmaxf(py2, ty2) - fminf(py1, ty1), 0.f);
  float ae = ew * eh;
  float giou = iou - (ae - uni) / ae;

  out[idx] = 5.f * l1 + 2.f * (-giou) + 2.f * cc + 5.f * cm + 5.f * cd;
}

// =====================================================================
// FALLBACK PATH (only if ws too small)
// =====================================================================

__device__ __forceinline__ float sigf(float x) {
  return 1.f / (1.f + __expf(-x));
}

__global__ void resize_lin(const float* __restrict__ tm, ushort* __restrict__ T,
                           float* __restrict__ tsum) {
  int m = blockIdx.x;
  int p = blockIdx.y * 256 + threadIdx.x;
  int y = p / 160;
  int x = p - y * 160;
  float wy[4], wx[4];
  int jy0, jx0;
  {
    float s = (y + 0.5f) * 1.6f - 0.5f;
    jy0 = (int)ceilf(s - 1.6f);
    float ws = 0.f;
#pragma unroll
    for (int a = 0; a < 4; ++a) {
      int j = jy0 + a;
      float w = fmaxf(0.f, 1.f - fabsf((float)j - s) * 0.625f);
      if (j < 0 || j > 255) w = 0.f;
      wy[a] = w; ws += w;
    }
    float inv = 1.f / ws;
#pragma unroll
    for (int a = 0; a < 4; ++a) wy[a] *= inv;
  }
  {
    float s = (x + 0.5f) * 1.6f - 0.5f;
    jx0 = (int)ceilf(s - 1.6f);
    float ws = 0.f;
#pragma unroll
    for (int b = 0; b < 4; ++b) {
      int j = jx0 + b;
      float w = fmaxf(0.f, 1.f - fabsf((float)j - s) * 0.625f);
      if (j < 0 || j > 255) w = 0.f;
      wx[b] = w; ws += w;
    }
    float inv = 1.f / ws;
#pragma unroll
    for (int b = 0; b < 4; ++b) wx[b] *= inv;
  }
  const float* base = tm + (size_t)m * 65536;
  float acc = 0.f;
#pragma unroll
  for (int a = 0; a < 4; ++a) {
    int jy = min(max(jy0 + a, 0), 255);
    float wya = wy[a];
#pragma unroll
    for (int b = 0; b < 4; ++b) {
      int jx = min(max(jx0 + b, 0), 255);
      acc += wya * wx[b] * base[jy * 256 + jx];
    }
  }
  T[(size_t)m * KDIM + p] = f2bf(acc);
  float v = acc;
#pragma unroll
  for (int o = 32; o > 0; o >>= 1) v += __shfl_down(v, o, 64);
  __shared__ float red[4];
  int wid = threadIdx.x >> 6;
  if ((threadIdx.x & 63) == 0) red[wid] = v;
  __syncthreads();
  if (threadIdx.x == 0) atomicAdd(&tsum[m], red[0] + red[1] + red[2] + red[3]);
}

__global__ void stats_kernel(const float* __restrict__ pm, float* __restrict__ S,
                             float* __restrict__ sump) {
  int n = blockIdx.x;
  const float4* row = reinterpret_cast<const float4*>(pm + (size_t)n * KDIM);
  float ssp = 0.f, sp = 0.f;
  for (int i = threadIdx.x; i < KDIM / 4; i += 256) {
    float4 v = row[i];
    float xs[4] = {v.x, v.y, v.z, v.w};
#pragma unroll
    for (int j = 0; j < 4; ++j) {
      float x = xs[j];
      float e = __expf(-fabsf(x));
      float inv1pe = 1.f / (1.f + e);
      sp += (x >= 0.f) ? inv1pe : e * inv1pe;
      ssp += fmaxf(x, 0.f) + log1pf(e);
    }
  }
#pragma unroll
  for (int o = 32; o > 0; o >>= 1) {
    ssp += __shfl_down(ssp, o, 64);
    sp  += __shfl_down(sp, o, 64);
  }
  __shared__ float red[8];
  int wid = threadIdx.x >> 6;
  if ((threadIdx.x & 63) == 0) { red[wid] = ssp; red[4 + wid] = sp; }
  __syncthreads();
  if (threadIdx.x == 0) {
    S[n]    = -(red[0] + red[1] + red[2] + red[3]);
    sump[n] = red[4] + red[5] + red[6] + red[7];
  }
}

__device__ __forceinline__ bf16x8 load_frag_lin(const ushort* p) {
  union { ushort4 u[2]; bf16x8 f; } fr;
  fr.u[0] = *reinterpret_cast<const ushort4*>(p);
  fr.u[1] = *reinterpret_cast<const ushort4*>(p + 4);
  return fr.f;
}

__global__ __launch_bounds__(256) void gemm_fused(
    const float* __restrict__ pm, const ushort* __restrict__ T,
    ushort* __restrict__ part1, ushort* __restrict__ part2, int k_per) {
  __shared__ ushort Ax[64][40];
  __shared__ ushort Ap[64][40];
  __shared__ ushort Bs[64][40];
  int n0 = blockIdx.x * 64;
  int m0 = blockIdx.y * 64;
  int kz = blockIdx.z;
  int k_begin = kz * k_per;
  int t = threadIdx.x;
  int r = t >> 2;
  int q = t & 3;
  bool a_ok = (n0 + r) < N_PRED;
  bool b_ok = (m0 + r) < M_TGT;
  const float*  pA = pm + (size_t)(n0 + r) * KDIM + k_begin + q * 8;
  const ushort* pB = T  + (size_t)(m0 + r) * KDIM + k_begin + q * 8;
  int lane = t & 63;
  int w = t >> 6;
  int wr = (w >> 1) * 32;
  int wc = (w & 1) * 32;
  int lrow = lane & 15;
  int kc = (lane >> 4) * 8;
  f32x4 zero = {0.f, 0.f, 0.f, 0.f};
  f32x4 acc1[2][2] = {{zero, zero}, {zero, zero}};
  f32x4 acc2[2][2] = {{zero, zero}, {zero, zero}};
  int steps = k_per / 32;
  for (int kt = 0; kt < steps; ++kt) {
    __syncthreads();
    float4 f0 = {0.f,0.f,0.f,0.f}, f1 = {0.f,0.f,0.f,0.f};
    if (a_ok) {
      f0 = *reinterpret_cast<const float4*>(pA);
      f1 = *reinterpret_cast<const float4*>(pA + 4);
    }
    pA += 32;
    ushort4 xa, xb, pa, pb4;
    xa.x = f2bf(f0.x); xa.y = f2bf(f0.y); xa.z = f2bf(f0.z); xa.w = f2bf(f0.w);
    xb.x = f2bf(f1.x); xb.y = f2bf(f1.y); xb.z = f2bf(f1.z); xb.w = f2bf(f1.w);
    pa.x = f2bf(sigf(f0.x)); pa.y = f2bf(sigf(f0.y)); pa.z = f2bf(sigf(f0.z)); pa.w = f2bf(sigf(f0.w));
    pb4.x = f2bf(sigf(f1.x)); pb4.y = f2bf(sigf(f1.y)); pb4.z = f2bf(sigf(f1.z)); pb4.w = f2bf(sigf(f1.w));
    *reinterpret_cast<ushort4*>(&Ax[r][q * 8])     = xa;
    *reinterpret_cast<ushort4*>(&Ax[r][q * 8 + 4]) = xb;
    *reinterpret_cast<ushort4*>(&Ap[r][q * 8])     = pa;
    *reinterpret_cast<ushort4*>(&Ap[r][q * 8 + 4]) = pb4;
    union { uint4 u; ushort4 s[2]; } bv;
    bv.u = make_uint4(0, 0, 0, 0);
    if (b_ok) bv.u = *reinterpret_cast<const uint4*>(pB);
    pB += 32;
    *reinterpret_cast<ushort4*>(&Bs[r][q * 8])     = bv.s[0];
    *reinterpret_cast<ushort4*>(&Bs[r][q * 8 + 4]) = bv.s[1];
    __syncthreads();
    bf16x8 ax[2], ap[2], bb[2];
#pragma unroll
    for (int i = 0; i < 2; ++i) {
      ax[i] = load_frag_lin(&Ax[wr + i * 16 + lrow][kc]);
      ap[i] = load_frag_lin(&Ap[wr + i * 16 + lrow][kc]);
      bb[i] = load_frag_lin(&Bs[wc + i * 16 + lrow][kc]);
    }
#pragma unroll
    for (int i = 0; i < 2; ++i)
#pragma unroll
      for (int j = 0; j < 2; ++j) {
        acc1[i][j] = __builtin_amdgcn_mfma_f32_16x16x32_bf16(ax[i], bb[j], acc1[i][j], 0, 0, 0);
        acc2[i][j] = __builtin_amdgcn_mfma_f32_16x16x32_bf16(ap[i], bb[j], acc2[i][j], 0, 0, 0);
      }
  }
  int rowb = (lane >> 4) * 4;
  int col = lane & 15;
#pragma unroll
  for (int i = 0; i < 2; ++i)
#pragma unroll
    for (int j = 0; j < 2; ++j)
#pragma unroll
      for (int rr = 0; rr < 4; ++rr) {
        int gn = n0 + wr + i * 16 + rowb + rr;
        int gm = m0 + wc + j * 16 + col;
        if (gn < N_PRED && gm < M_TGT) {
          size_t o = (size_t)kz * 480000 + (size_t)gn * 400 + gm;
          part1[o] = f2bf(acc1[i][j][rr]);
          part2[o] = f2bf(acc2[i][j][rr]);
        }
      }
}

__global__ void combine_fb(const ushort* __restrict__ part1, const ushort* __restrict__ part2,
                           const float* __restrict__ S, const float* __restrict__ sump,
                           const float* __restrict__ tsum, const float* __restrict__ probs,
                           const float* __restrict__ pboxes, const float* __restrict__ tboxes,
                           const int* __restrict__ tids, float* __restrict__ out, int KZ) {
  int idx = blockIdx.x * 256 + threadIdx.x;
  int n = idx / M_TGT;
  int m = idx - n * M_TGT;
  float A1 = 0.f, A2 = 0.f;
  for (int kz = 0; kz < KZ; ++kz) {
    A1 += bf2f(part1[(size_t)kz * 480000 + idx]);
    A2 += bf2f(part2[(size_t)kz * 480000 + idx]);
  }
  float cm = -(A1 + S[n]) * (1.0f / (float)KDIM);
  float cd = 1.f - (2.f * A2 + 1e-5f) / (sump[n] + tsum[m] + 1e-5f);
  float cc = -probs[n * NCLS + tids[m]];
  float4 pb = reinterpret_cast<const float4*>(pboxes)[n];
  float4 tb = reinterpret_cast<const float4*>(tboxes)[m];
  float l1 = fabsf(pb.x - tb.x) + fabsf(pb.y - tb.y) + fabsf(pb.z - tb.z) + fabsf(pb.w - tb.w);
  float px1 = pb.x - 0.5f * pb.z, py1 = pb.y - 0.5f * pb.w;
  float px2 = pb.x + 0.5f * pb.z, py2 = pb.y + 0.5f * pb.w;
  float tx1 = tb.x - 0.5f * tb.z, ty1 = tb.y - 0.5f * tb.w;
  float tx2 = tb.x + 0.5f * tb.z, ty2 = tb.y + 0.5f * tb.w;
  float a1 = (px2 - px1) * (py2 - py1);
  float a2 = (tx2 - tx1) * (ty2 - ty1);
  float iw = fmaxf(fminf(px2, tx2) - fmaxf(px1, tx1), 0.f);
  float ih = fmaxf(fminf(py2, ty2) - fmaxf(py1, ty1), 0.f);
  float inter = iw * ih;
  float uni = a1 + a2 - inter;
  float iou = inter / uni;
  float ew = fmaxf(fmaxf(px2, tx2) - fminf(px1, tx1), 0.f);
  float eh = fmaxf(fmaxf(py2, ty2) - fminf(py1, ty1), 0.f);
  float ae = ew * eh;
  float giou = iou - (ae - uni) / ae;
  out[idx] = 5.f * l1 + 2.f * (-giou) + 2.f * cc + 5.f * cm + 5.f * cd;
}

// =====================================================================

extern "C" void kernel_launch(void* const* d_in, const int* in_sizes, int n_in,
                              void* d_out, int out_size, void* d_ws, size_t ws_size,
                              hipStream_t stream) {
  const float* logits = (const float*)d_in[0];
  const float* pboxes = (const float*)d_in[1];
  const float* pmasks = (const float*)d_in[2];
  const float* tboxes = (const float*)d_in[3];
  const float* tmasks = (const float*)d_in[4];
  const int*   tids   = (const int*)d_in[5];
  float* out = (float*)d_out;
  char* ws = (char*)d_ws;

  // new-path workspace layout
  const size_t offT     = 0;                         // 800*14336 = 11,468,800 (fp8)
  const size_t offPart  = 24371200;                  // 2*25*1200*448*2 = 53,760,000
  const size_t offProbs = offPart + 53760000;        // 388,800
  const size_t offStats = offProbs + 390400;         // SP 4800 | sump 4800 | tsum 1600
  const size_t needNew  = offStats + 11200;

  if (ws_size >= needNew) {
    uchar* Tg    = (uchar*)(ws + offT);
    ushort* part = (ushort*)(ws + offPart);
    float* probs = (float*)(ws + offProbs);
    float* SP    = (float*)(ws + offStats);
    float* sump  = (float*)(ws + offStats + 4800);
    float* tsum  = (float*)(ws + offStats + 9600);

    hipMemsetAsync(SP, 0, 11200, stream);   // SP + sump + tsum
    resize2<<<dim3(M_TGT, 20), 256, 0, stream>>>(tmasks, Tg, tsum);
    probs_kernel<<<N_PRED, 64, 0, stream>>>(logits, probs);
    gemm_mega<<<NBLK * KZN, 512, 0, stream>>>(pmasks, Tg, part, SP, sump);
    combine2<<<1875, 256, 0, stream>>>(part, SP, sump, tsum, probs,
                                       pboxes, tboxes, tids, out);
  } else {
    // fallback (R4 pipeline)
    ushort* T     = (ushort*)ws;
    float*  probs = (float*)(ws + 20480000);
    float*  S     = (float*)(ws + 20868800);
    float*  sump  = (float*)(ws + 20873600);
    float*  tsum  = (float*)(ws + 20878400);
    ushort* part1 = (ushort*)(ws + 20880000);
    size_t need8 = 20880000ull + 2ull * 8 * 480000 * 2;
    int KZf = (ws_size >= need8) ? 8 : 1;
    ushort* part2 = part1 + (size_t)KZf * 480000;

    hipMemsetAsync(tsum, 0, M_TGT * sizeof(float), stream);
    resize_lin<<<dim3(M_TGT, 100), 256, 0, stream>>>(tmasks, T, tsum);
    probs_kernel<<<N_PRED, 64, 0, stream>>>(logits, probs);
    stats_kernel<<<N_PRED, 256, 0, stream>>>(pmasks, S, sump);
    gemm_fused<<<dim3(19, 7, KZf), 256, 0, stream>>>(pmasks, T, part1, part2, KDIM / KZf);
    combine_fb<<<1875, 256, 0, stream>>>(part1, part2, S, sump, tsum, probs,
                                         pboxes, tboxes, tids, out, KZf);
  }
}

// Round 13
// 152.710 us; speedup vs baseline: 3.9030x; 3.9030x over previous
//
#include <hip/hip_runtime.h>
#include <cstdint>

#define N_PRED 1200
#define M_TGT  400
#define KDIM   25600   // 160*160
#define NCLS   81
#define MPAD   448     // padded target count for partials (28 x 16)
#define SPAD   512     // padded target count for staging (16 x 1KB chunks)
#define KZN    25      // split-K factor
#define NBLK   38      // row blocks of 32 (1216 >= 1200)
#define STEPS  32      // K-steps (BK=32) per block
#define TSLICE 16384   // BYTES per BK=32 step: 4(kq) * 512 * 8 fp8

typedef __attribute__((ext_vector_type(8)))  short bf16x8;
typedef __attribute__((ext_vector_type(4)))  float f32x4;
typedef unsigned char uchar;

__device__ __forceinline__ ushort f2bf(float f) {
  union { float f; uint32_t u; } v; v.f = f;
  uint32_t u = v.u + 0x7fffu + ((v.u >> 16) & 1u);
  return (ushort)(u >> 16);
}

__device__ __forceinline__ float bf2f(ushort s) {
  union { uint32_t u; float f; } v; v.u = ((uint32_t)s) << 16;
  return v.f;
}

// pack 4 f32 -> 4 fp8 e4m3 (OCP, saturating) in one u32
__device__ __forceinline__ uint32_t pk_fp8(float a, float b, float c, float d) {
  uint32_t v = (uint32_t)__builtin_amdgcn_cvt_pk_fp8_f32(a, b, 0, false);
  v = (uint32_t)__builtin_amdgcn_cvt_pk_fp8_f32(c, d, (int)v, true);
  return v;
}

__device__ __forceinline__ void gll16(const void* g, void* l) {
  __builtin_amdgcn_global_load_lds(
      (const __attribute__((address_space(1))) void*)g,
      (__attribute__((address_space(3))) void*)l, 16, 0, 0);
}

// =====================================================================
// Resize tgt_masks [400,256,256] -> T fp8 fragment-major: [kt(800)][kq(4)][m(512)][8]
__global__ __launch_bounds__(256) void resize2(const float* __restrict__ tm,
                                               uchar* __restrict__ T,
                                               float* __restrict__ tsum) {
  __shared__ float rows[16][256];
  __shared__ float vbuf[8][256];

  int m = blockIdx.x, yt = blockIdx.y;  // yt 0..19
  int y0 = yt * 8;
  int t = threadIdx.x;

  int jbase = (int)ceilf((y0 + 0.5f) * 1.6f - 2.1f);

  const float* base = tm + (size_t)m * 65536;
  {
    int r = t >> 4;
    int c0 = (t & 15) * 16;
    int jr = min(max(jbase + r, 0), 255);
    const float4* src = reinterpret_cast<const float4*>(base + jr * 256 + c0);
#pragma unroll
    for (int i = 0; i < 4; ++i)
      *reinterpret_cast<float4*>(&rows[r][c0 + i * 4]) = src[i];
  }
  __syncthreads();

#pragma unroll
  for (int yy = 0; yy < 8; ++yy) {
    int y = y0 + yy;
    float s = (y + 0.5f) * 1.6f - 0.5f;
    int j0 = (int)ceilf(s - 1.6f);
    float w[4]; float wsum = 0.f;
#pragma unroll
    for (int a = 0; a < 4; ++a) {
      int j = j0 + a;
      float wv = fmaxf(0.f, 1.f - fabsf((float)j - s) * 0.625f);
      if (j < 0 || j > 255) wv = 0.f;
      w[a] = wv; wsum += wv;
    }
    float winv = __builtin_amdgcn_rcpf(wsum);
    float acc = 0.f;
    int rbase = j0 - jbase;
#pragma unroll
    for (int a = 0; a < 4; ++a) acc += w[a] * rows[rbase + a][t];
    vbuf[yy][t] = acc * winv;
  }
  __syncthreads();

  float bsum = 0.f;
  if (t < 160) {
    int yy = t / 20, ch = t - yy * 20;
    float o[8];
#pragma unroll
    for (int j = 0; j < 8; ++j) {
      int x = ch * 8 + j;
      float sx = (x + 0.5f) * 1.6f - 0.5f;
      int jx0 = (int)ceilf(sx - 1.6f);
      float wsum = 0.f, h = 0.f;
#pragma unroll
      for (int b = 0; b < 4; ++b) {
        int jj = jx0 + b;
        float wv = fmaxf(0.f, 1.f - fabsf((float)jj - sx) * 0.625f);
        if (jj < 0 || jj > 255) wv = 0.f;
        wsum += wv;
        h += wv * vbuf[yy][min(max(jj, 0), 255)];
      }
      h *= __builtin_amdgcn_rcpf(wsum);
      o[j] = h; bsum += h;
    }
    int p0 = (y0 + yy) * 160 + ch * 8;
    int kt = p0 >> 5, kq = (p0 >> 3) & 3;
    size_t a = ((size_t)(kt * 4 + kq) * SPAD + m) * 8;
    uint2 pk;
    pk.x = pk_fp8(o[0], o[1], o[2], o[3]);
    pk.y = pk_fp8(o[4], o[5], o[6], o[7]);
    *reinterpret_cast<uint2*>(&T[a]) = pk;
  }
#pragma unroll
  for (int o2 = 32; o2 > 0; o2 >>= 1) bsum += __shfl_down(bsum, o2, 64);
  __shared__ float red[4];
  int wid = t >> 6;
  if ((t & 63) == 0) red[wid] = bsum;
  __syncthreads();
  if (t == 0) atomicAdd(&tsum[m], red[0] + red[1] + red[2] + red[3]);
}

// =====================================================================
// Fused dual GEMM (fp8 e4m3 MFMA) + one-shot conversion + row stats.
// Triple-buffered B staged 2 steps ahead (each stage = exactly 4 gll16 per
// staging thread; in-loop wait = vmcnt(4), never 0 until drain). A: f32
// global->reg with full-iteration lookahead, converted once, ds_write abuf.
// 512 thr: waves 0-3 stage B, waves 4-7 load+convert A; all 8 do MFMA.
// LDS 54 KB -> 2 blocks/CU. launch_bounds (512,4): 128-reg budget, no spill.
__global__ __launch_bounds__(512, 4) void gemm_mega(
    const float* __restrict__ pm, const uchar* __restrict__ Tg,
    ushort* __restrict__ part, float* __restrict__ SP, float* __restrict__ sump) {
  __shared__ uchar buf[3][TSLICE];        // 49,152 B
  __shared__ uchar abuf[2][2][32 * 40];   //  5,120 B (40-byte padded rows)

  // bijective XCD swizzle (m204): nwg=950, q=118, r=6; kz-major chunks
  int orig = blockIdx.x;
  int xcd = orig & 7, base = orig >> 3;
  int wgid = (xcd < 6 ? xcd * 119 : 714 + (xcd - 6) * 118) + base;
  int kz = wgid / NBLK;
  int bn = wgid - kz * NBLK;

  int t = threadIdx.x, lane = t & 63, w = t >> 6;
  int rg = w >> 2, cg = w & 3;
  int l15 = lane & 15, kq = lane >> 4;

  bool is_b = (t < 256);
  bool is_a = (t >= 256);

  int at = t & 255;
  int arow = at >> 3, kf = at & 7;       // row 0..31, float4 chunk 0..7
  int rowA = bn * 32 + arow;
  int rowAc = min(rowA, N_PRED - 1);
  const float* apf = pm + (size_t)rowAc * KDIM + kz * (STEPS * 32) + kf * 4;
  int awoff = arow * 40 + kf * 4;        // BYTES within abuf[ni][arr]

  const uchar* tsrc = Tg + (size_t)(kz * STEPS) * TSLICE;
  int bbase = (kq * SPAD + cg * 112 + l15) * 8;      // B frag (byte idx)
  int afoff = (rg * 16 + l15) * 40 + kq * 8;         // A frag (byte idx)

  uchar* bufb = &buf[0][0];

  f32x4 z = {0.f, 0.f, 0.f, 0.f};
  f32x4 acc1[7], acc2[7];
#pragma unroll
  for (int j = 0; j < 7; ++j) { acc1[j] = z; acc2[j] = z; }
  float stx = 0.f, stp = 0.f;

  union fragu { uint2 u; long long l; };

#define WAITV(N) asm volatile("s_waitcnt vmcnt(" #N ")" ::: "memory")

// stage step ST into LDS byte-offset BO (runtime). 16 chunks x 1KB; every
// staging thread issues exactly 4 gll16 -> uniform vmcnt accounting.
#define STAGE_B(BO, ST)                                                        \
  do {                                                                         \
    const uchar* s_ = tsrc + (size_t)(ST) * TSLICE;                            \
    _Pragma("unroll")                                                          \
    for (int i_ = 0; i_ < 4; ++i_) {                                           \
      int c_ = w * 4 + i_;                                                     \
      gll16(s_ + c_ * 1024 + lane * 16, bufb + (BO) + c_ * 1024);              \
    }                                                                          \
  } while (0)

#define CONVERT(NI, V)                                                         \
  do {                                                                         \
    float e0_ = __expf(-fabsf(V.x)), e1_ = __expf(-fabsf(V.y));                \
    float e2_ = __expf(-fabsf(V.z)), e3_ = __expf(-fabsf(V.w));                \
    float o0_ = 1.f + e0_, o1_ = 1.f + e1_, o2_ = 1.f + e2_, o3_ = 1.f + e3_;  \
    float i0_ = __builtin_amdgcn_rcpf(o0_), i1_ = __builtin_amdgcn_rcpf(o1_);  \
    float i2_ = __builtin_amdgcn_rcpf(o2_), i3_ = __builtin_amdgcn_rcpf(o3_);  \
    float s0_ = (V.x >= 0.f) ? i0_ : e0_ * i0_;                                \
    float s1_ = (V.y >= 0.f) ? i1_ : e1_ * i1_;                                \
    float s2_ = (V.z >= 0.f) ? i2_ : e2_ * i2_;                                \
    float s3_ = (V.w >= 0.f) ? i3_ : e3_ * i3_;                                \
    stp += s0_ + s1_ + s2_ + s3_;                                              \
    stx += fmaxf(V.x, 0.f) + fmaxf(V.y, 0.f) + fmaxf(V.z, 0.f) +              \
           fmaxf(V.w, 0.f) + __logf(o0_) + __logf(o1_) + __logf(o2_) +        \
           __logf(o3_);                                                        \
    *reinterpret_cast<uint32_t*>(&abuf[NI][0][awoff]) =                        \
        pk_fp8(V.x, V.y, V.z, V.w);                                            \
    *reinterpret_cast<uint32_t*>(&abuf[NI][1][awoff]) =                        \
        pk_fp8(s0_, s1_, s2_, s3_);                                            \
  } while (0)

// ACUR: compile-time parity (A regs / abuf). bR/bW: runtime tri-buffer offsets.
#define ITER(ACUR, S)                                                          \
  do {                                                                         \
    if (is_a && (S) + 2 < STEPS) {  /* issue A load for S+2 (same parity) */   \
      float4 nv_ = *reinterpret_cast<const float4*>(apf + ((S) + 2) * 32);     \
      if (ACUR) fB = nv_; else fA = nv_;                                       \
    }                                                                          \
    if (is_b) { if ((S) < STEPS - 1) WAITV(4); else WAITV(0); }                \
    __builtin_amdgcn_s_barrier();                                              \
    __builtin_amdgcn_sched_barrier(0);                                         \
    if ((S) + 2 < STEPS) { if (is_b) STAGE_B(bW, (S) + 2); }                   \
    if ((S) + 1 < STEPS) { if (is_a) CONVERT(ACUR ^ 1, (ACUR ? fA : fB)); }    \
    {                                                                          \
      fragu ax_, ap_;                                                          \
      ax_.u = *reinterpret_cast<const uint2*>(&abuf[ACUR][0][afoff]);          \
      ap_.u = *reinterpret_cast<const uint2*>(&abuf[ACUR][1][afoff]);          \
      __builtin_amdgcn_s_setprio(1);                                           \
      _Pragma("unroll")                                                        \
      for (int j_ = 0; j_ < 7; ++j_) {                                         \
        fragu bv_;                                                             \
        bv_.u = *reinterpret_cast<const uint2*>(bufb + bR + bbase + j_ * 128); \
        acc1[j_] = __builtin_amdgcn_mfma_f32_16x16x32_fp8_fp8(ax_.l, bv_.l, acc1[j_], 0, 0, 0); \
        acc2[j_] = __builtin_amdgcn_mfma_f32_16x16x32_fp8_fp8(ap_.l, bv_.l, acc2[j_], 0, 0, 0); \
      }                                                                        \
      __builtin_amdgcn_s_setprio(0);                                           \
    }                                                                          \
    asm volatile("s_waitcnt lgkmcnt(0)" ::: "memory");                         \
    bR = (bR == 2 * TSLICE) ? 0 : bR + TSLICE;                                 \
    bW = (bW == 2 * TSLICE) ? 0 : bW + TSLICE;                                 \
  } while (0)

  // ---- prologue: stage(0)->buf0, stage(1)->buf1; A: f(0) converted, f(1)->fB ----
  int bR = 0, bW = 2 * TSLICE;   // step 0 reads buf0; stage(2) targets buf2
  float4 fA, fB;
  if (is_b) { STAGE_B(0, 0); STAGE_B(TSLICE, 1); }
  if (is_a) {
    float4 f0 = *reinterpret_cast<const float4*>(apf);
    fB = *reinterpret_cast<const float4*>(apf + 32);
    CONVERT(0, f0);
  }
  asm volatile("s_waitcnt lgkmcnt(0)" ::: "memory");

  for (int s = 0; s < STEPS; s += 2) {
    ITER(0, s);
    ITER(1, s + 1);
  }
#undef ITER
#undef CONVERT
#undef STAGE_B
#undef WAITV

  // ---- row stats: 8 A-threads per row, xor-reduce width 8 ----
  if (is_a) {
    stx += __shfl_xor(stx, 1, 8); stx += __shfl_xor(stx, 2, 8); stx += __shfl_xor(stx, 4, 8);
    stp += __shfl_xor(stp, 1, 8); stp += __shfl_xor(stp, 2, 8); stp += __shfl_xor(stp, 4, 8);
    if ((at & 7) == 0 && rowA < N_PRED) {
      atomicAdd(SP + rowA, stx);
      atomicAdd(sump + rowA, stp);
    }
  }

  // ---- store bf16 partials: part[arr][n][kz][MPAD] ----
  ushort* p1 = part;
  ushort* p2 = part + (size_t)KZN * 1200 * MPAD;
#pragma unroll
  for (int j = 0; j < 7; ++j)
#pragma unroll
    for (int rr = 0; rr < 4; ++rr) {
      int gn = bn * 32 + rg * 16 + kq * 4 + rr;   // C/D: row=(lane>>4)*4+reg
      if (gn < N_PRED) {
        int gm = cg * 112 + j * 16 + l15;         // col=lane&15
        size_t o = ((size_t)gn * KZN + kz) * MPAD + gm;
        p1[o] = f2bf(acc1[j][rr]);
        p2[o] = f2bf(acc2[j][rr]);
      }
    }
}

// ---------------- softmax probs [1200,81] ----------------
__global__ void probs_kernel(const float* __restrict__ logits, float* __restrict__ probs) {
  int n = blockIdx.x;
  int l = threadIdx.x;
  const float* row = logits + n * NCLS;
  float v0 = row[l];
  bool has2 = (l + 64) < NCLS;
  float v1 = has2 ? row[l + 64] : -3.4e38f;
  float mx = fmaxf(v0, v1);
#pragma unroll
  for (int o = 1; o < 64; o <<= 1) mx = fmaxf(mx, __shfl_xor(mx, o, 64));
  float e0 = expf(v0 - mx);
  float e1 = has2 ? expf(v1 - mx) : 0.f;
  float sm = e0 + e1;
#pragma unroll
  for (int o = 1; o < 64; o <<= 1) sm += __shfl_xor(sm, o, 64);
  float inv = 1.f / sm;
  probs[n * NCLS + l] = e0 * inv;
  if (has2) probs[n * NCLS + l + 64] = e1 * inv;
}

// ---------------- final combine (bf16 partials, [n][kz][MPAD] layout) ----------------
__global__ void combine2(const ushort* __restrict__ part,
                         const float* __restrict__ SP, const float* __restrict__ sump,
                         const float* __restrict__ tsum, const float* __restrict__ probs,
                         const float* __restrict__ pboxes, const float* __restrict__ tboxes,
                         const int* __restrict__ tids, float* __restrict__ out) {
  int idx = blockIdx.x * 256 + threadIdx.x;   // < 480000
  int n = idx / M_TGT;
  int m = idx - n * M_TGT;

  const ushort* p1 = part + (size_t)n * (KZN * MPAD) + m;
  const ushort* p2 = p1 + (size_t)KZN * 1200 * MPAD;
  float A1 = 0.f, A2 = 0.f;
  for (int kz = 0; kz < KZN; ++kz) {
    A1 += bf2f(p1[kz * MPAD]);
    A2 += bf2f(p2[kz * MPAD]);
  }
  float cm = (SP[n] - A1) * (1.0f / (float)KDIM);
  float cd = 1.f - (2.f * A2 + 1e-5f) / (sump[n] + tsum[m] + 1e-5f);
  float cc = -probs[n * NCLS + tids[m]];

  float4 pb = reinterpret_cast<const float4*>(pboxes)[n];
  float4 tb = reinterpret_cast<const float4*>(tboxes)[m];
  float l1 = fabsf(pb.x - tb.x) + fabsf(pb.y - tb.y) + fabsf(pb.z - tb.z) + fabsf(pb.w - tb.w);
  float px1 = pb.x - 0.5f * pb.z, py1 = pb.y - 0.5f * pb.w;
  float px2 = pb.x + 0.5f * pb.z, py2 = pb.y + 0.5f * pb.w;
  float tx1 = tb.x - 0.5f * tb.z, ty1 = tb.y - 0.5f * tb.w;
  float tx2 = tb.x + 0.5f * tb.z, ty2 = tb.y + 0.5f * tb.w;
  float a1 = (px2 - px1) * (py2 - py1);
  float a2 = (tx2 - tx1) * (ty2 - ty1);
  float iw = fmaxf(fminf(px2, tx2) - fmaxf(px1, tx1), 0.f);
  float ih = fmaxf(fminf(py2, ty2) - fmaxf(py1, ty1), 0.f);
  float inter = iw * ih;
  float uni = a1 + a2 - inter;
  float iou = inter / uni;
  float ew = fmaxf(fmaxf(px2, tx2) - fminf(px1, tx1), 0.f);
  float eh = fmaxf(fmaxf(py2, ty2) - fminf(py1, ty1), 0.f);
  float ae = ew * eh;
  float giou = iou - (ae - uni) / ae;

  out[idx] = 5.f * l1 + 2.f * (-giou) + 2.f * cc + 5.f * cm + 5.f * cd;
}

// =====================================================================
// FALLBACK PATH (only if ws too small)
// =====================================================================

__device__ __forceinline__ float sigf(float x) {
  return 1.f / (1.f + __expf(-x));
}

__global__ void resize_lin(const float* __restrict__ tm, ushort* __restrict__ T,
                           float* __restrict__ tsum) {
  int m = blockIdx.x;
  int p = blockIdx.y * 256 + threadIdx.x;
  int y = p / 160;
  int x = p - y * 160;
  float wy[4], wx[4];
  int jy0, jx0;
  {
    float s = (y + 0.5f) * 1.6f - 0.5f;
    jy0 = (int)ceilf(s - 1.6f);
    float ws = 0.f;
#pragma unroll
    for (int a = 0; a < 4; ++a) {
      int j = jy0 + a;
      float w = fmaxf(0.f, 1.f - fabsf((float)j - s) * 0.625f);
      if (j < 0 || j > 255) w = 0.f;
      wy[a] = w; ws += w;
    }
    float inv = 1.f / ws;
#pragma unroll
    for (int a = 0; a < 4; ++a) wy[a] *= inv;
  }
  {
    float s = (x + 0.5f) * 1.6f - 0.5f;
    jx0 = (int)ceilf(s - 1.6f);
    float ws = 0.f;
#pragma unroll
    for (int b = 0; b < 4; ++b) {
      int j = jx0 + b;
      float w = fmaxf(0.f, 1.f - fabsf((float)j - s) * 0.625f);
      if (j < 0 || j > 255) w = 0.f;
      wx[b] = w; ws += w;
    }
    float inv = 1.f / ws;
#pragma unroll
    for (int b = 0; b < 4; ++b) wx[b] *= inv;
  }
  const float* base = tm + (size_t)m * 65536;
  float acc = 0.f;
#pragma unroll
  for (int a = 0; a < 4; ++a) {
    int jy = min(max(jy0 + a, 0), 255);
    float wya = wy[a];
#pragma unroll
    for (int b = 0; b < 4; ++b) {
      int jx = min(max(jx0 + b, 0), 255);
      acc += wya * wx[b] * base[jy * 256 + jx];
    }
  }
  T[(size_t)m * KDIM + p] = f2bf(acc);
  float v = acc;
#pragma unroll
  for (int o = 32; o > 0; o >>= 1) v += __shfl_down(v, o, 64);
  __shared__ float red[4];
  int wid = threadIdx.x >> 6;
  if ((threadIdx.x & 63) == 0) red[wid] = v;
  __syncthreads();
  if (threadIdx.x == 0) atomicAdd(&tsum[m], red[0] + red[1] + red[2] + red[3]);
}

__global__ void stats_kernel(const float* __restrict__ pm, float* __restrict__ S,
                             float* __restrict__ sump) {
  int n = blockIdx.x;
  const float4* row = reinterpret_cast<const float4*>(pm + (size_t)n * KDIM);
  float ssp = 0.f, sp = 0.f;
  for (int i = threadIdx.x; i < KDIM / 4; i += 256) {
    float4 v = row[i];
    float xs[4] = {v.x, v.y, v.z, v.w};
#pragma unroll
    for (int j = 0; j < 4; ++j) {
      float x = xs[j];
      float e = __expf(-fabsf(x));
      float inv1pe = 1.f / (1.f + e);
      sp += (x >= 0.f) ? inv1pe : e * inv1pe;
      ssp += fmaxf(x, 0.f) + log1pf(e);
    }
  }
#pragma unroll
  for (int o = 32; o > 0; o >>= 1) {
    ssp += __shfl_down(ssp, o, 64);
    sp  += __shfl_down(sp, o, 64);
  }
  __shared__ float red[8];
  int wid = threadIdx.x >> 6;
  if ((threadIdx.x & 63) == 0) { red[wid] = ssp; red[4 + wid] = sp; }
  __syncthreads();
  if (threadIdx.x == 0) {
    S[n]    = -(red[0] + red[1] + red[2] + red[3]);
    sump[n] = red[4] + red[5] + red[6] + red[7];
  }
}

__device__ __forceinline__ bf16x8 load_frag_lin(const ushort* p) {
  union { ushort4 u[2]; bf16x8 f; } fr;
  fr.u[0] = *reinterpret_cast<const ushort4*>(p);
  fr.u[1] = *reinterpret_cast<const ushort4*>(p + 4);
  return fr.f;
}

__global__ __launch_bounds__(256) void gemm_fused(
    const float* __restrict__ pm, const ushort* __restrict__ T,
    ushort* __restrict__ part1, ushort* __restrict__ part2, int k_per) {
  __shared__ ushort Ax[64][40];
  __shared__ ushort Ap[64][40];
  __shared__ ushort Bs[64][40];
  int n0 = blockIdx.x * 64;
  int m0 = blockIdx.y * 64;
  int kz = blockIdx.z;
  int k_begin = kz * k_per;
  int t = threadIdx.x;
  int r = t >> 2;
  int q = t & 3;
  bool a_ok = (n0 + r) < N_PRED;
  bool b_ok = (m0 + r) < M_TGT;
  const float*  pA = pm + (size_t)(n0 + r) * KDIM + k_begin + q * 8;
  const ushort* pB = T  + (size_t)(m0 + r) * KDIM + k_begin + q * 8;
  int lane = t & 63;
  int w = t >> 6;
  int wr = (w >> 1) * 32;
  int wc = (w & 1) * 32;
  int lrow = lane & 15;
  int kc = (lane >> 4) * 8;
  f32x4 zero = {0.f, 0.f, 0.f, 0.f};
  f32x4 acc1[2][2] = {{zero, zero}, {zero, zero}};
  f32x4 acc2[2][2] = {{zero, zero}, {zero, zero}};
  int steps = k_per / 32;
  for (int kt = 0; kt < steps; ++kt) {
    __syncthreads();
    float4 f0 = {0.f,0.f,0.f,0.f}, f1 = {0.f,0.f,0.f,0.f};
    if (a_ok) {
      f0 = *reinterpret_cast<const float4*>(pA);
      f1 = *reinterpret_cast<const float4*>(pA + 4);
    }
    pA += 32;
    ushort4 xa, xb, pa, pb4;
    xa.x = f2bf(f0.x); xa.y = f2bf(f0.y); xa.z = f2bf(f0.z); xa.w = f2bf(f0.w);
    xb.x = f2bf(f1.x); xb.y = f2bf(f1.y); xb.z = f2bf(f1.z); xb.w = f2bf(f1.w);
    pa.x = f2bf(sigf(f0.x)); pa.y = f2bf(sigf(f0.y)); pa.z = f2bf(sigf(f0.z)); pa.w = f2bf(sigf(f0.w));
    pb4.x = f2bf(sigf(f1.x)); pb4.y = f2bf(sigf(f1.y)); pb4.z = f2bf(sigf(f1.z)); pb4.w = f2bf(sigf(f1.w));
    *reinterpret_cast<ushort4*>(&Ax[r][q * 8])     = xa;
    *reinterpret_cast<ushort4*>(&Ax[r][q * 8 + 4]) = xb;
    *reinterpret_cast<ushort4*>(&Ap[r][q * 8])     = pa;
    *reinterpret_cast<ushort4*>(&Ap[r][q * 8 + 4]) = pb4;
    union { uint4 u; ushort4 s[2]; } bv;
    bv.u = make_uint4(0, 0, 0, 0);
    if (b_ok) bv.u = *reinterpret_cast<const uint4*>(pB);
    pB += 32;
    *reinterpret_cast<ushort4*>(&Bs[r][q * 8])     = bv.s[0];
    *reinterpret_cast<ushort4*>(&Bs[r][q * 8 + 4]) = bv.s[1];
    __syncthreads();
    bf16x8 ax[2], ap[2], bb[2];
#pragma unroll
    for (int i = 0; i < 2; ++i) {
      ax[i] = load_frag_lin(&Ax[wr + i * 16 + lrow][kc]);
      ap[i] = load_frag_lin(&Ap[wr + i * 16 + lrow][kc]);
      bb[i] = load_frag_lin(&Bs[wc + i * 16 + lrow][kc]);
    }
#pragma unroll
    for (int i = 0; i < 2; ++i)
#pragma unroll
      for (int j = 0; j < 2; ++j) {
        acc1[i][j] = __builtin_amdgcn_mfma_f32_16x16x32_bf16(ax[i], bb[j], acc1[i][j], 0, 0, 0);
        acc2[i][j] = __builtin_amdgcn_mfma_f32_16x16x32_bf16(ap[i], bb[j], acc2[i][j], 0, 0, 0);
      }
  }
  int rowb = (lane >> 4) * 4;
  int col = lane & 15;
#pragma unroll
  for (int i = 0; i < 2; ++i)
#pragma unroll
    for (int j = 0; j < 2; ++j)
#pragma unroll
      for (int rr = 0; rr < 4; ++rr) {
        int gn = n0 + wr + i * 16 + rowb + rr;
        int gm = m0 + wc + j * 16 + col;
        if (gn < N_PRED && gm < M_TGT) {
          size_t o = (size_t)kz * 480000 + (size_t)gn * 400 + gm;
          part1[o] = f2bf(acc1[i][j][rr]);
          part2[o] = f2bf(acc2[i][j][rr]);
        }
      }
}

__global__ void combine_fb(const ushort* __restrict__ part1, const ushort* __restrict__ part2,
                           const float* __restrict__ S, const float* __restrict__ sump,
                           const float* __restrict__ tsum, const float* __restrict__ probs,
                           const float* __restrict__ pboxes, const float* __restrict__ tboxes,
                           const int* __restrict__ tids, float* __restrict__ out, int KZ) {
  int idx = blockIdx.x * 256 + threadIdx.x;
  int n = idx / M_TGT;
  int m = idx - n * M_TGT;
  float A1 = 0.f, A2 = 0.f;
  for (int kz = 0; kz < KZ; ++kz) {
    A1 += bf2f(part1[(size_t)kz * 480000 + idx]);
    A2 += bf2f(part2[(size_t)kz * 480000 + idx]);
  }
  float cm = -(A1 + S[n]) * (1.0f / (float)KDIM);
  float cd = 1.f - (2.f * A2 + 1e-5f) / (sump[n] + tsum[m] + 1e-5f);
  float cc = -probs[n * NCLS + tids[m]];
  float4 pb = reinterpret_cast<const float4*>(pboxes)[n];
  float4 tb = reinterpret_cast<const float4*>(tboxes)[m];
  float l1 = fabsf(pb.x - tb.x) + fabsf(pb.y - tb.y) + fabsf(pb.z - tb.z) + fabsf(pb.w - tb.w);
  float px1 = pb.x - 0.5f * pb.z, py1 = pb.y - 0.5f * pb.w;
  float px2 = pb.x + 0.5f * pb.z, py2 = pb.y + 0.5f * pb.w;
  float tx1 = tb.x - 0.5f * tb.z, ty1 = tb.y - 0.5f * tb.w;
  float tx2 = tb.x + 0.5f * tb.z, ty2 = tb.y + 0.5f * tb.w;
  float a1 = (px2 - px1) * (py2 - py1);
  float a2 = (tx2 - tx1) * (ty2 - ty1);
  float iw = fmaxf(fminf(px2, tx2) - fmaxf(px1, tx1), 0.f);
  float ih = fmaxf(fminf(py2, ty2) - fmaxf(py1, ty1), 0.f);
  float inter = iw * ih;
  float uni = a1 + a2 - inter;
  float iou = inter / uni;
  float ew = fmaxf(fmaxf(px2, tx2) - fminf(px1, tx1), 0.f);
  float eh = fmaxf(fmaxf(py2, ty2) - fminf(py1, ty1), 0.f);
  float ae = ew * eh;
  float giou = iou - (ae - uni) / ae;
  out[idx] = 5.f * l1 + 2.f * (-giou) + 2.f * cc + 5.f * cm + 5.f * cd;
}

// =====================================================================

extern "C" void kernel_launch(void* const* d_in, const int* in_sizes, int n_in,
                              void* d_out, int out_size, void* d_ws, size_t ws_size,
                              hipStream_t stream) {
  const float* logits = (const float*)d_in[0];
  const float* pboxes = (const float*)d_in[1];
  const float* pmasks = (const float*)d_in[2];
  const float* tboxes = (const float*)d_in[3];
  const float* tmasks = (const float*)d_in[4];
  const int*   tids   = (const int*)d_in[5];
  float* out = (float*)d_out;
  char* ws = (char*)d_ws;

  // new-path workspace layout
  const size_t offT     = 0;                         // 800*16384 = 13,107,200 (fp8, SPAD=512)
  const size_t offPart  = 24371200;                  // 2*25*1200*448*2 = 53,760,000
  const size_t offProbs = offPart + 53760000;        // 388,800
  const size_t offStats = offProbs + 390400;         // SP 4800 | sump 4800 | tsum 1600
  const size_t needNew  = offStats + 11200;

  if (ws_size >= needNew) {
    uchar* Tg    = (uchar*)(ws + offT);
    ushort* part = (ushort*)(ws + offPart);
    float* probs = (float*)(ws + offProbs);
    float* SP    = (float*)(ws + offStats);
    float* sump  = (float*)(ws + offStats + 4800);
    float* tsum  = (float*)(ws + offStats + 9600);

    hipMemsetAsync(SP, 0, 11200, stream);   // SP + sump + tsum
    resize2<<<dim3(M_TGT, 20), 256, 0, stream>>>(tmasks, Tg, tsum);
    probs_kernel<<<N_PRED, 64, 0, stream>>>(logits, probs);
    gemm_mega<<<NBLK * KZN, 512, 0, stream>>>(pmasks, Tg, part, SP, sump);
    combine2<<<1875, 256, 0, stream>>>(part, SP, sump, tsum, probs,
                                       pboxes, tboxes, tids, out);
  } else {
    // fallback (R4 pipeline)
    ushort* T     = (ushort*)ws;
    float*  probs = (float*)(ws + 20480000);
    float*  S     = (float*)(ws + 20868800);
    float*  sump  = (float*)(ws + 20873600);
    float*  tsum  = (float*)(ws + 20878400);
    ushort* part1 = (ushort*)(ws + 20880000);
    size_t need8 = 20880000ull + 2ull * 8 * 480000 * 2;
    int KZf = (ws_size >= need8) ? 8 : 1;
    ushort* part2 = part1 + (size_t)KZf * 480000;

    hipMemsetAsync(tsum, 0, M_TGT * sizeof(float), stream);
    resize_lin<<<dim3(M_TGT, 100), 256, 0, stream>>>(tmasks, T, tsum);
    probs_kernel<<<N_PRED, 64, 0, stream>>>(logits, probs);
    stats_kernel<<<N_PRED, 256, 0, stream>>>(pmasks, S, sump);
    gemm_fused<<<dim3(19, 7, KZf), 256, 0, stream>>>(pmasks, T, part1, part2, KDIM / KZf);
    combine_fb<<<1875, 256, 0, stream>>>(part1, part2, S, sump, tsum, probs,
                                         pboxes, tboxes, tids, out, KZf);
  }
}

// Round 14
// 141.593 us; speedup vs baseline: 4.2094x; 1.0785x over previous
//
#include <hip/hip_runtime.h>
#include <cstdint>

#define N_PRED 1200
#define M_TGT  400
#define KDIM   25600   // 160*160
#define NCLS   81
#define MPAD   448     // padded target count (28 x 16)
#define KZN    25      // split-K factor
#define NBLK   38      // row blocks of 32 (1216 >= 1200)
#define STEPS  16      // K-steps (BK=64) per block: 25*16*64 = 25600
#define TSLICE 28672   // BYTES per BK=64 step: 8(kq) * 448 * 8 fp8

typedef __attribute__((ext_vector_type(8)))  short bf16x8;
typedef __attribute__((ext_vector_type(4)))  float f32x4;
typedef unsigned char uchar;

__device__ __forceinline__ ushort f2bf(float f) {
  union { float f; uint32_t u; } v; v.f = f;
  uint32_t u = v.u + 0x7fffu + ((v.u >> 16) & 1u);
  return (ushort)(u >> 16);
}

__device__ __forceinline__ float bf2f(ushort s) {
  union { uint32_t u; float f; } v; v.u = ((uint32_t)s) << 16;
  return v.f;
}

// pack 4 f32 -> 4 fp8 e4m3 (OCP, saturating) in one u32
__device__ __forceinline__ uint32_t pk_fp8(float a, float b, float c, float d) {
  uint32_t v = (uint32_t)__builtin_amdgcn_cvt_pk_fp8_f32(a, b, 0, false);
  v = (uint32_t)__builtin_amdgcn_cvt_pk_fp8_f32(c, d, (int)v, true);
  return v;
}

__device__ __forceinline__ void gll16(const void* g, void* l) {
  __builtin_amdgcn_global_load_lds(
      (const __attribute__((address_space(1))) void*)g,
      (__attribute__((address_space(3))) void*)l, 16, 0, 0);
}

// =====================================================================
// Resize tgt_masks [400,256,256] -> T fp8 fragment-major: [kt(400)][kq(8)][m(448)][8]
__global__ __launch_bounds__(256) void resize2(const float* __restrict__ tm,
                                               uchar* __restrict__ T,
                                               float* __restrict__ tsum) {
  __shared__ float rows[16][256];
  __shared__ float vbuf[8][256];

  int m = blockIdx.x, yt = blockIdx.y;  // yt 0..19
  int y0 = yt * 8;
  int t = threadIdx.x;

  int jbase = (int)ceilf((y0 + 0.5f) * 1.6f - 2.1f);

  const float* base = tm + (size_t)m * 65536;
  {
    int r = t >> 4;
    int c0 = (t & 15) * 16;
    int jr = min(max(jbase + r, 0), 255);
    const float4* src = reinterpret_cast<const float4*>(base + jr * 256 + c0);
#pragma unroll
    for (int i = 0; i < 4; ++i)
      *reinterpret_cast<float4*>(&rows[r][c0 + i * 4]) = src[i];
  }
  __syncthreads();

#pragma unroll
  for (int yy = 0; yy < 8; ++yy) {
    int y = y0 + yy;
    float s = (y + 0.5f) * 1.6f - 0.5f;
    int j0 = (int)ceilf(s - 1.6f);
    float w[4]; float wsum = 0.f;
#pragma unroll
    for (int a = 0; a < 4; ++a) {
      int j = j0 + a;
      float wv = fmaxf(0.f, 1.f - fabsf((float)j - s) * 0.625f);
      if (j < 0 || j > 255) wv = 0.f;
      w[a] = wv; wsum += wv;
    }
    float winv = __builtin_amdgcn_rcpf(wsum);
    float acc = 0.f;
    int rbase = j0 - jbase;
#pragma unroll
    for (int a = 0; a < 4; ++a) acc += w[a] * rows[rbase + a][t];
    vbuf[yy][t] = acc * winv;
  }
  __syncthreads();

  float bsum = 0.f;
  if (t < 160) {
    int yy = t / 20, ch = t - yy * 20;
    float o[8];
#pragma unroll
    for (int j = 0; j < 8; ++j) {
      int x = ch * 8 + j;
      float sx = (x + 0.5f) * 1.6f - 0.5f;
      int jx0 = (int)ceilf(sx - 1.6f);
      float wsum = 0.f, h = 0.f;
#pragma unroll
      for (int b = 0; b < 4; ++b) {
        int jj = jx0 + b;
        float wv = fmaxf(0.f, 1.f - fabsf((float)jj - sx) * 0.625f);
        if (jj < 0 || jj > 255) wv = 0.f;
        wsum += wv;
        h += wv * vbuf[yy][min(max(jj, 0), 255)];
      }
      h *= __builtin_amdgcn_rcpf(wsum);
      o[j] = h; bsum += h;
    }
    int p0 = (y0 + yy) * 160 + ch * 8;
    int kt = p0 >> 6, kq = (p0 >> 3) & 7;
    size_t a = ((size_t)(kt * 8 + kq) * MPAD + m) * 8;
    uint2 pk;
    pk.x = pk_fp8(o[0], o[1], o[2], o[3]);
    pk.y = pk_fp8(o[4], o[5], o[6], o[7]);
    *reinterpret_cast<uint2*>(&T[a]) = pk;
  }
#pragma unroll
  for (int o2 = 32; o2 > 0; o2 >>= 1) bsum += __shfl_down(bsum, o2, 64);
  __shared__ float red[4];
  int wid = t >> 6;
  if ((t & 63) == 0) red[wid] = bsum;
  __syncthreads();
  if (t == 0) atomicAdd(&tsum[m], red[0] + red[1] + red[2] + red[3]);
}

// =====================================================================
// Fused dual GEMM (fp8 e4m3) + one-shot conversion + row stats. BK=64:
// 16 fat steps (28 MFMA/wave/step) halve the per-step barrier overhead.
// 1-barrier dbuf parity scheme: step S reads buf[S&1]; stage(S+1)->buf^1
// issued right after the barrier; A f32 loads issued a full iteration early.
// waves 0-3 stage B (7 gll16/thread), waves 4-7 load+convert A; all do MFMA.
// LDS 65 KB -> 2 blocks/CU.
__global__ __launch_bounds__(512, 4) void gemm_mega(
    const float* __restrict__ pm, const uchar* __restrict__ Tg,
    ushort* __restrict__ part, float* __restrict__ SP, float* __restrict__ sump) {
  __shared__ uchar buf[2][TSLICE];        // 57,344 B
  __shared__ uchar abuf[2][2][32 * 72];   //  9,216 B (72-byte padded rows)

  // bijective XCD swizzle (m204): nwg=950, q=118, r=6; kz-major chunks
  int orig = blockIdx.x;
  int xcd = orig & 7, base = orig >> 3;
  int wgid = (xcd < 6 ? xcd * 119 : 714 + (xcd - 6) * 118) + base;
  int kz = wgid / NBLK;
  int bn = wgid - kz * NBLK;

  int t = threadIdx.x, lane = t & 63, w = t >> 6;
  int rg = w >> 2, cg = w & 3;
  int l15 = lane & 15, kq = lane >> 4;

  bool is_b = (t < 256);
  bool is_a = (t >= 256);

  int at = t & 255;
  int arow = at >> 3, kf = at & 7;       // row 0..31, 8-float chunk 0..7
  int rowA = bn * 32 + arow;
  int rowAc = min(rowA, N_PRED - 1);
  const float* apf = pm + (size_t)rowAc * KDIM + kz * (STEPS * 64) + kf * 8;
  int awoff = arow * 72 + kf * 8;        // BYTES within abuf[ni][arr]

  const uchar* tsrc = Tg + (size_t)(kz * STEPS) * TSLICE;
  int bbase = (kq * MPAD + cg * 112 + l15) * 8;      // B frag (byte idx), +h*14336
  int afbase = (rg * 16 + l15) * 72 + kq * 8;        // A frag (byte idx), +h*32

  f32x4 z = {0.f, 0.f, 0.f, 0.f};
  f32x4 acc1[7], acc2[7];
#pragma unroll
  for (int j = 0; j < 7; ++j) { acc1[j] = z; acc2[j] = z; }
  float stx = 0.f, stp = 0.f;

  union fragu { uint2 u; long long l; };

#define WAITV(N) asm volatile("s_waitcnt vmcnt(" #N ")" ::: "memory")

// stage step ST into buf[BI]: 28 chunks x 1KB; 7 gll16 per staging thread.
#define STAGE_B(BI, ST)                                                        \
  do {                                                                         \
    const uchar* s_ = tsrc + (size_t)(ST) * TSLICE;                            \
    _Pragma("unroll")                                                          \
    for (int i_ = 0; i_ < 7; ++i_) {                                           \
      int c_ = w * 7 + i_;                                                     \
      gll16(s_ + c_ * 1024 + lane * 16, &buf[BI][c_ * 1024]);                  \
    }                                                                          \
  } while (0)

// convert 8 f32 (V0,V1) -> fp8 x/p bytes + stats, write uint2 each array.
#define CONVERT(NI, V0, V1)                                                    \
  do {                                                                         \
    float xs_[8] = {V0.x, V0.y, V0.z, V0.w, V1.x, V1.y, V1.z, V1.w};           \
    uint32_t xw_[2], pw_[2];                                                   \
    _Pragma("unroll")                                                          \
    for (int h_ = 0; h_ < 2; ++h_) {                                           \
      float sg_[4];                                                            \
      _Pragma("unroll")                                                        \
      for (int q_ = 0; q_ < 4; ++q_) {                                         \
        float a_ = xs_[h_ * 4 + q_];                                           \
        float e_ = __expf(-fabsf(a_));                                         \
        float o_ = 1.f + e_;                                                   \
        float i_ = __builtin_amdgcn_rcpf(o_);                                  \
        sg_[q_] = (a_ >= 0.f) ? i_ : e_ * i_;                                  \
        stp += sg_[q_];                                                        \
        stx += fmaxf(a_, 0.f) + __logf(o_);                                    \
      }                                                                        \
      xw_[h_] = pk_fp8(xs_[h_ * 4], xs_[h_ * 4 + 1], xs_[h_ * 4 + 2], xs_[h_ * 4 + 3]); \
      pw_[h_] = pk_fp8(sg_[0], sg_[1], sg_[2], sg_[3]);                        \
    }                                                                          \
    *reinterpret_cast<uint2*>(&abuf[NI][0][awoff]) = make_uint2(xw_[0], xw_[1]); \
    *reinterpret_cast<uint2*>(&abuf[NI][1][awoff]) = make_uint2(pw_[0], pw_[1]); \
  } while (0)

// ACUR = S&1 (compile-time). f(k): fA* when k even, fB* when k odd.
#define ITER(ACUR, S)                                                          \
  do {                                                                         \
    if (is_a && (S) + 2 < STEPS) {  /* issue A load for S+2 (same parity) */   \
      float4 n0_ = *reinterpret_cast<const float4*>(apf + ((S) + 2) * 64);     \
      float4 n1_ = *reinterpret_cast<const float4*>(apf + ((S) + 2) * 64 + 4); \
      if (ACUR) { fB0 = n0_; fB1 = n1_; } else { fA0 = n0_; fA1 = n1_; }       \
    }                                                                          \
    if (is_b) WAITV(0);             /* stage(S) issued a full step ago */      \
    __builtin_amdgcn_s_barrier();                                              \
    __builtin_amdgcn_sched_barrier(0);                                         \
    if ((S) + 1 < STEPS) {                                                     \
      if (is_b) STAGE_B(ACUR ^ 1, (S) + 1);                                    \
      if (is_a) { if (ACUR) CONVERT(0, fA0, fA1); else CONVERT(1, fB0, fB1); } \
    }                                                                          \
    _Pragma("unroll")                                                          \
    for (int h_ = 0; h_ < 2; ++h_) {                                           \
      fragu ax_, ap_;                                                          \
      ax_.u = *reinterpret_cast<const uint2*>(&abuf[ACUR][0][afbase + h_ * 32]); \
      ap_.u = *reinterpret_cast<const uint2*>(&abuf[ACUR][1][afbase + h_ * 32]); \
      __builtin_amdgcn_s_setprio(1);                                           \
      _Pragma("unroll")                                                        \
      for (int j_ = 0; j_ < 7; ++j_) {                                         \
        fragu bv_;                                                             \
        bv_.u = *reinterpret_cast<const uint2*>(                               \
            &buf[ACUR][bbase + h_ * 14336 + j_ * 128]);                        \
        acc1[j_] = __builtin_amdgcn_mfma_f32_16x16x32_fp8_fp8(ax_.l, bv_.l, acc1[j_], 0, 0, 0); \
        acc2[j_] = __builtin_amdgcn_mfma_f32_16x16x32_fp8_fp8(ap_.l, bv_.l, acc2[j_], 0, 0, 0); \
      }                                                                        \
      __builtin_amdgcn_s_setprio(0);                                           \
    }                                                                          \
    asm volatile("s_waitcnt lgkmcnt(0)" ::: "memory");                         \
  } while (0)

  // ---- prologue: stage(0)->buf0; A: f(0) converted->abuf0, f(1)->fB ----
  float4 fA0, fA1, fB0, fB1;
  if (is_b) STAGE_B(0, 0);
  if (is_a) {
    float4 f00 = *reinterpret_cast<const float4*>(apf);
    float4 f01 = *reinterpret_cast<const float4*>(apf + 4);
    fB0 = *reinterpret_cast<const float4*>(apf + 64);
    fB1 = *reinterpret_cast<const float4*>(apf + 68);
    CONVERT(0, f00, f01);
  }
  asm volatile("s_waitcnt lgkmcnt(0)" ::: "memory");

  for (int s = 0; s < STEPS; s += 2) {
    ITER(0, s);
    ITER(1, s + 1);
  }
#undef ITER
#undef CONVERT
#undef STAGE_B
#undef WAITV

  // ---- row stats: 8 A-threads per row, xor-reduce width 8 ----
  if (is_a) {
    stx += __shfl_xor(stx, 1, 8); stx += __shfl_xor(stx, 2, 8); stx += __shfl_xor(stx, 4, 8);
    stp += __shfl_xor(stp, 1, 8); stp += __shfl_xor(stp, 2, 8); stp += __shfl_xor(stp, 4, 8);
    if ((at & 7) == 0 && rowA < N_PRED) {
      atomicAdd(SP + rowA, stx);
      atomicAdd(sump + rowA, stp);
    }
  }

  // ---- store bf16 partials: part[arr][n][kz][MPAD] ----
  ushort* p1 = part;
  ushort* p2 = part + (size_t)KZN * 1200 * MPAD;
#pragma unroll
  for (int j = 0; j < 7; ++j)
#pragma unroll
    for (int rr = 0; rr < 4; ++rr) {
      int gn = bn * 32 + rg * 16 + kq * 4 + rr;   // C/D: row=(lane>>4)*4+reg
      if (gn < N_PRED) {
        int gm = cg * 112 + j * 16 + l15;         // col=lane&15
        size_t o = ((size_t)gn * KZN + kz) * MPAD + gm;
        p1[o] = f2bf(acc1[j][rr]);
        p2[o] = f2bf(acc2[j][rr]);
      }
    }
}

// ---------------- softmax probs [1200,81] ----------------
__global__ void probs_kernel(const float* __restrict__ logits, float* __restrict__ probs) {
  int n = blockIdx.x;
  int l = threadIdx.x;
  const float* row = logits + n * NCLS;
  float v0 = row[l];
  bool has2 = (l + 64) < NCLS;
  float v1 = has2 ? row[l + 64] : -3.4e38f;
  float mx = fmaxf(v0, v1);
#pragma unroll
  for (int o = 1; o < 64; o <<= 1) mx = fmaxf(mx, __shfl_xor(mx, o, 64));
  float e0 = expf(v0 - mx);
  float e1 = has2 ? expf(v1 - mx) : 0.f;
  float sm = e0 + e1;
#pragma unroll
  for (int o = 1; o < 64; o <<= 1) sm += __shfl_xor(sm, o, 64);
  float inv = 1.f / sm;
  probs[n * NCLS + l] = e0 * inv;
  if (has2) probs[n * NCLS + l + 64] = e1 * inv;
}

// ---------------- final combine (bf16 partials, [n][kz][MPAD] layout) ----------------
__global__ void combine2(const ushort* __restrict__ part,
                         const float* __restrict__ SP, const float* __restrict__ sump,
                         const float* __restrict__ tsum, const float* __restrict__ probs,
                         const float* __restrict__ pboxes, const float* __restrict__ tboxes,
                         const int* __restrict__ tids, float* __restrict__ out) {
  int idx = blockIdx.x * 256 + threadIdx.x;   // < 480000
  int n = idx / M_TGT;
  int m = idx - n * M_TGT;

  const ushort* p1 = part + (size_t)n * (KZN * MPAD) + m;
  const ushort* p2 = p1 + (size_t)KZN * 1200 * MPAD;
  float A1 = 0.f, A2 = 0.f;
  for (int kz = 0; kz < KZN; ++kz) {
    A1 += bf2f(p1[kz * MPAD]);
    A2 += bf2f(p2[kz * MPAD]);
  }
  float cm = (SP[n] - A1) * (1.0f / (float)KDIM);
  float cd = 1.f - (2.f * A2 + 1e-5f) / (sump[n] + tsum[m] + 1e-5f);
  float cc = -probs[n * NCLS + tids[m]];

  float4 pb = reinterpret_cast<const float4*>(pboxes)[n];
  float4 tb = reinterpret_cast<const float4*>(tboxes)[m];
  float l1 = fabsf(pb.x - tb.x) + fabsf(pb.y - tb.y) + fabsf(pb.z - tb.z) + fabsf(pb.w - tb.w);
  float px1 = pb.x - 0.5f * pb.z, py1 = pb.y - 0.5f * pb.w;
  float px2 = pb.x + 0.5f * pb.z, py2 = pb.y + 0.5f * pb.w;
  float tx1 = tb.x - 0.5f * tb.z, ty1 = tb.y - 0.5f * tb.w;
  float tx2 = tb.x + 0.5f * tb.z, ty2 = tb.y + 0.5f * tb.w;
  float a1 = (px2 - px1) * (py2 - py1);
  float a2 = (tx2 - tx1) * (ty2 - ty1);
  float iw = fmaxf(fminf(px2, tx2) - fmaxf(px1, tx1), 0.f);
  float ih = fmaxf(fminf(py2, ty2) - fmaxf(py1, ty1), 0.f);
  float inter = iw * ih;
  float uni = a1 + a2 - inter;
  float iou = inter / uni;
  float ew = fmaxf(fmaxf(px2, tx2) - fminf(px1, tx1), 0.f);
  float eh = fmaxf(fmaxf(py2, ty2) - fminf(py1, ty1), 0.f);
  float ae = ew * eh;
  float giou = iou - (ae - uni) / ae;

  out[idx] = 5.f * l1 + 2.f * (-giou) + 2.f * cc + 5.f * cm + 5.f * cd;
}

// =====================================================================
// FALLBACK PATH (only if ws too small)
// =====================================================================

__device__ __forceinline__ float sigf(float x) {
  return 1.f / (1.f + __expf(-x));
}

__global__ void resize_lin(const float* __restrict__ tm, ushort* __restrict__ T,
                           float* __restrict__ tsum) {
  int m = blockIdx.x;
  int p = blockIdx.y * 256 + threadIdx.x;
  int y = p / 160;
  int x = p - y * 160;
  float wy[4], wx[4];
  int jy0, jx0;
  {
    float s = (y + 0.5f) * 1.6f - 0.5f;
    jy0 = (int)ceilf(s - 1.6f);
    float ws = 0.f;
#pragma unroll
    for (int a = 0; a < 4; ++a) {
      int j = jy0 + a;
      float w = fmaxf(0.f, 1.f - fabsf((float)j - s) * 0.625f);
      if (j < 0 || j > 255) w = 0.f;
      wy[a] = w; ws += w;
    }
    float inv = 1.f / ws;
#pragma unroll
    for (int a = 0; a < 4; ++a) wy[a] *= inv;
  }
  {
    float s = (x + 0.5f) * 1.6f - 0.5f;
    jx0 = (int)ceilf(s - 1.6f);
    float ws = 0.f;
#pragma unroll
    for (int b = 0; b < 4; ++b) {
      int j = jx0 + b;
      float w = fmaxf(0.f, 1.f - fabsf((float)j - s) * 0.625f);
      if (j < 0 || j > 255) w = 0.f;
      wx[b] = w; ws += w;
    }
    float inv = 1.f / ws;
#pragma unroll
    for (int b = 0; b < 4; ++b) wx[b] *= inv;
  }
  const float* base = tm + (size_t)m * 65536;
  float acc = 0.f;
#pragma unroll
  for (int a = 0; a < 4; ++a) {
    int jy = min(max(jy0 + a, 0), 255);
    float wya = wy[a];
#pragma unroll
    for (int b = 0; b < 4; ++b) {
      int jx = min(max(jx0 + b, 0), 255);
      acc += wya * wx[b] * base[jy * 256 + jx];
    }
  }
  T[(size_t)m * KDIM + p] = f2bf(acc);
  float v = acc;
#pragma unroll
  for (int o = 32; o > 0; o >>= 1) v += __shfl_down(v, o, 64);
  __shared__ float red[4];
  int wid = threadIdx.x >> 6;
  if ((threadIdx.x & 63) == 0) red[wid] = v;
  __syncthreads();
  if (threadIdx.x == 0) atomicAdd(&tsum[m], red[0] + red[1] + red[2] + red[3]);
}

__global__ void stats_kernel(const float* __restrict__ pm, float* __restrict__ S,
                             float* __restrict__ sump) {
  int n = blockIdx.x;
  const float4* row = reinterpret_cast<const float4*>(pm + (size_t)n * KDIM);
  float ssp = 0.f, sp = 0.f;
  for (int i = threadIdx.x; i < KDIM / 4; i += 256) {
    float4 v = row[i];
    float xs[4] = {v.x, v.y, v.z, v.w};
#pragma unroll
    for (int j = 0; j < 4; ++j) {
      float x = xs[j];
      float e = __expf(-fabsf(x));
      float inv1pe = 1.f / (1.f + e);
      sp += (x >= 0.f) ? inv1pe : e * inv1pe;
      ssp += fmaxf(x, 0.f) + log1pf(e);
    }
  }
#pragma unroll
  for (int o = 32; o > 0; o >>= 1) {
    ssp += __shfl_down(ssp, o, 64);
    sp  += __shfl_down(sp, o, 64);
  }
  __shared__ float red[8];
  int wid = threadIdx.x >> 6;
  if ((threadIdx.x & 63) == 0) { red[wid] = ssp; red[4 + wid] = sp; }
  __syncthreads();
  if (threadIdx.x == 0) {
    S[n]    = -(red[0] + red[1] + red[2] + red[3]);
    sump[n] = red[4] + red[5] + red[6] + red[7];
  }
}

__device__ __forceinline__ bf16x8 load_frag_lin(const ushort* p) {
  union { ushort4 u[2]; bf16x8 f; } fr;
  fr.u[0] = *reinterpret_cast<const ushort4*>(p);
  fr.u[1] = *reinterpret_cast<const ushort4*>(p + 4);
  return fr.f;
}

__global__ __launch_bounds__(256) void gemm_fused(
    const float* __restrict__ pm, const ushort* __restrict__ T,
    ushort* __restrict__ part1, ushort* __restrict__ part2, int k_per) {
  __shared__ ushort Ax[64][40];
  __shared__ ushort Ap[64][40];
  __shared__ ushort Bs[64][40];
  int n0 = blockIdx.x * 64;
  int m0 = blockIdx.y * 64;
  int kz = blockIdx.z;
  int k_begin = kz * k_per;
  int t = threadIdx.x;
  int r = t >> 2;
  int q = t & 3;
  bool a_ok = (n0 + r) < N_PRED;
  bool b_ok = (m0 + r) < M_TGT;
  const float*  pA = pm + (size_t)(n0 + r) * KDIM + k_begin + q * 8;
  const ushort* pB = T  + (size_t)(m0 + r) * KDIM + k_begin + q * 8;
  int lane = t & 63;
  int w = t >> 6;
  int wr = (w >> 1) * 32;
  int wc = (w & 1) * 32;
  int lrow = lane & 15;
  int kc = (lane >> 4) * 8;
  f32x4 zero = {0.f, 0.f, 0.f, 0.f};
  f32x4 acc1[2][2] = {{zero, zero}, {zero, zero}};
  f32x4 acc2[2][2] = {{zero, zero}, {zero, zero}};
  int steps = k_per / 32;
  for (int kt = 0; kt < steps; ++kt) {
    __syncthreads();
    float4 f0 = {0.f,0.f,0.f,0.f}, f1 = {0.f,0.f,0.f,0.f};
    if (a_ok) {
      f0 = *reinterpret_cast<const float4*>(pA);
      f1 = *reinterpret_cast<const float4*>(pA + 4);
    }
    pA += 32;
    ushort4 xa, xb, pa, pb4;
    xa.x = f2bf(f0.x); xa.y = f2bf(f0.y); xa.z = f2bf(f0.z); xa.w = f2bf(f0.w);
    xb.x = f2bf(f1.x); xb.y = f2bf(f1.y); xb.z = f2bf(f1.z); xb.w = f2bf(f1.w);
    pa.x = f2bf(sigf(f0.x)); pa.y = f2bf(sigf(f0.y)); pa.z = f2bf(sigf(f0.z)); pa.w = f2bf(sigf(f0.w));
    pb4.x = f2bf(sigf(f1.x)); pb4.y = f2bf(sigf(f1.y)); pb4.z = f2bf(sigf(f1.z)); pb4.w = f2bf(sigf(f1.w));
    *reinterpret_cast<ushort4*>(&Ax[r][q * 8])     = xa;
    *reinterpret_cast<ushort4*>(&Ax[r][q * 8 + 4]) = xb;
    *reinterpret_cast<ushort4*>(&Ap[r][q * 8])     = pa;
    *reinterpret_cast<ushort4*>(&Ap[r][q * 8 + 4]) = pb4;
    union { uint4 u; ushort4 s[2]; } bv;
    bv.u = make_uint4(0, 0, 0, 0);
    if (b_ok) bv.u = *reinterpret_cast<const uint4*>(pB);
    pB += 32;
    *reinterpret_cast<ushort4*>(&Bs[r][q * 8])     = bv.s[0];
    *reinterpret_cast<ushort4*>(&Bs[r][q * 8 + 4]) = bv.s[1];
    __syncthreads();
    bf16x8 ax[2], ap[2], bb[2];
#pragma unroll
    for (int i = 0; i < 2; ++i) {
      ax[i] = load_frag_lin(&Ax[wr + i * 16 + lrow][kc]);
      ap[i] = load_frag_lin(&Ap[wr + i * 16 + lrow][kc]);
      bb[i] = load_frag_lin(&Bs[wc + i * 16 + lrow][kc]);
    }
#pragma unroll
    for (int i = 0; i < 2; ++i)
#pragma unroll
      for (int j = 0; j < 2; ++j) {
        acc1[i][j] = __builtin_amdgcn_mfma_f32_16x16x32_bf16(ax[i], bb[j], acc1[i][j], 0, 0, 0);
        acc2[i][j] = __builtin_amdgcn_mfma_f32_16x16x32_bf16(ap[i], bb[j], acc2[i][j], 0, 0, 0);
      }
  }
  int rowb = (lane >> 4) * 4;
  int col = lane & 15;
#pragma unroll
  for (int i = 0; i < 2; ++i)
#pragma unroll
    for (int j = 0; j < 2; ++j)
#pragma unroll
      for (int rr = 0; rr < 4; ++rr) {
        int gn = n0 + wr + i * 16 + rowb + rr;
        int gm = m0 + wc + j * 16 + col;
        if (gn < N_PRED && gm < M_TGT) {
          size_t o = (size_t)kz * 480000 + (size_t)gn * 400 + gm;
          part1[o] = f2bf(acc1[i][j][rr]);
          part2[o] = f2bf(acc2[i][j][rr]);
        }
      }
}

__global__ void combine_fb(const ushort* __restrict__ part1, const ushort* __restrict__ part2,
                           const float* __restrict__ S, const float* __restrict__ sump,
                           const float* __restrict__ tsum, const float* __restrict__ probs,
                           const float* __restrict__ pboxes, const float* __restrict__ tboxes,
                           const int* __restrict__ tids, float* __restrict__ out, int KZ) {
  int idx = blockIdx.x * 256 + threadIdx.x;
  int n = idx / M_TGT;
  int m = idx - n * M_TGT;
  float A1 = 0.f, A2 = 0.f;
  for (int kz = 0; kz < KZ; ++kz) {
    A1 += bf2f(part1[(size_t)kz * 480000 + idx]);
    A2 += bf2f(part2[(size_t)kz * 480000 + idx]);
  }
  float cm = -(A1 + S[n]) * (1.0f / (float)KDIM);
  float cd = 1.f - (2.f * A2 + 1e-5f) / (sump[n] + tsum[m] + 1e-5f);
  float cc = -probs[n * NCLS + tids[m]];
  float4 pb = reinterpret_cast<const float4*>(pboxes)[n];
  float4 tb = reinterpret_cast<const float4*>(tboxes)[m];
  float l1 = fabsf(pb.x - tb.x) + fabsf(pb.y - tb.y) + fabsf(pb.z - tb.z) + fabsf(pb.w - tb.w);
  float px1 = pb.x - 0.5f * pb.z, py1 = pb.y - 0.5f * pb.w;
  float px2 = pb.x + 0.5f * pb.z, py2 = pb.y + 0.5f * pb.w;
  float tx1 = tb.x - 0.5f * tb.z, ty1 = tb.y - 0.5f * tb.w;
  float tx2 = tb.x + 0.5f * tb.z, ty2 = tb.y + 0.5f * tb.w;
  float a1 = (px2 - px1) * (py2 - py1);
  float a2 = (tx2 - tx1) * (ty2 - ty1);
  float iw = fmaxf(fminf(px2, tx2) - fmaxf(px1, tx1), 0.f);
  float ih = fmaxf(fminf(py2, ty2) - fmaxf(py1, ty1), 0.f);
  float inter = iw * ih;
  float uni = a1 + a2 - inter;
  float iou = inter / uni;
  float ew = fmaxf(fmaxf(px2, tx2) - fminf(px1, tx1), 0.f);
  float eh = fmaxf(fmaxf(py2, ty2) - fminf(py1, ty1), 0.f);
  float ae = ew * eh;
  float giou = iou - (ae - uni) / ae;
  out[idx] = 5.f * l1 + 2.f * (-giou) + 2.f * cc + 5.f * cm + 5.f * cd;
}

// =====================================================================

extern "C" void kernel_launch(void* const* d_in, const int* in_sizes, int n_in,
                              void* d_out, int out_size, void* d_ws, size_t ws_size,
                              hipStream_t stream) {
  const float* logits = (const float*)d_in[0];
  const float* pboxes = (const float*)d_in[1];
  const float* pmasks = (const float*)d_in[2];
  const float* tboxes = (const float*)d_in[3];
  const float* tmasks = (const float*)d_in[4];
  const int*   tids   = (const int*)d_in[5];
  float* out = (float*)d_out;
  char* ws = (char*)d_ws;

  // new-path workspace layout
  const size_t offT     = 0;                         // 400*28672 = 11,468,800 (fp8)
  const size_t offPart  = 24371200;                  // 2*25*1200*448*2 = 53,760,000
  const size_t offProbs = offPart + 53760000;        // 388,800
  const size_t offStats = offProbs + 390400;         // SP 4800 | sump 4800 | tsum 1600
  const size_t needNew  = offStats + 11200;

  if (ws_size >= needNew) {
    uchar* Tg    = (uchar*)(ws + offT);
    ushort* part = (ushort*)(ws + offPart);
    float* probs = (float*)(ws + offProbs);
    float* SP    = (float*)(ws + offStats);
    float* sump  = (float*)(ws + offStats + 4800);
    float* tsum  = (float*)(ws + offStats + 9600);

    hipMemsetAsync(SP, 0, 11200, stream);   // SP + sump + tsum
    resize2<<<dim3(M_TGT, 20), 256, 0, stream>>>(tmasks, Tg, tsum);
    probs_kernel<<<N_PRED, 64, 0, stream>>>(logits, probs);
    gemm_mega<<<NBLK * KZN, 512, 0, stream>>>(pmasks, Tg, part, SP, sump);
    combine2<<<1875, 256, 0, stream>>>(part, SP, sump, tsum, probs,
                                       pboxes, tboxes, tids, out);
  } else {
    // fallback (R4 pipeline)
    ushort* T     = (ushort*)ws;
    float*  probs = (float*)(ws + 20480000);
    float*  S     = (float*)(ws + 20868800);
    float*  sump  = (float*)(ws + 20873600);
    float*  tsum  = (float*)(ws + 20878400);
    ushort* part1 = (ushort*)(ws + 20880000);
    size_t need8 = 20880000ull + 2ull * 8 * 480000 * 2;
    int KZf = (ws_size >= need8) ? 8 : 1;
    ushort* part2 = part1 + (size_t)KZf * 480000;

    hipMemsetAsync(tsum, 0, M_TGT * sizeof(float), stream);
    resize_lin<<<dim3(M_TGT, 100), 256, 0, stream>>>(tmasks, T, tsum);
    probs_kernel<<<N_PRED, 64, 0, stream>>>(logits, probs);
    stats_kernel<<<N_PRED, 256, 0, stream>>>(pmasks, S, sump);
    gemm_fused<<<dim3(19, 7, KZf), 256, 0, stream>>>(pmasks, T, part1, part2, KDIM / KZf);
    combine_fb<<<1875, 256, 0, stream>>>(part1, part2, S, sump, tsum, probs,
                                         pboxes, tboxes, tids, out, KZf);
  }
}

// Round 15
// 139.297 us; speedup vs baseline: 4.2788x; 1.0165x over previous
//
#include <hip/hip_runtime.h>
#include <cstdint>

#define N_PRED 1200
#define M_TGT  400
#define KDIM   25600   // 160*160
#define NCLS   81
#define MPAD   448     // padded target count (28 x 16)
#define KZN    20      // split-K factor
#define NBLK   38      // row blocks of 32 (1216 >= 1200)
#define STEPS  20      // K-steps (BK=64) per block: 20*20*64 = 25600
#define TSLICE 28672   // BYTES per BK=64 step: 8(kq) * 448 * 8 fp8

typedef __attribute__((ext_vector_type(8)))  short bf16x8;
typedef __attribute__((ext_vector_type(4)))  float f32x4;
typedef unsigned char uchar;

__device__ __forceinline__ ushort f2bf(float f) {
  union { float f; uint32_t u; } v; v.f = f;
  uint32_t u = v.u + 0x7fffu + ((v.u >> 16) & 1u);
  return (ushort)(u >> 16);
}

__device__ __forceinline__ float bf2f(ushort s) {
  union { uint32_t u; float f; } v; v.u = ((uint32_t)s) << 16;
  return v.f;
}

// pack 4 f32 -> 4 fp8 e4m3 (OCP, saturating) in one u32
__device__ __forceinline__ uint32_t pk_fp8(float a, float b, float c, float d) {
  uint32_t v = (uint32_t)__builtin_amdgcn_cvt_pk_fp8_f32(a, b, 0, false);
  v = (uint32_t)__builtin_amdgcn_cvt_pk_fp8_f32(c, d, (int)v, true);
  return v;
}

__device__ __forceinline__ void gll16(const void* g, void* l) {
  __builtin_amdgcn_global_load_lds(
      (const __attribute__((address_space(1))) void*)g,
      (__attribute__((address_space(3))) void*)l, 16, 0, 0);
}

// =====================================================================
// Resize tgt_masks [400,256,256] -> T fp8 fragment-major: [kt(400)][kq(8)][m(448)][8]
__global__ __launch_bounds__(256) void resize2(const float* __restrict__ tm,
                                               uchar* __restrict__ T,
                                               float* __restrict__ tsum) {
  __shared__ float rows[16][256];
  __shared__ float vbuf[8][256];

  int m = blockIdx.x, yt = blockIdx.y;  // yt 0..19
  int y0 = yt * 8;
  int t = threadIdx.x;

  int jbase = (int)ceilf((y0 + 0.5f) * 1.6f - 2.1f);

  const float* base = tm + (size_t)m * 65536;
  {
    int r = t >> 4;
    int c0 = (t & 15) * 16;
    int jr = min(max(jbase + r, 0), 255);
    const float4* src = reinterpret_cast<const float4*>(base + jr * 256 + c0);
#pragma unroll
    for (int i = 0; i < 4; ++i)
      *reinterpret_cast<float4*>(&rows[r][c0 + i * 4]) = src[i];
  }
  __syncthreads();

#pragma unroll
  for (int yy = 0; yy < 8; ++yy) {
    int y = y0 + yy;
    float s = (y + 0.5f) * 1.6f - 0.5f;
    int j0 = (int)ceilf(s - 1.6f);
    float w[4]; float wsum = 0.f;
#pragma unroll
    for (int a = 0; a < 4; ++a) {
      int j = j0 + a;
      float wv = fmaxf(0.f, 1.f - fabsf((float)j - s) * 0.625f);
      if (j < 0 || j > 255) wv = 0.f;
      w[a] = wv; wsum += wv;
    }
    float winv = __builtin_amdgcn_rcpf(wsum);
    float acc = 0.f;
    int rbase = j0 - jbase;
#pragma unroll
    for (int a = 0; a < 4; ++a) acc += w[a] * rows[rbase + a][t];
    vbuf[yy][t] = acc * winv;
  }
  __syncthreads();

  float bsum = 0.f;
  if (t < 160) {
    int yy = t / 20, ch = t - yy * 20;
    float o[8];
#pragma unroll
    for (int j = 0; j < 8; ++j) {
      int x = ch * 8 + j;
      float sx = (x + 0.5f) * 1.6f - 0.5f;
      int jx0 = (int)ceilf(sx - 1.6f);
      float wsum = 0.f, h = 0.f;
#pragma unroll
      for (int b = 0; b < 4; ++b) {
        int jj = jx0 + b;
        float wv = fmaxf(0.f, 1.f - fabsf((float)jj - sx) * 0.625f);
        if (jj < 0 || jj > 255) wv = 0.f;
        wsum += wv;
        h += wv * vbuf[yy][min(max(jj, 0), 255)];
      }
      h *= __builtin_amdgcn_rcpf(wsum);
      o[j] = h; bsum += h;
    }
    int p0 = (y0 + yy) * 160 + ch * 8;
    int kt = p0 >> 6, kq = (p0 >> 3) & 7;
    size_t a = ((size_t)(kt * 8 + kq) * MPAD + m) * 8;
    uint2 pk;
    pk.x = pk_fp8(o[0], o[1], o[2], o[3]);
    pk.y = pk_fp8(o[4], o[5], o[6], o[7]);
    *reinterpret_cast<uint2*>(&T[a]) = pk;
  }
#pragma unroll
  for (int o2 = 32; o2 > 0; o2 >>= 1) bsum += __shfl_down(bsum, o2, 64);
  __shared__ float red[4];
  int wid = t >> 6;
  if ((t & 63) == 0) red[wid] = bsum;
  __syncthreads();
  if (t == 0) atomicAdd(&tsum[m], red[0] + red[1] + red[2] + red[3]);
}

// ones column: T[kt][kq][m=400][0..7] = fp8(1.0)=0x38 -> A2[:,400] = row-sum of p
__global__ void ones_init(uchar* __restrict__ T) {
  int i = blockIdx.x * 256 + threadIdx.x;   // over 3200 (kt*8+kq) slices
  if (i < 3200) {
    uint2 v; v.x = 0x38383838u; v.y = 0x38383838u;
    *reinterpret_cast<uint2*>(&T[((size_t)i * MPAD + 400) * 8]) = v;
  }
}

// =====================================================================
// Fused dual GEMM (fp8 e4m3) + conversion (spread over ALL 512 threads,
// 4 elements each) + softplus row-stats. BK=64, 1-barrier dbuf parity.
// waves 0-3 additionally stage B (7 gll16/thread, drained via WAITV(0)
// BEFORE issuing their A-load so the A-load stays in flight a full iter).
// sump comes free from the ones-column of T. LDS 66.5 KB -> 2 blocks/CU.
__global__ __launch_bounds__(512, 4) void gemm_mega(
    const float* __restrict__ pm, const uchar* __restrict__ Tg,
    ushort* __restrict__ part, float* __restrict__ SP) {
  __shared__ uchar buf[2][TSLICE];        // 57,344 B
  __shared__ uchar abuf[2][2][32 * 72];   //  9,216 B (72-byte padded rows)

  // XCD swizzle: nwg = 760 = 8 x 95 (exact chunks), kz-major
  int orig = blockIdx.x;
  int xcd = orig & 7, base = orig >> 3;
  int wgid = xcd * 95 + base;
  int kz = wgid / NBLK;
  int bn = wgid - kz * NBLK;

  int t = threadIdx.x, lane = t & 63, w = t >> 6;
  int rg = w >> 2, cg = w & 3;
  int l15 = lane & 15, kq = lane >> 4;

  bool is_b = (t < 256);

  int arow = t >> 4, kc4 = t & 15;       // row 0..31, float4 chunk 0..15
  int rowA = bn * 32 + arow;
  int rowAc = min(rowA, N_PRED - 1);
  const float* apf = pm + (size_t)rowAc * KDIM + kz * (STEPS * 64) + kc4 * 4;
  int awoff = arow * 72 + kc4 * 4;       // BYTES within abuf[ni][arr]

  const uchar* tsrc = Tg + (size_t)(kz * STEPS) * TSLICE;
  int bbase = (kq * MPAD + cg * 112 + l15) * 8;      // B frag (byte idx), +h*14336
  int afbase = (rg * 16 + l15) * 72 + kq * 8;        // A frag (byte idx), +h*32

  f32x4 z = {0.f, 0.f, 0.f, 0.f};
  f32x4 acc1[7], acc2[7];
#pragma unroll
  for (int j = 0; j < 7; ++j) { acc1[j] = z; acc2[j] = z; }
  float stx = 0.f;

  union fragu { uint2 u; long long l; };

#define WAITV(N) asm volatile("s_waitcnt vmcnt(" #N ")" ::: "memory")

// stage step ST into buf[BI]: 28 chunks x 1KB; 7 gll16 per staging thread.
#define STAGE_B(BI, ST)                                                        \
  do {                                                                         \
    const uchar* s_ = tsrc + (size_t)(ST) * TSLICE;                            \
    _Pragma("unroll")                                                          \
    for (int i_ = 0; i_ < 7; ++i_) {                                           \
      int c_ = w * 7 + i_;                                                     \
      gll16(s_ + c_ * 1024 + lane * 16, &buf[BI][c_ * 1024]);                  \
    }                                                                          \
  } while (0)

// convert 4 f32 (one float4) -> fp8 x/p + softplus stat; one b32 per array.
#define CONVERT(NI, V)                                                         \
  do {                                                                         \
    float xs_[4] = {V.x, V.y, V.z, V.w};                                       \
    float sg_[4];                                                              \
    _Pragma("unroll")                                                          \
    for (int q_ = 0; q_ < 4; ++q_) {                                           \
      float a_ = xs_[q_];                                                      \
      float e_ = __expf(-fabsf(a_));                                           \
      float o_ = 1.f + e_;                                                     \
      float i_ = __builtin_amdgcn_rcpf(o_);                                    \
      sg_[q_] = (a_ >= 0.f) ? i_ : e_ * i_;                                    \
      stx += fmaxf(a_, 0.f) + __logf(o_);                                      \
    }                                                                          \
    *reinterpret_cast<uint32_t*>(&abuf[NI][0][awoff]) =                        \
        pk_fp8(xs_[0], xs_[1], xs_[2], xs_[3]);                                \
    *reinterpret_cast<uint32_t*>(&abuf[NI][1][awoff]) =                        \
        pk_fp8(sg_[0], sg_[1], sg_[2], sg_[3]);                                \
  } while (0)

// ACUR = S&1 (compile-time). f(k): fA when k even, fB when k odd.
#define ITER(ACUR, S)                                                          \
  do {                                                                         \
    if (is_b) WAITV(0);             /* stage(S) + A(S+1) issued a step ago */  \
    if ((S) + 2 < STEPS) {          /* issue A load for S+2 (all threads) */   \
      float4 nv_ = *reinterpret_cast<const float4*>(apf + ((S) + 2) * 64);     \
      if (ACUR) fB = nv_; else fA = nv_;                                       \
    }                                                                          \
    __builtin_amdgcn_s_barrier();                                              \
    __builtin_amdgcn_sched_barrier(0);                                         \
    if ((S) + 1 < STEPS) {                                                     \
      if (is_b) STAGE_B(ACUR ^ 1, (S) + 1);                                    \
      if (ACUR) CONVERT(0, fA); else CONVERT(1, fB);                           \
    }                                                                          \
    _Pragma("unroll")                                                          \
    for (int h_ = 0; h_ < 2; ++h_) {                                           \
      fragu ax_, ap_;                                                          \
      ax_.u = *reinterpret_cast<const uint2*>(&abuf[ACUR][0][afbase + h_ * 32]); \
      ap_.u = *reinterpret_cast<const uint2*>(&abuf[ACUR][1][afbase + h_ * 32]); \
      __builtin_amdgcn_s_setprio(1);                                           \
      _Pragma("unroll")                                                        \
      for (int j_ = 0; j_ < 7; ++j_) {                                         \
        fragu bv_;                                                             \
        bv_.u = *reinterpret_cast<const uint2*>(                               \
            &buf[ACUR][bbase + h_ * 14336 + j_ * 128]);                        \
        acc1[j_] = __builtin_amdgcn_mfma_f32_16x16x32_fp8_fp8(ax_.l, bv_.l, acc1[j_], 0, 0, 0); \
        acc2[j_] = __builtin_amdgcn_mfma_f32_16x16x32_fp8_fp8(ap_.l, bv_.l, acc2[j_], 0, 0, 0); \
      }                                                                        \
      __builtin_amdgcn_s_setprio(0);                                           \
    }                                                                          \
    asm volatile("s_waitcnt lgkmcnt(0)" ::: "memory");                         \
  } while (0)

  // ---- prologue: stage(0)->buf0; all: f(0) converted->abuf0, f(1)->fB ----
  float4 fA, fB;
  {
    float4 f0 = *reinterpret_cast<const float4*>(apf);
    fB = *reinterpret_cast<const float4*>(apf + 64);
    if (is_b) STAGE_B(0, 0);
    CONVERT(0, f0);
  }
  asm volatile("s_waitcnt lgkmcnt(0)" ::: "memory");

  for (int s = 0; s < STEPS; s += 2) {
    ITER(0, s);
    ITER(1, s + 1);
  }
#undef ITER
#undef CONVERT
#undef STAGE_B
#undef WAITV

  // ---- softplus row stats: 16 threads per row, xor-reduce width 16 ----
  stx += __shfl_xor(stx, 1, 16); stx += __shfl_xor(stx, 2, 16);
  stx += __shfl_xor(stx, 4, 16); stx += __shfl_xor(stx, 8, 16);
  if ((t & 15) == 0 && rowA < N_PRED)
    atomicAdd(SP + rowA, stx);

  // ---- store bf16 partials: part[arr][n][kz][MPAD] ----
  ushort* p1 = part;
  ushort* p2 = part + (size_t)KZN * 1200 * MPAD;
#pragma unroll
  for (int j = 0; j < 7; ++j)
#pragma unroll
    for (int rr = 0; rr < 4; ++rr) {
      int gn = bn * 32 + rg * 16 + kq * 4 + rr;   // C/D: row=(lane>>4)*4+reg
      if (gn < N_PRED) {
        int gm = cg * 112 + j * 16 + l15;         // col=lane&15
        size_t o = ((size_t)gn * KZN + kz) * MPAD + gm;
        p1[o] = f2bf(acc1[j][rr]);
        p2[o] = f2bf(acc2[j][rr]);
      }
    }
}

// sump[n] = sum over kz of A2 partial at ones-column (m=400)
__global__ void sumprow(const ushort* __restrict__ part, float* __restrict__ sump) {
  int n = blockIdx.x * 256 + threadIdx.x;
  if (n < N_PRED) {
    const ushort* p2 = part + (size_t)KZN * 1200 * MPAD + (size_t)n * KZN * MPAD + 400;
    float s = 0.f;
#pragma unroll
    for (int kz = 0; kz < KZN; ++kz) s += bf2f(p2[kz * MPAD]);
    sump[n] = s;
  }
}

// ---------------- softmax probs [1200,81] ----------------
__global__ void probs_kernel(const float* __restrict__ logits, float* __restrict__ probs) {
  int n = blockIdx.x;
  int l = threadIdx.x;
  const float* row = logits + n * NCLS;
  float v0 = row[l];
  bool has2 = (l + 64) < NCLS;
  float v1 = has2 ? row[l + 64] : -3.4e38f;
  float mx = fmaxf(v0, v1);
#pragma unroll
  for (int o = 1; o < 64; o <<= 1) mx = fmaxf(mx, __shfl_xor(mx, o, 64));
  float e0 = expf(v0 - mx);
  float e1 = has2 ? expf(v1 - mx) : 0.f;
  float sm = e0 + e1;
#pragma unroll
  for (int o = 1; o < 64; o <<= 1) sm += __shfl_xor(sm, o, 64);
  float inv = 1.f / sm;
  probs[n * NCLS + l] = e0 * inv;
  if (has2) probs[n * NCLS + l + 64] = e1 * inv;
}

// ---------------- final combine (bf16 partials, [n][kz][MPAD] layout) ----------------
__global__ void combine2(const ushort* __restrict__ part,
                         const float* __restrict__ SP, const float* __restrict__ sump,
                         const float* __restrict__ tsum, const float* __restrict__ probs,
                         const float* __restrict__ pboxes, const float* __restrict__ tboxes,
                         const int* __restrict__ tids, float* __restrict__ out) {
  int idx = blockIdx.x * 256 + threadIdx.x;   // < 480000
  int n = idx / M_TGT;
  int m = idx - n * M_TGT;

  const ushort* p1 = part + (size_t)n * (KZN * MPAD) + m;
  const ushort* p2 = p1 + (size_t)KZN * 1200 * MPAD;
  float A1 = 0.f, A2 = 0.f;
  for (int kz = 0; kz < KZN; ++kz) {
    A1 += bf2f(p1[kz * MPAD]);
    A2 += bf2f(p2[kz * MPAD]);
  }
  float cm = (SP[n] - A1) * (1.0f / (float)KDIM);
  float cd = 1.f - (2.f * A2 + 1e-5f) / (sump[n] + tsum[m] + 1e-5f);
  float cc = -probs[n * NCLS + tids[m]];

  float4 pb = reinterpret_cast<const float4*>(pboxes)[n];
  float4 tb = reinterpret_cast<const float4*>(tboxes)[m];
  float l1 = fabsf(pb.x - tb.x) + fabsf(pb.y - tb.y) + fabsf(pb.z - tb.z) + fabsf(pb.w - tb.w);
  float px1 = pb.x - 0.5f * pb.z, py1 = pb.y - 0.5f * pb.w;
  float px2 = pb.x + 0.5f * pb.z, py2 = pb.y + 0.5f * pb.w;
  float tx1 = tb.x - 0.5f * tb.z, ty1 = tb.y - 0.5f * tb.w;
  float tx2 = tb.x + 0.5f * tb.z, ty2 = tb.y + 0.5f * tb.w;
  float a1 = (px2 - px1) * (py2 - py1);
  float a2 = (tx2 - tx1) * (ty2 - ty1);
  float iw = fmaxf(fminf(px2, tx2) - fmaxf(px1, tx1), 0.f);
  float ih = fmaxf(fminf(py2, ty2) - fmaxf(py1, ty1), 0.f);
  float inter = iw * ih;
  float uni = a1 + a2 - inter;
  float iou = inter / uni;
  float ew = fmaxf(fmaxf(px2, tx2) - fminf(px1, tx1), 0.f);
  float eh = fmaxf(fmaxf(py2, ty2) - fminf(py1, ty1), 0.f);
  float ae = ew * eh;
  float giou = iou - (ae - uni) / ae;

  out[idx] = 5.f * l1 + 2.f * (-giou) + 2.f * cc + 5.f * cm + 5.f * cd;
}

// =====================================================================
// FALLBACK PATH (only if ws too small)
// =====================================================================

__device__ __forceinline__ float sigf(float x) {
  return 1.f / (1.f + __expf(-x));
}

__global__ void resize_lin(const float* __restrict__ tm, ushort* __restrict__ T,
                           float* __restrict__ tsum) {
  int m = blockIdx.x;
  int p = blockIdx.y * 256 + threadIdx.x;
  int y = p / 160;
  int x = p - y * 160;
  float wy[4], wx[4];
  int jy0, jx0;
  {
    float s = (y + 0.5f) * 1.6f - 0.5f;
    jy0 = (int)ceilf(s - 1.6f);
    float ws = 0.f;
#pragma unroll
    for (int a = 0; a < 4; ++a) {
      int j = jy0 + a;
      float w = fmaxf(0.f, 1.f - fabsf((float)j - s) * 0.625f);
      if (j < 0 || j > 255) w = 0.f;
      wy[a] = w; ws += w;
    }
    float inv = 1.f / ws;
#pragma unroll
    for (int a = 0; a < 4; ++a) wy[a] *= inv;
  }
  {
    float s = (x + 0.5f) * 1.6f - 0.5f;
    jx0 = (int)ceilf(s - 1.6f);
    float ws = 0.f;
#pragma unroll
    for (int b = 0; b < 4; ++b) {
      int j = jx0 + b;
      float w = fmaxf(0.f, 1.f - fabsf((float)j - s) * 0.625f);
      if (j < 0 || j > 255) w = 0.f;
      wx[b] = w; ws += w;
    }
    float inv = 1.f / ws;
#pragma unroll
    for (int b = 0; b < 4; ++b) wx[b] *= inv;
  }
  const float* base = tm + (size_t)m * 65536;
  float acc = 0.f;
#pragma unroll
  for (int a = 0; a < 4; ++a) {
    int jy = min(max(jy0 + a, 0), 255);
    float wya = wy[a];
#pragma unroll
    for (int b = 0; b < 4; ++b) {
      int jx = min(max(jx0 + b, 0), 255);
      acc += wya * wx[b] * base[jy * 256 + jx];
    }
  }
  T[(size_t)m * KDIM + p] = f2bf(acc);
  float v = acc;
#pragma unroll
  for (int o = 32; o > 0; o >>= 1) v += __shfl_down(v, o, 64);
  __shared__ float red[4];
  int wid = threadIdx.x >> 6;
  if ((threadIdx.x & 63) == 0) red[wid] = v;
  __syncthreads();
  if (threadIdx.x == 0) atomicAdd(&tsum[m], red[0] + red[1] + red[2] + red[3]);
}

__global__ void stats_kernel(const float* __restrict__ pm, float* __restrict__ S,
                             float* __restrict__ sump) {
  int n = blockIdx.x;
  const float4* row = reinterpret_cast<const float4*>(pm + (size_t)n * KDIM);
  float ssp = 0.f, sp = 0.f;
  for (int i = threadIdx.x; i < KDIM / 4; i += 256) {
    float4 v = row[i];
    float xs[4] = {v.x, v.y, v.z, v.w};
#pragma unroll
    for (int j = 0; j < 4; ++j) {
      float x = xs[j];
      float e = __expf(-fabsf(x));
      float inv1pe = 1.f / (1.f + e);
      sp += (x >= 0.f) ? inv1pe : e * inv1pe;
      ssp += fmaxf(x, 0.f) + log1pf(e);
    }
  }
#pragma unroll
  for (int o = 32; o > 0; o >>= 1) {
    ssp += __shfl_down(ssp, o, 64);
    sp  += __shfl_down(sp, o, 64);
  }
  __shared__ float red[8];
  int wid = threadIdx.x >> 6;
  if ((threadIdx.x & 63) == 0) { red[wid] = ssp; red[4 + wid] = sp; }
  __syncthreads();
  if (threadIdx.x == 0) {
    S[n]    = -(red[0] + red[1] + red[2] + red[3]);
    sump[n] = red[4] + red[5] + red[6] + red[7];
  }
}

__device__ __forceinline__ bf16x8 load_frag_lin(const ushort* p) {
  union { ushort4 u[2]; bf16x8 f; } fr;
  fr.u[0] = *reinterpret_cast<const ushort4*>(p);
  fr.u[1] = *reinterpret_cast<const ushort4*>(p + 4);
  return fr.f;
}

__global__ __launch_bounds__(256) void gemm_fused(
    const float* __restrict__ pm, const ushort* __restrict__ T,
    ushort* __restrict__ part1, ushort* __restrict__ part2, int k_per) {
  __shared__ ushort Ax[64][40];
  __shared__ ushort Ap[64][40];
  __shared__ ushort Bs[64][40];
  int n0 = blockIdx.x * 64;
  int m0 = blockIdx.y * 64;
  int kz = blockIdx.z;
  int k_begin = kz * k_per;
  int t = threadIdx.x;
  int r = t >> 2;
  int q = t & 3;
  bool a_ok = (n0 + r) < N_PRED;
  bool b_ok = (m0 + r) < M_TGT;
  const float*  pA = pm + (size_t)(n0 + r) * KDIM + k_begin + q * 8;
  const ushort* pB = T  + (size_t)(m0 + r) * KDIM + k_begin + q * 8;
  int lane = t & 63;
  int w = t >> 6;
  int wr = (w >> 1) * 32;
  int wc = (w & 1) * 32;
  int lrow = lane & 15;
  int kc = (lane >> 4) * 8;
  f32x4 zero = {0.f, 0.f, 0.f, 0.f};
  f32x4 acc1[2][2] = {{zero, zero}, {zero, zero}};
  f32x4 acc2[2][2] = {{zero, zero}, {zero, zero}};
  int steps = k_per / 32;
  for (int kt = 0; kt < steps; ++kt) {
    __syncthreads();
    float4 f0 = {0.f,0.f,0.f,0.f}, f1 = {0.f,0.f,0.f,0.f};
    if (a_ok) {
      f0 = *reinterpret_cast<const float4*>(pA);
      f1 = *reinterpret_cast<const float4*>(pA + 4);
    }
    pA += 32;
    ushort4 xa, xb, pa, pb4;
    xa.x = f2bf(f0.x); xa.y = f2bf(f0.y); xa.z = f2bf(f0.z); xa.w = f2bf(f0.w);
    xb.x = f2bf(f1.x); xb.y = f2bf(f1.y); xb.z = f2bf(f1.z); xb.w = f2bf(f1.w);
    pa.x = f2bf(sigf(f0.x)); pa.y = f2bf(sigf(f0.y)); pa.z = f2bf(sigf(f0.z)); pa.w = f2bf(sigf(f0.w));
    pb4.x = f2bf(sigf(f1.x)); pb4.y = f2bf(sigf(f1.y)); pb4.z = f2bf(sigf(f1.z)); pb4.w = f2bf(sigf(f1.w));
    *reinterpret_cast<ushort4*>(&Ax[r][q * 8])     = xa;
    *reinterpret_cast<ushort4*>(&Ax[r][q * 8 + 4]) = xb;
    *reinterpret_cast<ushort4*>(&Ap[r][q * 8])     = pa;
    *reinterpret_cast<ushort4*>(&Ap[r][q * 8 + 4]) = pb4;
    union { uint4 u; ushort4 s[2]; } bv;
    bv.u = make_uint4(0, 0, 0, 0);
    if (b_ok) bv.u = *reinterpret_cast<const uint4*>(pB);
    pB += 32;
    *reinterpret_cast<ushort4*>(&Bs[r][q * 8])     = bv.s[0];
    *reinterpret_cast<ushort4*>(&Bs[r][q * 8 + 4]) = bv.s[1];
    __syncthreads();
    bf16x8 ax[2], ap[2], bb[2];
#pragma unroll
    for (int i = 0; i < 2; ++i) {
      ax[i] = load_frag_lin(&Ax[wr + i * 16 + lrow][kc]);
      ap[i] = load_frag_lin(&Ap[wr + i * 16 + lrow][kc]);
      bb[i] = load_frag_lin(&Bs[wc + i * 16 + lrow][kc]);
    }
#pragma unroll
    for (int i = 0; i < 2; ++i)
#pragma unroll
      for (int j = 0; j < 2; ++j) {
        acc1[i][j] = __builtin_amdgcn_mfma_f32_16x16x32_bf16(ax[i], bb[j], acc1[i][j], 0, 0, 0);
        acc2[i][j] = __builtin_amdgcn_mfma_f32_16x16x32_bf16(ap[i], bb[j], acc2[i][j], 0, 0, 0);
      }
  }
  int rowb = (lane >> 4) * 4;
  int col = lane & 15;
#pragma unroll
  for (int i = 0; i < 2; ++i)
#pragma unroll
    for (int j = 0; j < 2; ++j)
#pragma unroll
      for (int rr = 0; rr < 4; ++rr) {
        int gn = n0 + wr + i * 16 + rowb + rr;
        int gm = m0 + wc + j * 16 + col;
        if (gn < N_PRED && gm < M_TGT) {
          size_t o = (size_t)kz * 480000 + (size_t)gn * 400 + gm;
          part1[o] = f2bf(acc1[i][j][rr]);
          part2[o] = f2bf(acc2[i][j][rr]);
        }
      }
}

__global__ void combine_fb(const ushort* __restrict__ part1, const ushort* __restrict__ part2,
                           const float* __restrict__ S, const float* __restrict__ sump,
                           const float* __restrict__ tsum, const float* __restrict__ probs,
                           const float* __restrict__ pboxes, const float* __restrict__ tboxes,
                           const int* __restrict__ tids, float* __restrict__ out, int KZ) {
  int idx = blockIdx.x * 256 + threadIdx.x;
  int n = idx / M_TGT;
  int m = idx - n * M_TGT;
  float A1 = 0.f, A2 = 0.f;
  for (int kz = 0; kz < KZ; ++kz) {
    A1 += bf2f(part1[(size_t)kz * 480000 + idx]);
    A2 += bf2f(part2[(size_t)kz * 480000 + idx]);
  }
  float cm = -(A1 + S[n]) * (1.0f / (float)KDIM);
  float cd = 1.f - (2.f * A2 + 1e-5f) / (sump[n] + tsum[m] + 1e-5f);
  float cc = -probs[n * NCLS + tids[m]];
  float4 pb = reinterpret_cast<const float4*>(pboxes)[n];
  float4 tb = reinterpret_cast<const float4*>(tboxes)[m];
  float l1 = fabsf(pb.x - tb.x) + fabsf(pb.y - tb.y) + fabsf(pb.z - tb.z) + fabsf(pb.w - tb.w);
  float px1 = pb.x - 0.5f * pb.z, py1 = pb.y - 0.5f * pb.w;
  float px2 = pb.x + 0.5f * pb.z, py2 = pb.y + 0.5f * pb.w;
  float tx1 = tb.x - 0.5f * tb.z, ty1 = tb.y - 0.5f * tb.w;
  float tx2 = tb.x + 0.5f * tb.z, ty2 = tb.y + 0.5f * tb.w;
  float a1 = (px2 - px1) * (py2 - py1);
  float a2 = (tx2 - tx1) * (ty2 - ty1);
  float iw = fmaxf(fminf(px2, tx2) - fmaxf(px1, tx1), 0.f);
  float ih = fmaxf(fminf(py2, ty2) - fmaxf(py1, ty1), 0.f);
  float inter = iw * ih;
  float uni = a1 + a2 - inter;
  float iou = inter / uni;
  float ew = fmaxf(fmaxf(px2, tx2) - fminf(px1, tx1), 0.f);
  float eh = fmaxf(fmaxf(py2, ty2) - fminf(py1, ty1), 0.f);
  float ae = ew * eh;
  float giou = iou - (ae - uni) / ae;
  out[idx] = 5.f * l1 + 2.f * (-giou) + 2.f * cc + 5.f * cm + 5.f * cd;
}

// =====================================================================

extern "C" void kernel_launch(void* const* d_in, const int* in_sizes, int n_in,
                              void* d_out, int out_size, void* d_ws, size_t ws_size,
                              hipStream_t stream) {
  const float* logits = (const float*)d_in[0];
  const float* pboxes = (const float*)d_in[1];
  const float* pmasks = (const float*)d_in[2];
  const float* tboxes = (const float*)d_in[3];
  const float* tmasks = (const float*)d_in[4];
  const int*   tids   = (const int*)d_in[5];
  float* out = (float*)d_out;
  char* ws = (char*)d_ws;

  // new-path workspace layout
  const size_t offT     = 0;                         // 400*28672 = 11,468,800 (fp8)
  const size_t offPart  = 24371200;                  // 2*20*1200*448*2 = 43,008,000
  const size_t offProbs = offPart + 53760000;        // 388,800
  const size_t offStats = offProbs + 390400;         // SP 4800 | sump 4800 | tsum 1600
  const size_t needNew  = offStats + 11200;

  if (ws_size >= needNew) {
    uchar* Tg    = (uchar*)(ws + offT);
    ushort* part = (ushort*)(ws + offPart);
    float* probs = (float*)(ws + offProbs);
    float* SP    = (float*)(ws + offStats);
    float* sump  = (float*)(ws + offStats + 4800);
    float* tsum  = (float*)(ws + offStats + 9600);

    hipMemsetAsync(SP, 0, 11200, stream);   // SP + sump + tsum
    resize2<<<dim3(M_TGT, 20), 256, 0, stream>>>(tmasks, Tg, tsum);
    ones_init<<<13, 256, 0, stream>>>(Tg);
    probs_kernel<<<N_PRED, 64, 0, stream>>>(logits, probs);
    gemm_mega<<<NBLK * KZN, 512, 0, stream>>>(pmasks, Tg, part, SP);
    sumprow<<<5, 256, 0, stream>>>(part, sump);
    combine2<<<1875, 256, 0, stream>>>(part, SP, sump, tsum, probs,
                                       pboxes, tboxes, tids, out);
  } else {
    // fallback (R4 pipeline)
    ushort* T     = (ushort*)ws;
    float*  probs = (float*)(ws + 20480000);
    float*  S     = (float*)(ws + 20868800);
    float*  sump  = (float*)(ws + 20873600);
    float*  tsum  = (float*)(ws + 20878400);
    ushort* part1 = (ushort*)(ws + 20880000);
    size_t need8 = 20880000ull + 2ull * 8 * 480000 * 2;
    int KZf = (ws_size >= need8) ? 8 : 1;
    ushort* part2 = part1 + (size_t)KZf * 480000;

    hipMemsetAsync(tsum, 0, M_TGT * sizeof(float), stream);
    resize_lin<<<dim3(M_TGT, 100), 256, 0, stream>>>(tmasks, T, tsum);
    probs_kernel<<<N_PRED, 64, 0, stream>>>(logits, probs);
    stats_kernel<<<N_PRED, 256, 0, stream>>>(pmasks, S, sump);
    gemm_fused<<<dim3(19, 7, KZf), 256, 0, stream>>>(pmasks, T, part1, part2, KDIM / KZf);
    combine_fb<<<1875, 256, 0, stream>>>(part1, part2, S, sump, tsum, probs,
                                         pboxes, tboxes, tids, out, KZf);
  }
}

// Round 16
// 133.818 us; speedup vs baseline: 4.4540x; 1.0409x over previous
//
#include <hip/hip_runtime.h>
#include <cstdint>

#define N_PRED 1200
#define M_TGT  400
#define KDIM   25600   // 160*160
#define NCLS   81
#define MPAD   448     // padded target count (28 x 16)
#define KZN    13      // split-K factor (5 kz with 32 steps + 8 kz with 30)
#define NBLK   38      // row blocks of 32 (1216 >= 1200)
#define TSLICE 28672   // BYTES per BK=64 step: 8(kq) * 448 * 8 fp8

typedef __attribute__((ext_vector_type(8)))  short bf16x8;
typedef __attribute__((ext_vector_type(4)))  float f32x4;
typedef unsigned char uchar;

__device__ __forceinline__ ushort f2bf(float f) {
  union { float f; uint32_t u; } v; v.f = f;
  uint32_t u = v.u + 0x7fffu + ((v.u >> 16) & 1u);
  return (ushort)(u >> 16);
}

__device__ __forceinline__ float bf2f(ushort s) {
  union { uint32_t u; float f; } v; v.u = ((uint32_t)s) << 16;
  return v.f;
}

// pack 4 f32 -> 4 fp8 e4m3 (OCP, saturating) in one u32
__device__ __forceinline__ uint32_t pk_fp8(float a, float b, float c, float d) {
  uint32_t v = (uint32_t)__builtin_amdgcn_cvt_pk_fp8_f32(a, b, 0, false);
  v = (uint32_t)__builtin_amdgcn_cvt_pk_fp8_f32(c, d, (int)v, true);
  return v;
}

__device__ __forceinline__ void gll16(const void* g, void* l) {
  __builtin_amdgcn_global_load_lds(
      (const __attribute__((address_space(1))) void*)g,
      (__attribute__((address_space(3))) void*)l, 16, 0, 0);
}

// =====================================================================
// Resize tgt_masks [400,256,256] -> T fp8 fragment-major: [kt(400)][kq(8)][m(448)][8]
__global__ __launch_bounds__(256) void resize2(const float* __restrict__ tm,
                                               uchar* __restrict__ T,
                                               float* __restrict__ tsum) {
  __shared__ float rows[16][256];
  __shared__ float vbuf[8][256];

  int m = blockIdx.x, yt = blockIdx.y;  // yt 0..19
  int y0 = yt * 8;
  int t = threadIdx.x;

  int jbase = (int)ceilf((y0 + 0.5f) * 1.6f - 2.1f);

  const float* base = tm + (size_t)m * 65536;
  {
    int r = t >> 4;
    int c0 = (t & 15) * 16;
    int jr = min(max(jbase + r, 0), 255);
    const float4* src = reinterpret_cast<const float4*>(base + jr * 256 + c0);
#pragma unroll
    for (int i = 0; i < 4; ++i)
      *reinterpret_cast<float4*>(&rows[r][c0 + i * 4]) = src[i];
  }
  __syncthreads();

#pragma unroll
  for (int yy = 0; yy < 8; ++yy) {
    int y = y0 + yy;
    float s = (y + 0.5f) * 1.6f - 0.5f;
    int j0 = (int)ceilf(s - 1.6f);
    float w[4]; float wsum = 0.f;
#pragma unroll
    for (int a = 0; a < 4; ++a) {
      int j = j0 + a;
      float wv = fmaxf(0.f, 1.f - fabsf((float)j - s) * 0.625f);
      if (j < 0 || j > 255) wv = 0.f;
      w[a] = wv; wsum += wv;
    }
    float winv = __builtin_amdgcn_rcpf(wsum);
    float acc = 0.f;
    int rbase = j0 - jbase;
#pragma unroll
    for (int a = 0; a < 4; ++a) acc += w[a] * rows[rbase + a][t];
    vbuf[yy][t] = acc * winv;
  }
  __syncthreads();

  float bsum = 0.f;
  if (t < 160) {
    int yy = t / 20, ch = t - yy * 20;
    float o[8];
#pragma unroll
    for (int j = 0; j < 8; ++j) {
      int x = ch * 8 + j;
      float sx = (x + 0.5f) * 1.6f - 0.5f;
      int jx0 = (int)ceilf(sx - 1.6f);
      float wsum = 0.f, h = 0.f;
#pragma unroll
      for (int b = 0; b < 4; ++b) {
        int jj = jx0 + b;
        float wv = fmaxf(0.f, 1.f - fabsf((float)jj - sx) * 0.625f);
        if (jj < 0 || jj > 255) wv = 0.f;
        wsum += wv;
        h += wv * vbuf[yy][min(max(jj, 0), 255)];
      }
      h *= __builtin_amdgcn_rcpf(wsum);
      o[j] = h; bsum += h;
    }
    int p0 = (y0 + yy) * 160 + ch * 8;
    int kt = p0 >> 6, kq = (p0 >> 3) & 7;
    size_t a = ((size_t)(kt * 8 + kq) * MPAD + m) * 8;
    uint2 pk;
    pk.x = pk_fp8(o[0], o[1], o[2], o[3]);
    pk.y = pk_fp8(o[4], o[5], o[6], o[7]);
    *reinterpret_cast<uint2*>(&T[a]) = pk;
  }
#pragma unroll
  for (int o2 = 32; o2 > 0; o2 >>= 1) bsum += __shfl_down(bsum, o2, 64);
  __shared__ float red[4];
  int wid = t >> 6;
  if ((t & 63) == 0) red[wid] = bsum;
  __syncthreads();
  if (t == 0) atomicAdd(&tsum[m], red[0] + red[1] + red[2] + red[3]);
}

// ones column: T[kt][kq][m=400][0..7] = fp8(1.0)=0x38 -> A2[:,400] = row-sum of p
__global__ void ones_init(uchar* __restrict__ T) {
  int i = blockIdx.x * 256 + threadIdx.x;   // over 3200 (kt*8+kq) slices
  if (i < 3200) {
    uint2 v; v.x = 0x38383838u; v.y = 0x38383838u;
    *reinterpret_cast<uint2*>(&T[((size_t)i * MPAD + 400) * 8]) = v;
  }
}

// =====================================================================
// Fused dual GEMM (fp8 e4m3) + conversion (spread over ALL 512 threads)
// + softplus row-stats. BK=64, 1-barrier dbuf parity pipeline.
// KZN=13 -> 494 blocks = ONE co-resident generation (2 blocks/CU, no tail).
// Non-uniform split-K: kz<5 -> 32 steps, else 30 (all even for parity loop).
__global__ __launch_bounds__(512, 4) void gemm_mega(
    const float* __restrict__ pm, const uchar* __restrict__ Tg,
    ushort* __restrict__ part, float* __restrict__ SP) {
  __shared__ uchar buf[2][TSLICE];        // 57,344 B
  __shared__ uchar abuf[2][2][32 * 72];   //  9,216 B (72-byte padded rows)

  // bijective XCD swizzle for nwg=494 (m204): q=61, r=6; kz-major chunks
  int orig = blockIdx.x;
  int xcd = orig & 7, base = orig >> 3;
  int wgid = (xcd < 6 ? xcd * 62 : 372 + (xcd - 6) * 61) + base;
  int kz = wgid / NBLK;
  int bn = wgid - kz * NBLK;
  int koff  = (kz < 5) ? (32 * kz) : (160 + 30 * (kz - 5));   // in BK=64 units
  int steps = (kz < 5) ? 32 : 30;

  int t = threadIdx.x, lane = t & 63, w = t >> 6;
  int rg = w >> 2, cg = w & 3;
  int l15 = lane & 15, kq = lane >> 4;

  bool is_b = (t < 256);

  int arow = t >> 4, kc4 = t & 15;       // row 0..31, float4 chunk 0..15
  int rowA = bn * 32 + arow;
  int rowAc = min(rowA, N_PRED - 1);
  const float* apf = pm + (size_t)rowAc * KDIM + koff * 64 + kc4 * 4;
  int awoff = arow * 72 + kc4 * 4;       // BYTES within abuf[ni][arr]

  const uchar* tsrc = Tg + (size_t)koff * TSLICE;
  int bbase = (kq * MPAD + cg * 112 + l15) * 8;      // B frag (byte idx), +h*14336
  int afbase = (rg * 16 + l15) * 72 + kq * 8;        // A frag (byte idx), +h*32

  f32x4 z = {0.f, 0.f, 0.f, 0.f};
  f32x4 acc1[7], acc2[7];
#pragma unroll
  for (int j = 0; j < 7; ++j) { acc1[j] = z; acc2[j] = z; }
  float stx = 0.f;

  union fragu { uint2 u; long long l; };

#define WAITV(N) asm volatile("s_waitcnt vmcnt(" #N ")" ::: "memory")

// stage step ST into buf[BI]: 28 chunks x 1KB; 7 gll16 per staging thread.
#define STAGE_B(BI, ST)                                                        \
  do {                                                                         \
    const uchar* s_ = tsrc + (size_t)(ST) * TSLICE;                            \
    _Pragma("unroll")                                                          \
    for (int i_ = 0; i_ < 7; ++i_) {                                           \
      int c_ = w * 7 + i_;                                                     \
      gll16(s_ + c_ * 1024 + lane * 16, &buf[BI][c_ * 1024]);                  \
    }                                                                          \
  } while (0)

// convert 4 f32 (one float4) -> fp8 x/p + softplus stat; one b32 per array.
#define CONVERT(NI, V)                                                         \
  do {                                                                         \
    float xs_[4] = {V.x, V.y, V.z, V.w};                                       \
    float sg_[4];                                                              \
    _Pragma("unroll")                                                          \
    for (int q_ = 0; q_ < 4; ++q_) {                                           \
      float a_ = xs_[q_];                                                      \
      float e_ = __expf(-fabsf(a_));                                           \
      float o_ = 1.f + e_;                                                     \
      float i_ = __builtin_amdgcn_rcpf(o_);                                    \
      sg_[q_] = (a_ >= 0.f) ? i_ : e_ * i_;                                    \
      stx += fmaxf(a_, 0.f) + __logf(o_);                                      \
    }                                                                          \
    *reinterpret_cast<uint32_t*>(&abuf[NI][0][awoff]) =                        \
        pk_fp8(xs_[0], xs_[1], xs_[2], xs_[3]);                                \
    *reinterpret_cast<uint32_t*>(&abuf[NI][1][awoff]) =                        \
        pk_fp8(sg_[0], sg_[1], sg_[2], sg_[3]);                                \
  } while (0)

// ACUR = S&1 (compile-time). f(k): fA when k even, fB when k odd.
#define ITER(ACUR, S)                                                          \
  do {                                                                         \
    if (is_b) WAITV(0);             /* stage(S) + A(S+1) issued a step ago */  \
    if ((S) + 2 < steps) {          /* issue A load for S+2 (all threads) */   \
      float4 nv_ = *reinterpret_cast<const float4*>(apf + ((S) + 2) * 64);     \
      if (ACUR) fB = nv_; else fA = nv_;                                       \
    }                                                                          \
    __builtin_amdgcn_s_barrier();                                              \
    __builtin_amdgcn_sched_barrier(0);                                         \
    if ((S) + 1 < steps) {                                                     \
      if (is_b) STAGE_B(ACUR ^ 1, (S) + 1);                                    \
      if (ACUR) CONVERT(0, fA); else CONVERT(1, fB);                           \
    }                                                                          \
    _Pragma("unroll")                                                          \
    for (int h_ = 0; h_ < 2; ++h_) {                                           \
      fragu ax_, ap_;                                                          \
      ax_.u = *reinterpret_cast<const uint2*>(&abuf[ACUR][0][afbase + h_ * 32]); \
      ap_.u = *reinterpret_cast<const uint2*>(&abuf[ACUR][1][afbase + h_ * 32]); \
      __builtin_amdgcn_s_setprio(1);                                           \
      _Pragma("unroll")                                                        \
      for (int j_ = 0; j_ < 7; ++j_) {                                         \
        fragu bv_;                                                             \
        bv_.u = *reinterpret_cast<const uint2*>(                               \
            &buf[ACUR][bbase + h_ * 14336 + j_ * 128]);                        \
        acc1[j_] = __builtin_amdgcn_mfma_f32_16x16x32_fp8_fp8(ax_.l, bv_.l, acc1[j_], 0, 0, 0); \
        acc2[j_] = __builtin_amdgcn_mfma_f32_16x16x32_fp8_fp8(ap_.l, bv_.l, acc2[j_], 0, 0, 0); \
      }                                                                        \
      __builtin_amdgcn_s_setprio(0);                                           \
    }                                                                          \
    asm volatile("s_waitcnt lgkmcnt(0)" ::: "memory");                         \
  } while (0)

  // ---- prologue: stage(0)->buf0; all: f(0) converted->abuf0, f(1)->fB ----
  float4 fA, fB;
  {
    float4 f0 = *reinterpret_cast<const float4*>(apf);
    fB = *reinterpret_cast<const float4*>(apf + 64);
    if (is_b) STAGE_B(0, 0);
    CONVERT(0, f0);
  }
  asm volatile("s_waitcnt lgkmcnt(0)" ::: "memory");

  for (int s = 0; s < steps; s += 2) {
    ITER(0, s);
    ITER(1, s + 1);
  }
#undef ITER
#undef CONVERT
#undef STAGE_B
#undef WAITV

  // ---- softplus row stats: 16 threads per row, xor-reduce width 16 ----
  stx += __shfl_xor(stx, 1, 16); stx += __shfl_xor(stx, 2, 16);
  stx += __shfl_xor(stx, 4, 16); stx += __shfl_xor(stx, 8, 16);
  if ((t & 15) == 0 && rowA < N_PRED)
    atomicAdd(SP + rowA, stx);

  // ---- store bf16 partials: part[arr][n][kz][MPAD] ----
  ushort* p1 = part;
  ushort* p2 = part + (size_t)KZN * 1200 * MPAD;
#pragma unroll
  for (int j = 0; j < 7; ++j)
#pragma unroll
    for (int rr = 0; rr < 4; ++rr) {
      int gn = bn * 32 + rg * 16 + kq * 4 + rr;   // C/D: row=(lane>>4)*4+reg
      if (gn < N_PRED) {
        int gm = cg * 112 + j * 16 + l15;         // col=lane&15
        size_t o = ((size_t)gn * KZN + kz) * MPAD + gm;
        p1[o] = f2bf(acc1[j][rr]);
        p2[o] = f2bf(acc2[j][rr]);
      }
    }
}

// sump[n] = sum over kz of A2 partial at ones-column (m=400)
__global__ void sumprow(const ushort* __restrict__ part, float* __restrict__ sump) {
  int n = blockIdx.x * 256 + threadIdx.x;
  if (n < N_PRED) {
    const ushort* p2 = part + (size_t)KZN * 1200 * MPAD + (size_t)n * KZN * MPAD + 400;
    float s = 0.f;
#pragma unroll
    for (int kz = 0; kz < KZN; ++kz) s += bf2f(p2[kz * MPAD]);
    sump[n] = s;
  }
}

// ---------------- softmax probs [1200,81] ----------------
__global__ void probs_kernel(const float* __restrict__ logits, float* __restrict__ probs) {
  int n = blockIdx.x;
  int l = threadIdx.x;
  const float* row = logits + n * NCLS;
  float v0 = row[l];
  bool has2 = (l + 64) < NCLS;
  float v1 = has2 ? row[l + 64] : -3.4e38f;
  float mx = fmaxf(v0, v1);
#pragma unroll
  for (int o = 1; o < 64; o <<= 1) mx = fmaxf(mx, __shfl_xor(mx, o, 64));
  float e0 = expf(v0 - mx);
  float e1 = has2 ? expf(v1 - mx) : 0.f;
  float sm = e0 + e1;
#pragma unroll
  for (int o = 1; o < 64; o <<= 1) sm += __shfl_xor(sm, o, 64);
  float inv = 1.f / sm;
  probs[n * NCLS + l] = e0 * inv;
  if (has2) probs[n * NCLS + l + 64] = e1 * inv;
}

// ---------------- final combine (bf16 partials, [n][kz][MPAD] layout) ----------------
__global__ void combine2(const ushort* __restrict__ part,
                         const float* __restrict__ SP, const float* __restrict__ sump,
                         const float* __restrict__ tsum, const float* __restrict__ probs,
                         const float* __restrict__ pboxes, const float* __restrict__ tboxes,
                         const int* __restrict__ tids, float* __restrict__ out) {
  int idx = blockIdx.x * 256 + threadIdx.x;   // < 480000
  int n = idx / M_TGT;
  int m = idx - n * M_TGT;

  const ushort* p1 = part + (size_t)n * (KZN * MPAD) + m;
  const ushort* p2 = p1 + (size_t)KZN * 1200 * MPAD;
  float A1 = 0.f, A2 = 0.f;
#pragma unroll
  for (int kz = 0; kz < KZN; ++kz) {
    A1 += bf2f(p1[kz * MPAD]);
    A2 += bf2f(p2[kz * MPAD]);
  }
  float cm = (SP[n] - A1) * (1.0f / (float)KDIM);
  float cd = 1.f - (2.f * A2 + 1e-5f) / (sump[n] + tsum[m] + 1e-5f);
  float cc = -probs[n * NCLS + tids[m]];

  float4 pb = reinterpret_cast<const float4*>(pboxes)[n];
  float4 tb = reinterpret_cast<const float4*>(tboxes)[m];
  float l1 = fabsf(pb.x - tb.x) + fabsf(pb.y - tb.y) + fabsf(pb.z - tb.z) + fabsf(pb.w - tb.w);
  float px1 = pb.x - 0.5f * pb.z, py1 = pb.y - 0.5f * pb.w;
  float px2 = pb.x + 0.5f * pb.z, py2 = pb.y + 0.5f * pb.w;
  float tx1 = tb.x - 0.5f * tb.z, ty1 = tb.y - 0.5f * tb.w;
  float tx2 = tb.x + 0.5f * tb.z, ty2 = tb.y + 0.5f * tb.w;
  float a1 = (px2 - px1) * (py2 - py1);
  float a2 = (tx2 - tx1) * (ty2 - ty1);
  float iw = fmaxf(fminf(px2, tx2) - fmaxf(px1, tx1), 0.f);
  float ih = fmaxf(fminf(py2, ty2) - fmaxf(py1, ty1), 0.f);
  float inter = iw * ih;
  float uni = a1 + a2 - inter;
  float iou = inter / uni;
  float ew = fmaxf(fmaxf(px2, tx2) - fminf(px1, tx1), 0.f);
  float eh = fmaxf(fmaxf(py2, ty2) - fminf(py1, ty1), 0.f);
  float ae = ew * eh;
  float giou = iou - (ae - uni) / ae;

  out[idx] = 5.f * l1 + 2.f * (-giou) + 2.f * cc + 5.f * cm + 5.f * cd;
}

// =====================================================================
// FALLBACK PATH (only if ws too small)
// =====================================================================

__device__ __forceinline__ float sigf(float x) {
  return 1.f / (1.f + __expf(-x));
}

__global__ void resize_lin(const float* __restrict__ tm, ushort* __restrict__ T,
                           float* __restrict__ tsum) {
  int m = blockIdx.x;
  int p = blockIdx.y * 256 + threadIdx.x;
  int y = p / 160;
  int x = p - y * 160;
  float wy[4], wx[4];
  int jy0, jx0;
  {
    float s = (y + 0.5f) * 1.6f - 0.5f;
    jy0 = (int)ceilf(s - 1.6f);
    float ws = 0.f;
#pragma unroll
    for (int a = 0; a < 4; ++a) {
      int j = jy0 + a;
      float w = fmaxf(0.f, 1.f - fabsf((float)j - s) * 0.625f);
      if (j < 0 || j > 255) w = 0.f;
      wy[a] = w; ws += w;
    }
    float inv = 1.f / ws;
#pragma unroll
    for (int a = 0; a < 4; ++a) wy[a] *= inv;
  }
  {
    float s = (x + 0.5f) * 1.6f - 0.5f;
    jx0 = (int)ceilf(s - 1.6f);
    float ws = 0.f;
#pragma unroll
    for (int b = 0; b < 4; ++b) {
      int j = jx0 + b;
      float w = fmaxf(0.f, 1.f - fabsf((float)j - s) * 0.625f);
      if (j < 0 || j > 255) w = 0.f;
      wx[b] = w; ws += w;
    }
    float inv = 1.f / ws;
#pragma unroll
    for (int b = 0; b < 4; ++b) wx[b] *= inv;
  }
  const float* base = tm + (size_t)m * 65536;
  float acc = 0.f;
#pragma unroll
  for (int a = 0; a < 4; ++a) {
    int jy = min(max(jy0 + a, 0), 255);
    float wya = wy[a];
#pragma unroll
    for (int b = 0; b < 4; ++b) {
      int jx = min(max(jx0 + b, 0), 255);
      acc += wya * wx[b] * base[jy * 256 + jx];
    }
  }
  T[(size_t)m * KDIM + p] = f2bf(acc);
  float v = acc;
#pragma unroll
  for (int o = 32; o > 0; o >>= 1) v += __shfl_down(v, o, 64);
  __shared__ float red[4];
  int wid = threadIdx.x >> 6;
  if ((threadIdx.x & 63) == 0) red[wid] = v;
  __syncthreads();
  if (threadIdx.x == 0) atomicAdd(&tsum[m], red[0] + red[1] + red[2] + red[3]);
}

__global__ void stats_kernel(const float* __restrict__ pm, float* __restrict__ S,
                             float* __restrict__ sump) {
  int n = blockIdx.x;
  const float4* row = reinterpret_cast<const float4*>(pm + (size_t)n * KDIM);
  float ssp = 0.f, sp = 0.f;
  for (int i = threadIdx.x; i < KDIM / 4; i += 256) {
    float4 v = row[i];
    float xs[4] = {v.x, v.y, v.z, v.w};
#pragma unroll
    for (int j = 0; j < 4; ++j) {
      float x = xs[j];
      float e = __expf(-fabsf(x));
      float inv1pe = 1.f / (1.f + e);
      sp += (x >= 0.f) ? inv1pe : e * inv1pe;
      ssp += fmaxf(x, 0.f) + log1pf(e);
    }
  }
#pragma unroll
  for (int o = 32; o > 0; o >>= 1) {
    ssp += __shfl_down(ssp, o, 64);
    sp  += __shfl_down(sp, o, 64);
  }
  __shared__ float red[8];
  int wid = threadIdx.x >> 6;
  if ((threadIdx.x & 63) == 0) { red[wid] = ssp; red[4 + wid] = sp; }
  __syncthreads();
  if (threadIdx.x == 0) {
    S[n]    = -(red[0] + red[1] + red[2] + red[3]);
    sump[n] = red[4] + red[5] + red[6] + red[7];
  }
}

__device__ __forceinline__ bf16x8 load_frag_lin(const ushort* p) {
  union { ushort4 u[2]; bf16x8 f; } fr;
  fr.u[0] = *reinterpret_cast<const ushort4*>(p);
  fr.u[1] = *reinterpret_cast<const ushort4*>(p + 4);
  return fr.f;
}

__global__ __launch_bounds__(256) void gemm_fused(
    const float* __restrict__ pm, const ushort* __restrict__ T,
    ushort* __restrict__ part1, ushort* __restrict__ part2, int k_per) {
  __shared__ ushort Ax[64][40];
  __shared__ ushort Ap[64][40];
  __shared__ ushort Bs[64][40];
  int n0 = blockIdx.x * 64;
  int m0 = blockIdx.y * 64;
  int kz = blockIdx.z;
  int k_begin = kz * k_per;
  int t = threadIdx.x;
  int r = t >> 2;
  int q = t & 3;
  bool a_ok = (n0 + r) < N_PRED;
  bool b_ok = (m0 + r) < M_TGT;
  const float*  pA = pm + (size_t)(n0 + r) * KDIM + k_begin + q * 8;
  const ushort* pB = T  + (size_t)(m0 + r) * KDIM + k_begin + q * 8;
  int lane = t & 63;
  int w = t >> 6;
  int wr = (w >> 1) * 32;
  int wc = (w & 1) * 32;
  int lrow = lane & 15;
  int kc = (lane >> 4) * 8;
  f32x4 zero = {0.f, 0.f, 0.f, 0.f};
  f32x4 acc1[2][2] = {{zero, zero}, {zero, zero}};
  f32x4 acc2[2][2] = {{zero, zero}, {zero, zero}};
  int steps = k_per / 32;
  for (int kt = 0; kt < steps; ++kt) {
    __syncthreads();
    float4 f0 = {0.f,0.f,0.f,0.f}, f1 = {0.f,0.f,0.f,0.f};
    if (a_ok) {
      f0 = *reinterpret_cast<const float4*>(pA);
      f1 = *reinterpret_cast<const float4*>(pA + 4);
    }
    pA += 32;
    ushort4 xa, xb, pa, pb4;
    xa.x = f2bf(f0.x); xa.y = f2bf(f0.y); xa.z = f2bf(f0.z); xa.w = f2bf(f0.w);
    xb.x = f2bf(f1.x); xb.y = f2bf(f1.y); xb.z = f2bf(f1.z); xb.w = f2bf(f1.w);
    pa.x = f2bf(sigf(f0.x)); pa.y = f2bf(sigf(f0.y)); pa.z = f2bf(sigf(f0.z)); pa.w = f2bf(sigf(f0.w));
    pb4.x = f2bf(sigf(f1.x)); pb4.y = f2bf(sigf(f1.y)); pb4.z = f2bf(sigf(f1.z)); pb4.w = f2bf(sigf(f1.w));
    *reinterpret_cast<ushort4*>(&Ax[r][q * 8])     = xa;
    *reinterpret_cast<ushort4*>(&Ax[r][q * 8 + 4]) = xb;
    *reinterpret_cast<ushort4*>(&Ap[r][q * 8])     = pa;
    *reinterpret_cast<ushort4*>(&Ap[r][q * 8 + 4]) = pb4;
    union { uint4 u; ushort4 s[2]; } bv;
    bv.u = make_uint4(0, 0, 0, 0);
    if (b_ok) bv.u = *reinterpret_cast<const uint4*>(pB);
    pB += 32;
    *reinterpret_cast<ushort4*>(&Bs[r][q * 8])     = bv.s[0];
    *reinterpret_cast<ushort4*>(&Bs[r][q * 8 + 4]) = bv.s[1];
    __syncthreads();
    bf16x8 ax[2], ap[2], bb[2];
#pragma unroll
    for (int i = 0; i < 2; ++i) {
      ax[i] = load_frag_lin(&Ax[wr + i * 16 + lrow][kc]);
      ap[i] = load_frag_lin(&Ap[wr + i * 16 + lrow][kc]);
      bb[i] = load_frag_lin(&Bs[wc + i * 16 + lrow][kc]);
    }
#pragma unroll
    for (int i = 0; i < 2; ++i)
#pragma unroll
      for (int j = 0; j < 2; ++j) {
        acc1[i][j] = __builtin_amdgcn_mfma_f32_16x16x32_bf16(ax[i], bb[j], acc1[i][j], 0, 0, 0);
        acc2[i][j] = __builtin_amdgcn_mfma_f32_16x16x32_bf16(ap[i], bb[j], acc2[i][j], 0, 0, 0);
      }
  }
  int rowb = (lane >> 4) * 4;
  int col = lane & 15;
#pragma unroll
  for (int i = 0; i < 2; ++i)
#pragma unroll
    for (int j = 0; j < 2; ++j)
#pragma unroll
      for (int rr = 0; rr < 4; ++rr) {
        int gn = n0 + wr + i * 16 + rowb + rr;
        int gm = m0 + wc + j * 16 + col;
        if (gn < N_PRED && gm < M_TGT) {
          size_t o = (size_t)kz * 480000 + (size_t)gn * 400 + gm;
          part1[o] = f2bf(acc1[i][j][rr]);
          part2[o] = f2bf(acc2[i][j][rr]);
        }
      }
}

__global__ void combine_fb(const ushort* __restrict__ part1, const ushort* __restrict__ part2,
                           const float* __restrict__ S, const float* __restrict__ sump,
                           const float* __restrict__ tsum, const float* __restrict__ probs,
                           const float* __restrict__ pboxes, const float* __restrict__ tboxes,
                           const int* __restrict__ tids, float* __restrict__ out, int KZ) {
  int idx = blockIdx.x * 256 + threadIdx.x;
  int n = idx / M_TGT;
  int m = idx - n * M_TGT;
  float A1 = 0.f, A2 = 0.f;
  for (int kz = 0; kz < KZ; ++kz) {
    A1 += bf2f(part1[(size_t)kz * 480000 + idx]);
    A2 += bf2f(part2[(size_t)kz * 480000 + idx]);
  }
  float cm = -(A1 + S[n]) * (1.0f / (float)KDIM);
  float cd = 1.f - (2.f * A2 + 1e-5f) / (sump[n] + tsum[m] + 1e-5f);
  float cc = -probs[n * NCLS + tids[m]];
  float4 pb = reinterpret_cast<const float4*>(pboxes)[n];
  float4 tb = reinterpret_cast<const float4*>(tboxes)[m];
  float l1 = fabsf(pb.x - tb.x) + fabsf(pb.y - tb.y) + fabsf(pb.z - tb.z) + fabsf(pb.w - tb.w);
  float px1 = pb.x - 0.5f * pb.z, py1 = pb.y - 0.5f * pb.w;
  float px2 = pb.x + 0.5f * pb.z, py2 = pb.y + 0.5f * pb.w;
  float tx1 = tb.x - 0.5f * tb.z, ty1 = tb.y - 0.5f * tb.w;
  float tx2 = tb.x + 0.5f * tb.z, ty2 = tb.y + 0.5f * tb.w;
  float a1 = (px2 - px1) * (py2 - py1);
  float a2 = (tx2 - tx1) * (ty2 - ty1);
  float iw = fmaxf(fminf(px2, tx2) - fmaxf(px1, tx1), 0.f);
  float ih = fmaxf(fminf(py2, ty2) - fmaxf(py1, ty1), 0.f);
  float inter = iw * ih;
  float uni = a1 + a2 - inter;
  float iou = inter / uni;
  float ew = fmaxf(fmaxf(px2, tx2) - fminf(px1, tx1), 0.f);
  float eh = fmaxf(fmaxf(py2, ty2) - fminf(py1, ty1), 0.f);
  float ae = ew * eh;
  float giou = iou - (ae - uni) / ae;
  out[idx] = 5.f * l1 + 2.f * (-giou) + 2.f * cc + 5.f * cm + 5.f * cd;
}

// =====================================================================

extern "C" void kernel_launch(void* const* d_in, const int* in_sizes, int n_in,
                              void* d_out, int out_size, void* d_ws, size_t ws_size,
                              hipStream_t stream) {
  const float* logits = (const float*)d_in[0];
  const float* pboxes = (const float*)d_in[1];
  const float* pmasks = (const float*)d_in[2];
  const float* tboxes = (const float*)d_in[3];
  const float* tmasks = (const float*)d_in[4];
  const int*   tids   = (const int*)d_in[5];
  float* out = (float*)d_out;
  char* ws = (char*)d_ws;

  // new-path workspace layout
  const size_t offT     = 0;                         // 400*28672 = 11,468,800 (fp8)
  const size_t offPart  = 24371200;                  // 2*13*1200*448*2 = 27,955,200
  const size_t offProbs = offPart + 27955200;        // 388,800
  const size_t offStats = offProbs + 390400;         // SP 4800 | sump 4800 | tsum 1600
  const size_t needNew  = offStats + 11200;

  if (ws_size >= needNew) {
    uchar* Tg    = (uchar*)(ws + offT);
    ushort* part = (ushort*)(ws + offPart);
    float* probs = (float*)(ws + offProbs);
    float* SP    = (float*)(ws + offStats);
    float* sump  = (float*)(ws + offStats + 4800);
    float* tsum  = (float*)(ws + offStats + 9600);

    hipMemsetAsync(SP, 0, 11200, stream);   // SP + sump + tsum
    resize2<<<dim3(M_TGT, 20), 256, 0, stream>>>(tmasks, Tg, tsum);
    ones_init<<<13, 256, 0, stream>>>(Tg);
    probs_kernel<<<N_PRED, 64, 0, stream>>>(logits, probs);
    gemm_mega<<<NBLK * KZN, 512, 0, stream>>>(pmasks, Tg, part, SP);
    sumprow<<<5, 256, 0, stream>>>(part, sump);
    combine2<<<1875, 256, 0, stream>>>(part, SP, sump, tsum, probs,
                                       pboxes, tboxes, tids, out);
  } else {
    // fallback (R4 pipeline)
    ushort* T     = (ushort*)ws;
    float*  probs = (float*)(ws + 20480000);
    float*  S     = (float*)(ws + 20868800);
    float*  sump  = (float*)(ws + 20873600);
    float*  tsum  = (float*)(ws + 20878400);
    ushort* part1 = (ushort*)(ws + 20880000);
    size_t need8 = 20880000ull + 2ull * 8 * 480000 * 2;
    int KZf = (ws_size >= need8) ? 8 : 1;
    ushort* part2 = part1 + (size_t)KZf * 480000;

    hipMemsetAsync(tsum, 0, M_TGT * sizeof(float), stream);
    resize_lin<<<dim3(M_TGT, 100), 256, 0, stream>>>(tmasks, T, tsum);
    probs_kernel<<<N_PRED, 64, 0, stream>>>(logits, probs);
    stats_kernel<<<N_PRED, 256, 0, stream>>>(pmasks, S, sump);
    gemm_fused<<<dim3(19, 7, KZf), 256, 0, stream>>>(pmasks, T, part1, part2, KDIM / KZf);
    combine_fb<<<1875, 256, 0, stream>>>(part1, part2, S, sump, tsum, probs,
                                         pboxes, tboxes, tids, out, KZf);
  }
}

// Round 17
// 128.422 us; speedup vs baseline: 4.6411x; 1.0420x over previous
//
#include <hip/hip_runtime.h>
#include <cstdint>

#define N_PRED 1200
#define M_TGT  400
#define KDIM   25600   // 160*160
#define NCLS   81
#define MPAD   448     // padded target count (28 x 16)
#define KZN    13      // split-K factor (5 kz with 32 steps + 8 kz with 30)
#define NBLK   38      // row blocks of 32 (1216 >= 1200)
#define TSLICE 28672   // BYTES per BK=64 step: 4(kq) * 448 * 16 (h-paired fp8)

typedef __attribute__((ext_vector_type(8)))  short bf16x8;
typedef __attribute__((ext_vector_type(4)))  float f32x4;
typedef unsigned char uchar;

__device__ __forceinline__ ushort f2bf(float f) {
  union { float f; uint32_t u; } v; v.f = f;
  uint32_t u = v.u + 0x7fffu + ((v.u >> 16) & 1u);
  return (ushort)(u >> 16);
}

__device__ __forceinline__ float bf2f(ushort s) {
  union { uint32_t u; float f; } v; v.u = ((uint32_t)s) << 16;
  return v.f;
}

// pack 4 f32 -> 4 fp8 e4m3 (OCP, saturating) in one u32
__device__ __forceinline__ uint32_t pk_fp8(float a, float b, float c, float d) {
  uint32_t v = (uint32_t)__builtin_amdgcn_cvt_pk_fp8_f32(a, b, 0, false);
  v = (uint32_t)__builtin_amdgcn_cvt_pk_fp8_f32(c, d, (int)v, true);
  return v;
}

__device__ __forceinline__ void gll16(const void* g, void* l) {
  __builtin_amdgcn_global_load_lds(
      (const __attribute__((address_space(1))) void*)g,
      (__attribute__((address_space(3))) void*)l, 16, 0, 0);
}

// =====================================================================
// Resize tgt_masks [400,256,256] -> T fp8 h-paired fragment-major:
// element with k-chunk kql (0..7) of step kt stored at
//   kt*TSLICE + ((kql&3)*MPAD + m)*16 + (kql>>2)*8
__global__ __launch_bounds__(256) void resize2(const float* __restrict__ tm,
                                               uchar* __restrict__ T,
                                               float* __restrict__ tsum) {
  __shared__ float rows[16][256];
  __shared__ float vbuf[8][256];

  int m = blockIdx.x, yt = blockIdx.y;  // yt 0..19
  int y0 = yt * 8;
  int t = threadIdx.x;

  int jbase = (int)ceilf((y0 + 0.5f) * 1.6f - 2.1f);

  const float* base = tm + (size_t)m * 65536;
  {
    int r = t >> 4;
    int c0 = (t & 15) * 16;
    int jr = min(max(jbase + r, 0), 255);
    const float4* src = reinterpret_cast<const float4*>(base + jr * 256 + c0);
#pragma unroll
    for (int i = 0; i < 4; ++i)
      *reinterpret_cast<float4*>(&rows[r][c0 + i * 4]) = src[i];
  }
  __syncthreads();

#pragma unroll
  for (int yy = 0; yy < 8; ++yy) {
    int y = y0 + yy;
    float s = (y + 0.5f) * 1.6f - 0.5f;
    int j0 = (int)ceilf(s - 1.6f);
    float w[4]; float wsum = 0.f;
#pragma unroll
    for (int a = 0; a < 4; ++a) {
      int j = j0 + a;
      float wv = fmaxf(0.f, 1.f - fabsf((float)j - s) * 0.625f);
      if (j < 0 || j > 255) wv = 0.f;
      w[a] = wv; wsum += wv;
    }
    float winv = __builtin_amdgcn_rcpf(wsum);
    float acc = 0.f;
    int rbase = j0 - jbase;
#pragma unroll
    for (int a = 0; a < 4; ++a) acc += w[a] * rows[rbase + a][t];
    vbuf[yy][t] = acc * winv;
  }
  __syncthreads();

  float bsum = 0.f;
  if (t < 160) {
    int yy = t / 20, ch = t - yy * 20;
    float o[8];
#pragma unroll
    for (int j = 0; j < 8; ++j) {
      int x = ch * 8 + j;
      float sx = (x + 0.5f) * 1.6f - 0.5f;
      int jx0 = (int)ceilf(sx - 1.6f);
      float wsum = 0.f, h = 0.f;
#pragma unroll
      for (int b = 0; b < 4; ++b) {
        int jj = jx0 + b;
        float wv = fmaxf(0.f, 1.f - fabsf((float)jj - sx) * 0.625f);
        if (jj < 0 || jj > 255) wv = 0.f;
        wsum += wv;
        h += wv * vbuf[yy][min(max(jj, 0), 255)];
      }
      h *= __builtin_amdgcn_rcpf(wsum);
      o[j] = h; bsum += h;
    }
    int p0 = (y0 + yy) * 160 + ch * 8;
    int kt = p0 >> 6, kql = (p0 >> 3) & 7;
    size_t a = (size_t)kt * TSLICE +
               ((size_t)((kql & 3) * MPAD + m)) * 16 + (kql >> 2) * 8;
    uint2 pk;
    pk.x = pk_fp8(o[0], o[1], o[2], o[3]);
    pk.y = pk_fp8(o[4], o[5], o[6], o[7]);
    *reinterpret_cast<uint2*>(&T[a]) = pk;
  }
#pragma unroll
  for (int o2 = 32; o2 > 0; o2 >>= 1) bsum += __shfl_down(bsum, o2, 64);
  __shared__ float red[4];
  int wid = t >> 6;
  if ((t & 63) == 0) red[wid] = bsum;
  __syncthreads();
  if (t == 0) atomicAdd(&tsum[m], red[0] + red[1] + red[2] + red[3]);
}

// ones column at m=400: fp8(1.0)=0x38 across all k-chunks
__global__ void ones_init(uchar* __restrict__ T) {
  int i = blockIdx.x * 256 + threadIdx.x;   // over 3200 = kt(400) * kql(8)
  if (i < 3200) {
    int kt = i >> 3, kql = i & 7;
    size_t a = (size_t)kt * TSLICE +
               ((size_t)((kql & 3) * MPAD + 400)) * 16 + (kql >> 2) * 8;
    uint2 v; v.x = 0x38383838u; v.y = 0x38383838u;
    *reinterpret_cast<uint2*>(&T[a]) = v;
  }
}

// =====================================================================
// Fused dual GEMM (fp8 e4m3) + conversion + softplus row-stats. BK=64,
// 1-barrier dbuf parity pipeline, h-paired layout: one ds_read_b128 per
// fragment PAIR (9 b128/wave/step feed 28 MFMA). KZN=13 -> 494 blocks =
// one co-resident generation (2 blocks/CU, no tail).
__global__ __launch_bounds__(512, 4) void gemm_mega(
    const float* __restrict__ pm, const uchar* __restrict__ Tg,
    ushort* __restrict__ part, float* __restrict__ SP) {
  __shared__ uchar buf[2][TSLICE];        // 57,344 B
  __shared__ uchar abuf[2][2][2048];      //  8,192 B  [dbuf][x/p][kq(4)][row(32)][16]

  // bijective XCD swizzle for nwg=494 (m204): q=61, r=6; kz-major chunks
  int orig = blockIdx.x;
  int xcd = orig & 7, base = orig >> 3;
  int wgid = (xcd < 6 ? xcd * 62 : 372 + (xcd - 6) * 61) + base;
  int kz = wgid / NBLK;
  int bn = wgid - kz * NBLK;
  int koff  = (kz < 5) ? (32 * kz) : (160 + 30 * (kz - 5));   // in BK=64 units
  int steps = (kz < 5) ? 32 : 30;

  int t = threadIdx.x, lane = t & 63, w = t >> 6;
  int rg = w >> 2, cg = w & 3;
  int l15 = lane & 15, kq = lane >> 4;

  bool is_b = (t < 256);

  int arow = t >> 4, kc4 = t & 15;       // row 0..31, float4 chunk 0..15
  int rowA = bn * 32 + arow;
  int rowAc = min(rowA, N_PRED - 1);
  const float* apf = pm + (size_t)rowAc * KDIM + koff * 64 + kc4 * 4;
  // write addr: kql = kc4>>1; ((kql&3)*32 + arow)*16 + (kql>>2)*8 + (kc4&1)*4
  int kqlw = kc4 >> 1;
  int awoff = ((kqlw & 3) * 32 + arow) * 16 + (kqlw >> 2) * 8 + (kc4 & 1) * 4;

  const uchar* tsrc = Tg + (size_t)koff * TSLICE;
  int bbase = (kq * MPAD + cg * 112 + l15) * 16;     // B frag-pair (byte), +j*256
  int afoff = (kq * 32 + rg * 16 + l15) * 16;        // A frag-pair (byte)

  f32x4 z = {0.f, 0.f, 0.f, 0.f};
  f32x4 acc1[7], acc2[7];
#pragma unroll
  for (int j = 0; j < 7; ++j) { acc1[j] = z; acc2[j] = z; }
  float stx = 0.f;

  union fragu4 { uint4 u; long long l[2]; };

#define WAITV(N) asm volatile("s_waitcnt vmcnt(" #N ")" ::: "memory")

// stage step ST into buf[BI]: 28 chunks x 1KB; 7 gll16 per staging thread.
#define STAGE_B(BI, ST)                                                        \
  do {                                                                         \
    const uchar* s_ = tsrc + (size_t)(ST) * TSLICE;                            \
    _Pragma("unroll")                                                          \
    for (int i_ = 0; i_ < 7; ++i_) {                                           \
      int c_ = w * 7 + i_;                                                     \
      gll16(s_ + c_ * 1024 + lane * 16, &buf[BI][c_ * 1024]);                  \
    }                                                                          \
  } while (0)

// convert 4 f32 (one float4) -> fp8 x/p + softplus stat; one b32 per array.
#define CONVERT(NI, V)                                                         \
  do {                                                                         \
    float xs_[4] = {V.x, V.y, V.z, V.w};                                       \
    float sg_[4];                                                              \
    _Pragma("unroll")                                                          \
    for (int q_ = 0; q_ < 4; ++q_) {                                           \
      float a_ = xs_[q_];                                                      \
      float e_ = __expf(-fabsf(a_));                                           \
      float o_ = 1.f + e_;                                                     \
      float i_ = __builtin_amdgcn_rcpf(o_);                                    \
      sg_[q_] = (a_ >= 0.f) ? i_ : e_ * i_;                                    \
      stx += fmaxf(a_, 0.f) + __logf(o_);                                      \
    }                                                                          \
    *reinterpret_cast<uint32_t*>(&abuf[NI][0][awoff]) =                        \
        pk_fp8(xs_[0], xs_[1], xs_[2], xs_[3]);                                \
    *reinterpret_cast<uint32_t*>(&abuf[NI][1][awoff]) =                        \
        pk_fp8(sg_[0], sg_[1], sg_[2], sg_[3]);                                \
  } while (0)

// ACUR = S&1 (compile-time). f(k): fA when k even, fB when k odd.
#define ITER(ACUR, S)                                                          \
  do {                                                                         \
    if (is_b) WAITV(0);             /* stage(S) issued a full step ago */      \
    if ((S) + 2 < steps) {          /* issue A load for S+2 (all threads) */   \
      float4 nv_ = *reinterpret_cast<const float4*>(apf + ((S) + 2) * 64);     \
      if (ACUR) fB = nv_; else fA = nv_;                                       \
    }                                                                          \
    __builtin_amdgcn_s_barrier();                                              \
    __builtin_amdgcn_sched_barrier(0);                                         \
    if ((S) + 1 < steps) {                                                     \
      if (is_b) STAGE_B(ACUR ^ 1, (S) + 1);                                    \
      if (ACUR) CONVERT(0, fA); else CONVERT(1, fB);                           \
    }                                                                          \
    {                                                                          \
      fragu4 ax_, ap_;                                                         \
      ax_.u = *reinterpret_cast<const uint4*>(&abuf[ACUR][0][afoff]);          \
      ap_.u = *reinterpret_cast<const uint4*>(&abuf[ACUR][1][afoff]);          \
      __builtin_amdgcn_s_setprio(1);                                           \
      _Pragma("unroll")                                                        \
      for (int j_ = 0; j_ < 7; ++j_) {                                         \
        fragu4 bv_;                                                            \
        bv_.u = *reinterpret_cast<const uint4*>(&buf[ACUR][bbase + j_ * 256]); \
        acc1[j_] = __builtin_amdgcn_mfma_f32_16x16x32_fp8_fp8(ax_.l[0], bv_.l[0], acc1[j_], 0, 0, 0); \
        acc2[j_] = __builtin_amdgcn_mfma_f32_16x16x32_fp8_fp8(ap_.l[0], bv_.l[0], acc2[j_], 0, 0, 0); \
        acc1[j_] = __builtin_amdgcn_mfma_f32_16x16x32_fp8_fp8(ax_.l[1], bv_.l[1], acc1[j_], 0, 0, 0); \
        acc2[j_] = __builtin_amdgcn_mfma_f32_16x16x32_fp8_fp8(ap_.l[1], bv_.l[1], acc2[j_], 0, 0, 0); \
      }                                                                        \
      __builtin_amdgcn_s_setprio(0);                                           \
    }                                                                          \
    asm volatile("s_waitcnt lgkmcnt(0)" ::: "memory");                         \
  } while (0)

  // ---- prologue: stage(0)->buf0; all: f(0) converted->abuf0, f(1)->fB ----
  float4 fA, fB;
  {
    float4 f0 = *reinterpret_cast<const float4*>(apf);
    fB = *reinterpret_cast<const float4*>(apf + 64);
    if (is_b) STAGE_B(0, 0);
    CONVERT(0, f0);
  }
  asm volatile("s_waitcnt lgkmcnt(0)" ::: "memory");

  for (int s = 0; s < steps; s += 2) {
    ITER(0, s);
    ITER(1, s + 1);
  }
#undef ITER
#undef CONVERT
#undef STAGE_B
#undef WAITV

  // ---- softplus row stats: 16 threads per row, xor-reduce width 16 ----
  stx += __shfl_xor(stx, 1, 16); stx += __shfl_xor(stx, 2, 16);
  stx += __shfl_xor(stx, 4, 16); stx += __shfl_xor(stx, 8, 16);
  if ((t & 15) == 0 && rowA < N_PRED)
    atomicAdd(SP + rowA, stx);

  // ---- store bf16 partials: part[arr][n][kz][MPAD] ----
  ushort* p1 = part;
  ushort* p2 = part + (size_t)KZN * 1200 * MPAD;
#pragma unroll
  for (int j = 0; j < 7; ++j)
#pragma unroll
    for (int rr = 0; rr < 4; ++rr) {
      int gn = bn * 32 + rg * 16 + kq * 4 + rr;   // C/D: row=(lane>>4)*4+reg
      if (gn < N_PRED) {
        int gm = cg * 112 + j * 16 + l15;         // col=lane&15
        size_t o = ((size_t)gn * KZN + kz) * MPAD + gm;
        p1[o] = f2bf(acc1[j][rr]);
        p2[o] = f2bf(acc2[j][rr]);
      }
    }
}

// sump[n] = sum over kz of A2 partial at ones-column (m=400)
__global__ void sumprow(const ushort* __restrict__ part, float* __restrict__ sump) {
  int n = blockIdx.x * 256 + threadIdx.x;
  if (n < N_PRED) {
    const ushort* p2 = part + (size_t)KZN * 1200 * MPAD + (size_t)n * KZN * MPAD + 400;
    float s = 0.f;
#pragma unroll
    for (int kz = 0; kz < KZN; ++kz) s += bf2f(p2[kz * MPAD]);
    sump[n] = s;
  }
}

// ---------------- softmax probs [1200,81] ----------------
__global__ void probs_kernel(const float* __restrict__ logits, float* __restrict__ probs) {
  int n = blockIdx.x;
  int l = threadIdx.x;
  const float* row = logits + n * NCLS;
  float v0 = row[l];
  bool has2 = (l + 64) < NCLS;
  float v1 = has2 ? row[l + 64] : -3.4e38f;
  float mx = fmaxf(v0, v1);
#pragma unroll
  for (int o = 1; o < 64; o <<= 1) mx = fmaxf(mx, __shfl_xor(mx, o, 64));
  float e0 = expf(v0 - mx);
  float e1 = has2 ? expf(v1 - mx) : 0.f;
  float sm = e0 + e1;
#pragma unroll
  for (int o = 1; o < 64; o <<= 1) sm += __shfl_xor(sm, o, 64);
  float inv = 1.f / sm;
  probs[n * NCLS + l] = e0 * inv;
  if (has2) probs[n * NCLS + l + 64] = e1 * inv;
}

// ---------------- final combine (bf16 partials, [n][kz][MPAD] layout) ----------------
__global__ void combine2(const ushort* __restrict__ part,
                         const float* __restrict__ SP, const float* __restrict__ sump,
                         const float* __restrict__ tsum, const float* __restrict__ probs,
                         const float* __restrict__ pboxes, const float* __restrict__ tboxes,
                         const int* __restrict__ tids, float* __restrict__ out) {
  int idx = blockIdx.x * 256 + threadIdx.x;   // < 480000
  int n = idx / M_TGT;
  int m = idx - n * M_TGT;

  const ushort* p1 = part + (size_t)n * (KZN * MPAD) + m;
  const ushort* p2 = p1 + (size_t)KZN * 1200 * MPAD;
  float A1 = 0.f, A2 = 0.f;
#pragma unroll
  for (int kz = 0; kz < KZN; ++kz) {
    A1 += bf2f(p1[kz * MPAD]);
    A2 += bf2f(p2[kz * MPAD]);
  }
  float cm = (SP[n] - A1) * (1.0f / (float)KDIM);
  float cd = 1.f - (2.f * A2 + 1e-5f) / (sump[n] + tsum[m] + 1e-5f);
  float cc = -probs[n * NCLS + tids[m]];

  float4 pb = reinterpret_cast<const float4*>(pboxes)[n];
  float4 tb = reinterpret_cast<const float4*>(tboxes)[m];
  float l1 = fabsf(pb.x - tb.x) + fabsf(pb.y - tb.y) + fabsf(pb.z - tb.z) + fabsf(pb.w - tb.w);
  float px1 = pb.x - 0.5f * pb.z, py1 = pb.y - 0.5f * pb.w;
  float px2 = pb.x + 0.5f * pb.z, py2 = pb.y + 0.5f * pb.w;
  float tx1 = tb.x - 0.5f * tb.z, ty1 = tb.y - 0.5f * tb.w;
  float tx2 = tb.x + 0.5f * tb.z, ty2 = tb.y + 0.5f * tb.w;
  float a1 = (px2 - px1) * (py2 - py1);
  float a2 = (tx2 - tx1) * (ty2 - ty1);
  float iw = fmaxf(fminf(px2, tx2) - fmaxf(px1, tx1), 0.f);
  float ih = fmaxf(fminf(py2, ty2) - fmaxf(py1, ty1), 0.f);
  float inter = iw * ih;
  float uni = a1 + a2 - inter;
  float iou = inter / uni;
  float ew = fmaxf(fmaxf(px2, tx2) - fminf(px1, tx1), 0.f);
  float eh = fmaxf(fmaxf(py2, ty2) - fminf(py1, ty1), 0.f);
  float ae = ew * eh;
  float giou = iou - (ae - uni) / ae;

  out[idx] = 5.f * l1 + 2.f * (-giou) + 2.f * cc + 5.f * cm + 5.f * cd;
}

// =====================================================================
// FALLBACK PATH (only if ws too small)
// =====================================================================

__device__ __forceinline__ float sigf(float x) {
  return 1.f / (1.f + __expf(-x));
}

__global__ void resize_lin(const float* __restrict__ tm, ushort* __restrict__ T,
                           float* __restrict__ tsum) {
  int m = blockIdx.x;
  int p = blockIdx.y * 256 + threadIdx.x;
  int y = p / 160;
  int x = p - y * 160;
  float wy[4], wx[4];
  int jy0, jx0;
  {
    float s = (y + 0.5f) * 1.6f - 0.5f;
    jy0 = (int)ceilf(s - 1.6f);
    float ws = 0.f;
#pragma unroll
    for (int a = 0; a < 4; ++a) {
      int j = jy0 + a;
      float w = fmaxf(0.f, 1.f - fabsf((float)j - s) * 0.625f);
      if (j < 0 || j > 255) w = 0.f;
      wy[a] = w; ws += w;
    }
    float inv = 1.f / ws;
#pragma unroll
    for (int a = 0; a < 4; ++a) wy[a] *= inv;
  }
  {
    float s = (x + 0.5f) * 1.6f - 0.5f;
    jx0 = (int)ceilf(s - 1.6f);
    float ws = 0.f;
#pragma unroll
    for (int b = 0; b < 4; ++b) {
      int j = jx0 + b;
      float w = fmaxf(0.f, 1.f - fabsf((float)j - s) * 0.625f);
      if (j < 0 || j > 255) w = 0.f;
      wx[b] = w; ws += w;
    }
    float inv = 1.f / ws;
#pragma unroll
    for (int b = 0; b < 4; ++b) wx[b] *= inv;
  }
  const float* base = tm + (size_t)m * 65536;
  float acc = 0.f;
#pragma unroll
  for (int a = 0; a < 4; ++a) {
    int jy = min(max(jy0 + a, 0), 255);
    float wya = wy[a];
#pragma unroll
    for (int b = 0; b < 4; ++b) {
      int jx = min(max(jx0 + b, 0), 255);
      acc += wya * wx[b] * base[jy * 256 + jx];
    }
  }
  T[(size_t)m * KDIM + p] = f2bf(acc);
  float v = acc;
#pragma unroll
  for (int o = 32; o > 0; o >>= 1) v += __shfl_down(v, o, 64);
  __shared__ float red[4];
  int wid = threadIdx.x >> 6;
  if ((threadIdx.x & 63) == 0) red[wid] = v;
  __syncthreads();
  if (threadIdx.x == 0) atomicAdd(&tsum[m], red[0] + red[1] + red[2] + red[3]);
}

__global__ void stats_kernel(const float* __restrict__ pm, float* __restrict__ S,
                             float* __restrict__ sump) {
  int n = blockIdx.x;
  const float4* row = reinterpret_cast<const float4*>(pm + (size_t)n * KDIM);
  float ssp = 0.f, sp = 0.f;
  for (int i = threadIdx.x; i < KDIM / 4; i += 256) {
    float4 v = row[i];
    float xs[4] = {v.x, v.y, v.z, v.w};
#pragma unroll
    for (int j = 0; j < 4; ++j) {
      float x = xs[j];
      float e = __expf(-fabsf(x));
      float inv1pe = 1.f / (1.f + e);
      sp += (x >= 0.f) ? inv1pe : e * inv1pe;
      ssp += fmaxf(x, 0.f) + log1pf(e);
    }
  }
#pragma unroll
  for (int o = 32; o > 0; o >>= 1) {
    ssp += __shfl_down(ssp, o, 64);
    sp  += __shfl_down(sp, o, 64);
  }
  __shared__ float red[8];
  int wid = threadIdx.x >> 6;
  if ((threadIdx.x & 63) == 0) { red[wid] = ssp; red[4 + wid] = sp; }
  __syncthreads();
  if (threadIdx.x == 0) {
    S[n]    = -(red[0] + red[1] + red[2] + red[3]);
    sump[n] = red[4] + red[5] + red[6] + red[7];
  }
}

__device__ __forceinline__ bf16x8 load_frag_lin(const ushort* p) {
  union { ushort4 u[2]; bf16x8 f; } fr;
  fr.u[0] = *reinterpret_cast<const ushort4*>(p);
  fr.u[1] = *reinterpret_cast<const ushort4*>(p + 4);
  return fr.f;
}

__global__ __launch_bounds__(256) void gemm_fused(
    const float* __restrict__ pm, const ushort* __restrict__ T,
    ushort* __restrict__ part1, ushort* __restrict__ part2, int k_per) {
  __shared__ ushort Ax[64][40];
  __shared__ ushort Ap[64][40];
  __shared__ ushort Bs[64][40];
  int n0 = blockIdx.x * 64;
  int m0 = blockIdx.y * 64;
  int kz = blockIdx.z;
  int k_begin = kz * k_per;
  int t = threadIdx.x;
  int r = t >> 2;
  int q = t & 3;
  bool a_ok = (n0 + r) < N_PRED;
  bool b_ok = (m0 + r) < M_TGT;
  const float*  pA = pm + (size_t)(n0 + r) * KDIM + k_begin + q * 8;
  const ushort* pB = T  + (size_t)(m0 + r) * KDIM + k_begin + q * 8;
  int lane = t & 63;
  int w = t >> 6;
  int wr = (w >> 1) * 32;
  int wc = (w & 1) * 32;
  int lrow = lane & 15;
  int kc = (lane >> 4) * 8;
  f32x4 zero = {0.f, 0.f, 0.f, 0.f};
  f32x4 acc1[2][2] = {{zero, zero}, {zero, zero}};
  f32x4 acc2[2][2] = {{zero, zero}, {zero, zero}};
  int steps = k_per / 32;
  for (int kt = 0; kt < steps; ++kt) {
    __syncthreads();
    float4 f0 = {0.f,0.f,0.f,0.f}, f1 = {0.f,0.f,0.f,0.f};
    if (a_ok) {
      f0 = *reinterpret_cast<const float4*>(pA);
      f1 = *reinterpret_cast<const float4*>(pA + 4);
    }
    pA += 32;
    ushort4 xa, xb, pa, pb4;
    xa.x = f2bf(f0.x); xa.y = f2bf(f0.y); xa.z = f2bf(f0.z); xa.w = f2bf(f0.w);
    xb.x = f2bf(f1.x); xb.y = f2bf(f1.y); xb.z = f2bf(f1.z); xb.w = f2bf(f1.w);
    pa.x = f2bf(sigf(f0.x)); pa.y = f2bf(sigf(f0.y)); pa.z = f2bf(sigf(f0.z)); pa.w = f2bf(sigf(f0.w));
    pb4.x = f2bf(sigf(f1.x)); pb4.y = f2bf(sigf(f1.y)); pb4.z = f2bf(sigf(f1.z)); pb4.w = f2bf(sigf(f1.w));
    *reinterpret_cast<ushort4*>(&Ax[r][q * 8])     = xa;
    *reinterpret_cast<ushort4*>(&Ax[r][q * 8 + 4]) = xb;
    *reinterpret_cast<ushort4*>(&Ap[r][q * 8])     = pa;
    *reinterpret_cast<ushort4*>(&Ap[r][q * 8 + 4]) = pb4;
    union { uint4 u; ushort4 s[2]; } bv;
    bv.u = make_uint4(0, 0, 0, 0);
    if (b_ok) bv.u = *reinterpret_cast<const uint4*>(pB);
    pB += 32;
    *reinterpret_cast<ushort4*>(&Bs[r][q * 8])     = bv.s[0];
    *reinterpret_cast<ushort4*>(&Bs[r][q * 8 + 4]) = bv.s[1];
    __syncthreads();
    bf16x8 ax[2], ap[2], bb[2];
#pragma unroll
    for (int i = 0; i < 2; ++i) {
      ax[i] = load_frag_lin(&Ax[wr + i * 16 + lrow][kc]);
      ap[i] = load_frag_lin(&Ap[wr + i * 16 + lrow][kc]);
      bb[i] = load_frag_lin(&Bs[wc + i * 16 + lrow][kc]);
    }
#pragma unroll
    for (int i = 0; i < 2; ++i)
#pragma unroll
      for (int j = 0; j < 2; ++j) {
        acc1[i][j] = __builtin_amdgcn_mfma_f32_16x16x32_bf16(ax[i], bb[j], acc1[i][j], 0, 0, 0);
        acc2[i][j] = __builtin_amdgcn_mfma_f32_16x16x32_bf16(ap[i], bb[j], acc2[i][j], 0, 0, 0);
      }
  }
  int rowb = (lane >> 4) * 4;
  int col = lane & 15;
#pragma unroll
  for (int i = 0; i < 2; ++i)
#pragma unroll
    for (int j = 0; j < 2; ++j)
#pragma unroll
      for (int rr = 0; rr < 4; ++rr) {
        int gn = n0 + wr + i * 16 + rowb + rr;
        int gm = m0 + wc + j * 16 + col;
        if (gn < N_PRED && gm < M_TGT) {
          size_t o = (size_t)kz * 480000 + (size_t)gn * 400 + gm;
          part1[o] = f2bf(acc1[i][j][rr]);
          part2[o] = f2bf(acc2[i][j][rr]);
        }
      }
}

__global__ void combine_fb(const ushort* __restrict__ part1, const ushort* __restrict__ part2,
                           const float* __restrict__ S, const float* __restrict__ sump,
                           const float* __restrict__ tsum, const float* __restrict__ probs,
                           const float* __restrict__ pboxes, const float* __restrict__ tboxes,
                           const int* __restrict__ tids, float* __restrict__ out, int KZ) {
  int idx = blockIdx.x * 256 + threadIdx.x;
  int n = idx / M_TGT;
  int m = idx - n * M_TGT;
  float A1 = 0.f, A2 = 0.f;
  for (int kz = 0; kz < KZ; ++kz) {
    A1 += bf2f(part1[(size_t)kz * 480000 + idx]);
    A2 += bf2f(part2[(size_t)kz * 480000 + idx]);
  }
  float cm = -(A1 + S[n]) * (1.0f / (float)KDIM);
  float cd = 1.f - (2.f * A2 + 1e-5f) / (sump[n] + tsum[m] + 1e-5f);
  float cc = -probs[n * NCLS + tids[m]];
  float4 pb = reinterpret_cast<const float4*>(pboxes)[n];
  float4 tb = reinterpret_cast<const float4*>(tboxes)[m];
  float l1 = fabsf(pb.x - tb.x) + fabsf(pb.y - tb.y) + fabsf(pb.z - tb.z) + fabsf(pb.w - tb.w);
  float px1 = pb.x - 0.5f * pb.z, py1 = pb.y - 0.5f * pb.w;
  float px2 = pb.x + 0.5f * pb.z, py2 = pb.y + 0.5f * pb.w;
  float tx1 = tb.x - 0.5f * tb.z, ty1 = tb.y - 0.5f * tb.w;
  float tx2 = tb.x + 0.5f * tb.z, ty2 = tb.y + 0.5f * tb.w;
  float a1 = (px2 - px1) * (py2 - py1);
  float a2 = (tx2 - tx1) * (ty2 - ty1);
  float iw = fmaxf(fminf(px2, tx2) - fmaxf(px1, tx1), 0.f);
  float ih = fmaxf(fminf(py2, ty2) - fmaxf(py1, ty1), 0.f);
  float inter = iw * ih;
  float uni = a1 + a2 - inter;
  float iou = inter / uni;
  float ew = fmaxf(fmaxf(px2, tx2) - fminf(px1, tx1), 0.f);
  float eh = fmaxf(fmaxf(py2, ty2) - fminf(py1, ty1), 0.f);
  float ae = ew * eh;
  float giou = iou - (ae - uni) / ae;
  out[idx] = 5.f * l1 + 2.f * (-giou) + 2.f * cc + 5.f * cm + 5.f * cd;
}

// =====================================================================

extern "C" void kernel_launch(void* const* d_in, const int* in_sizes, int n_in,
                              void* d_out, int out_size, void* d_ws, size_t ws_size,
                              hipStream_t stream) {
  const float* logits = (const float*)d_in[0];
  const float* pboxes = (const float*)d_in[1];
  const float* pmasks = (const float*)d_in[2];
  const float* tboxes = (const float*)d_in[3];
  const float* tmasks = (const float*)d_in[4];
  const int*   tids   = (const int*)d_in[5];
  float* out = (float*)d_out;
  char* ws = (char*)d_ws;

  // new-path workspace layout
  const size_t offT     = 0;                         // 400*28672 = 11,468,800 (fp8)
  const size_t offPart  = 24371200;                  // 2*13*1200*448*2 = 27,955,200
  const size_t offProbs = offPart + 27955200;        // 388,800
  const size_t offStats = offProbs + 390400;         // SP 4800 | sump 4800 | tsum 1600
  const size_t needNew  = offStats + 11200;

  if (ws_size >= needNew) {
    uchar* Tg    = (uchar*)(ws + offT);
    ushort* part = (ushort*)(ws + offPart);
    float* probs = (float*)(ws + offProbs);
    float* SP    = (float*)(ws + offStats);
    float* sump  = (float*)(ws + offStats + 4800);
    float* tsum  = (float*)(ws + offStats + 9600);

    hipMemsetAsync(SP, 0, 11200, stream);   // SP + sump + tsum
    resize2<<<dim3(M_TGT, 20), 256, 0, stream>>>(tmasks, Tg, tsum);
    ones_init<<<13, 256, 0, stream>>>(Tg);
    probs_kernel<<<N_PRED, 64, 0, stream>>>(logits, probs);
    gemm_mega<<<NBLK * KZN, 512, 0, stream>>>(pmasks, Tg, part, SP);
    sumprow<<<5, 256, 0, stream>>>(part, sump);
    combine2<<<1875, 256, 0, stream>>>(part, SP, sump, tsum, probs,
                                       pboxes, tboxes, tids, out);
  } else {
    // fallback (R4 pipeline)
    ushort* T     = (ushort*)ws;
    float*  probs = (float*)(ws + 20480000);
    float*  S     = (float*)(ws + 20868800);
    float*  sump  = (float*)(ws + 20873600);
    float*  tsum  = (float*)(ws + 20878400);
    ushort* part1 = (ushort*)(ws + 20880000);
    size_t need8 = 20880000ull + 2ull * 8 * 480000 * 2;
    int KZf = (ws_size >= need8) ? 8 : 1;
    ushort* part2 = part1 + (size_t)KZf * 480000;

    hipMemsetAsync(tsum, 0, M_TGT * sizeof(float), stream);
    resize_lin<<<dim3(M_TGT, 100), 256, 0, stream>>>(tmasks, T, tsum);
    probs_kernel<<<N_PRED, 64, 0, stream>>>(logits, probs);
    stats_kernel<<<N_PRED, 256, 0, stream>>>(pmasks, S, sump);
    gemm_fused<<<dim3(19, 7, KZf), 256, 0, stream>>>(pmasks, T, part1, part2, KDIM / KZf);
    combine_fb<<<1875, 256, 0, stream>>>(part1, part2, S, sump, tsum, probs,
                                         pboxes, tboxes, tids, out, KZf);
  }
}

// Round 18
// 121.803 us; speedup vs baseline: 4.8933x; 1.0543x over previous
//
#include <hip/hip_runtime.h>
#include <cstdint>

#define N_PRED 1200
#define M_TGT  400
#define KDIM   25600   // 160*160
#define NCLS   81
#define MPAD   448     // padded target count (28 x 16)
#define KZN    13      // split-K factor (5 kz with 32 steps + 8 kz with 30)
#define NBLK   38      // row blocks of 32 (1216 >= 1200)
#define TSLICE 28672   // BYTES per BK=64 step: 4(kq) * 448 * 16 (h-paired fp8)

typedef __attribute__((ext_vector_type(8)))  short bf16x8;
typedef __attribute__((ext_vector_type(4)))  float f32x4;
typedef unsigned char uchar;

__device__ __forceinline__ ushort f2bf(float f) {
  union { float f; uint32_t u; } v; v.f = f;
  uint32_t u = v.u + 0x7fffu + ((v.u >> 16) & 1u);
  return (ushort)(u >> 16);
}

__device__ __forceinline__ float bf2f(ushort s) {
  union { uint32_t u; float f; } v; v.u = ((uint32_t)s) << 16;
  return v.f;
}

// pack 4 f32 -> 4 fp8 e4m3 (OCP, saturating) in one u32
__device__ __forceinline__ uint32_t pk_fp8(float a, float b, float c, float d) {
  uint32_t v = (uint32_t)__builtin_amdgcn_cvt_pk_fp8_f32(a, b, 0, false);
  v = (uint32_t)__builtin_amdgcn_cvt_pk_fp8_f32(c, d, (int)v, true);
  return v;
}

__device__ __forceinline__ void gll16(const void* g, void* l) {
  __builtin_amdgcn_global_load_lds(
      (const __attribute__((address_space(1))) void*)g,
      (__attribute__((address_space(3))) void*)l, 16, 0, 0);
}

// =====================================================================
// Resize tgt_masks [400,256,256] -> T fp8 h-paired fragment-major:
// element with k-chunk kql (0..7) of step kt stored at
//   kt*TSLICE + ((kql&3)*MPAD + m)*16 + (kql>>2)*8
// Block (0,0) additionally initializes the ones-column (m=400) so
// A2[:,400] = row-sum of p (free sump via GEMM).
__global__ __launch_bounds__(256) void resize2(const float* __restrict__ tm,
                                               uchar* __restrict__ T,
                                               float* __restrict__ tsum) {
  __shared__ float rows[16][256];
  __shared__ float vbuf[8][256];

  int m = blockIdx.x, yt = blockIdx.y;  // yt 0..19
  int y0 = yt * 8;
  int t = threadIdx.x;

  // fused ones_init (disjoint m=400 column; no race with resize writes)
  if (m == 0 && yt == 0) {
    for (int i = t; i < 3200; i += 256) {
      int kt = i >> 3, kql = i & 7;
      size_t a = (size_t)kt * TSLICE +
                 ((size_t)((kql & 3) * MPAD + 400)) * 16 + (kql >> 2) * 8;
      uint2 v; v.x = 0x38383838u; v.y = 0x38383838u;
      *reinterpret_cast<uint2*>(&T[a]) = v;
    }
  }

  int jbase = (int)ceilf((y0 + 0.5f) * 1.6f - 2.1f);

  const float* base = tm + (size_t)m * 65536;
  {
    int r = t >> 4;
    int c0 = (t & 15) * 16;
    int jr = min(max(jbase + r, 0), 255);
    const float4* src = reinterpret_cast<const float4*>(base + jr * 256 + c0);
#pragma unroll
    for (int i = 0; i < 4; ++i)
      *reinterpret_cast<float4*>(&rows[r][c0 + i * 4]) = src[i];
  }
  __syncthreads();

#pragma unroll
  for (int yy = 0; yy < 8; ++yy) {
    int y = y0 + yy;
    float s = (y + 0.5f) * 1.6f - 0.5f;
    int j0 = (int)ceilf(s - 1.6f);
    float w[4]; float wsum = 0.f;
#pragma unroll
    for (int a = 0; a < 4; ++a) {
      int j = j0 + a;
      float wv = fmaxf(0.f, 1.f - fabsf((float)j - s) * 0.625f);
      if (j < 0 || j > 255) wv = 0.f;
      w[a] = wv; wsum += wv;
    }
    float winv = __builtin_amdgcn_rcpf(wsum);
    float acc = 0.f;
    int rbase = j0 - jbase;
#pragma unroll
    for (int a = 0; a < 4; ++a) acc += w[a] * rows[rbase + a][t];
    vbuf[yy][t] = acc * winv;
  }
  __syncthreads();

  float bsum = 0.f;
  if (t < 160) {
    int yy = t / 20, ch = t - yy * 20;
    float o[8];
#pragma unroll
    for (int j = 0; j < 8; ++j) {
      int x = ch * 8 + j;
      float sx = (x + 0.5f) * 1.6f - 0.5f;
      int jx0 = (int)ceilf(sx - 1.6f);
      float wsum = 0.f, h = 0.f;
#pragma unroll
      for (int b = 0; b < 4; ++b) {
        int jj = jx0 + b;
        float wv = fmaxf(0.f, 1.f - fabsf((float)jj - sx) * 0.625f);
        if (jj < 0 || jj > 255) wv = 0.f;
        wsum += wv;
        h += wv * vbuf[yy][min(max(jj, 0), 255)];
      }
      h *= __builtin_amdgcn_rcpf(wsum);
      o[j] = h; bsum += h;
    }
    int p0 = (y0 + yy) * 160 + ch * 8;
    int kt = p0 >> 6, kql = (p0 >> 3) & 7;
    size_t a = (size_t)kt * TSLICE +
               ((size_t)((kql & 3) * MPAD + m)) * 16 + (kql >> 2) * 8;
    uint2 pk;
    pk.x = pk_fp8(o[0], o[1], o[2], o[3]);
    pk.y = pk_fp8(o[4], o[5], o[6], o[7]);
    *reinterpret_cast<uint2*>(&T[a]) = pk;
  }
#pragma unroll
  for (int o2 = 32; o2 > 0; o2 >>= 1) bsum += __shfl_down(bsum, o2, 64);
  __shared__ float red[4];
  int wid = t >> 6;
  if ((t & 63) == 0) red[wid] = bsum;
  __syncthreads();
  if (t == 0) atomicAdd(&tsum[m], red[0] + red[1] + red[2] + red[3]);
}

// =====================================================================
// Fused dual GEMM (fp8 e4m3) + conversion + softplus row-stats. BK=64,
// 1-barrier dbuf parity pipeline, h-paired layout: one ds_read_b128 per
// fragment PAIR. KZN=13 -> 494 blocks = one co-resident generation.
// (UNCHANGED from R17 — proven codegen.)
__global__ __launch_bounds__(512, 4) void gemm_mega(
    const float* __restrict__ pm, const uchar* __restrict__ Tg,
    ushort* __restrict__ part, float* __restrict__ SP) {
  __shared__ uchar buf[2][TSLICE];        // 57,344 B
  __shared__ uchar abuf[2][2][2048];      //  8,192 B  [dbuf][x/p][kq(4)][row(32)][16]

  // bijective XCD swizzle for nwg=494 (m204): q=61, r=6; kz-major chunks
  int orig = blockIdx.x;
  int xcd = orig & 7, base = orig >> 3;
  int wgid = (xcd < 6 ? xcd * 62 : 372 + (xcd - 6) * 61) + base;
  int kz = wgid / NBLK;
  int bn = wgid - kz * NBLK;
  int koff  = (kz < 5) ? (32 * kz) : (160 + 30 * (kz - 5));   // in BK=64 units
  int steps = (kz < 5) ? 32 : 30;

  int t = threadIdx.x, lane = t & 63, w = t >> 6;
  int rg = w >> 2, cg = w & 3;
  int l15 = lane & 15, kq = lane >> 4;

  bool is_b = (t < 256);

  int arow = t >> 4, kc4 = t & 15;       // row 0..31, float4 chunk 0..15
  int rowA = bn * 32 + arow;
  int rowAc = min(rowA, N_PRED - 1);
  const float* apf = pm + (size_t)rowAc * KDIM + koff * 64 + kc4 * 4;
  int kqlw = kc4 >> 1;
  int awoff = ((kqlw & 3) * 32 + arow) * 16 + (kqlw >> 2) * 8 + (kc4 & 1) * 4;

  const uchar* tsrc = Tg + (size_t)koff * TSLICE;
  int bbase = (kq * MPAD + cg * 112 + l15) * 16;     // B frag-pair (byte), +j*256
  int afoff = (kq * 32 + rg * 16 + l15) * 16;        // A frag-pair (byte)

  f32x4 z = {0.f, 0.f, 0.f, 0.f};
  f32x4 acc1[7], acc2[7];
#pragma unroll
  for (int j = 0; j < 7; ++j) { acc1[j] = z; acc2[j] = z; }
  float stx = 0.f;

  union fragu4 { uint4 u; long long l[2]; };

#define WAITV(N) asm volatile("s_waitcnt vmcnt(" #N ")" ::: "memory")

#define STAGE_B(BI, ST)                                                        \
  do {                                                                         \
    const uchar* s_ = tsrc + (size_t)(ST) * TSLICE;                            \
    _Pragma("unroll")                                                          \
    for (int i_ = 0; i_ < 7; ++i_) {                                           \
      int c_ = w * 7 + i_;                                                     \
      gll16(s_ + c_ * 1024 + lane * 16, &buf[BI][c_ * 1024]);                  \
    }                                                                          \
  } while (0)

#define CONVERT(NI, V)                                                         \
  do {                                                                         \
    float xs_[4] = {V.x, V.y, V.z, V.w};                                       \
    float sg_[4];                                                              \
    _Pragma("unroll")                                                          \
    for (int q_ = 0; q_ < 4; ++q_) {                                           \
      float a_ = xs_[q_];                                                      \
      float e_ = __expf(-fabsf(a_));                                           \
      float o_ = 1.f + e_;                                                     \
      float i_ = __builtin_amdgcn_rcpf(o_);                                    \
      sg_[q_] = (a_ >= 0.f) ? i_ : e_ * i_;                                    \
      stx += fmaxf(a_, 0.f) + __logf(o_);                                      \
    }                                                                          \
    *reinterpret_cast<uint32_t*>(&abuf[NI][0][awoff]) =                        \
        pk_fp8(xs_[0], xs_[1], xs_[2], xs_[3]);                                \
    *reinterpret_cast<uint32_t*>(&abuf[NI][1][awoff]) =                        \
        pk_fp8(sg_[0], sg_[1], sg_[2], sg_[3]);                                \
  } while (0)

#define ITER(ACUR, S)                                                          \
  do {                                                                         \
    if (is_b) WAITV(0);             /* stage(S) issued a full step ago */      \
    if ((S) + 2 < steps) {          /* issue A load for S+2 (all threads) */   \
      float4 nv_ = *reinterpret_cast<const float4*>(apf + ((S) + 2) * 64);     \
      if (ACUR) fB = nv_; else fA = nv_;                                       \
    }                                                                          \
    __builtin_amdgcn_s_barrier();                                              \
    __builtin_amdgcn_sched_barrier(0);                                         \
    if ((S) + 1 < steps) {                                                     \
      if (is_b) STAGE_B(ACUR ^ 1, (S) + 1);                                    \
      if (ACUR) CONVERT(0, fA); else CONVERT(1, fB);                           \
    }                                                                          \
    {                                                                          \
      fragu4 ax_, ap_;                                                         \
      ax_.u = *reinterpret_cast<const uint4*>(&abuf[ACUR][0][afoff]);          \
      ap_.u = *reinterpret_cast<const uint4*>(&abuf[ACUR][1][afoff]);          \
      __builtin_amdgcn_s_setprio(1);                                           \
      _Pragma("unroll")                                                        \
      for (int j_ = 0; j_ < 7; ++j_) {                                         \
        fragu4 bv_;                                                            \
        bv_.u = *reinterpret_cast<const uint4*>(&buf[ACUR][bbase + j_ * 256]); \
        acc1[j_] = __builtin_amdgcn_mfma_f32_16x16x32_fp8_fp8(ax_.l[0], bv_.l[0], acc1[j_], 0, 0, 0); \
        acc2[j_] = __builtin_amdgcn_mfma_f32_16x16x32_fp8_fp8(ap_.l[0], bv_.l[0], acc2[j_], 0, 0, 0); \
        acc1[j_] = __builtin_amdgcn_mfma_f32_16x16x32_fp8_fp8(ax_.l[1], bv_.l[1], acc1[j_], 0, 0, 0); \
        acc2[j_] = __builtin_amdgcn_mfma_f32_16x16x32_fp8_fp8(ap_.l[1], bv_.l[1], acc2[j_], 0, 0, 0); \
      }                                                                        \
      __builtin_amdgcn_s_setprio(0);                                           \
    }                                                                          \
    asm volatile("s_waitcnt lgkmcnt(0)" ::: "memory");                         \
  } while (0)

  // ---- prologue: stage(0)->buf0; all: f(0) converted->abuf0, f(1)->fB ----
  float4 fA, fB;
  {
    float4 f0 = *reinterpret_cast<const float4*>(apf);
    fB = *reinterpret_cast<const float4*>(apf + 64);
    if (is_b) STAGE_B(0, 0);
    CONVERT(0, f0);
  }
  asm volatile("s_waitcnt lgkmcnt(0)" ::: "memory");

  for (int s = 0; s < steps; s += 2) {
    ITER(0, s);
    ITER(1, s + 1);
  }
#undef ITER
#undef CONVERT
#undef STAGE_B
#undef WAITV

  // ---- softplus row stats: 16 threads per row, xor-reduce width 16 ----
  stx += __shfl_xor(stx, 1, 16); stx += __shfl_xor(stx, 2, 16);
  stx += __shfl_xor(stx, 4, 16); stx += __shfl_xor(stx, 8, 16);
  if ((t & 15) == 0 && rowA < N_PRED)
    atomicAdd(SP + rowA, stx);

  // ---- store bf16 partials: part[arr][n][kz][MPAD] ----
  ushort* p1 = part;
  ushort* p2 = part + (size_t)KZN * 1200 * MPAD;
#pragma unroll
  for (int j = 0; j < 7; ++j)
#pragma unroll
    for (int rr = 0; rr < 4; ++rr) {
      int gn = bn * 32 + rg * 16 + kq * 4 + rr;   // C/D: row=(lane>>4)*4+reg
      if (gn < N_PRED) {
        int gm = cg * 112 + j * 16 + l15;         // col=lane&15
        size_t o = ((size_t)gn * KZN + kz) * MPAD + gm;
        p1[o] = f2bf(acc1[j][rr]);
        p2[o] = f2bf(acc2[j][rr]);
      }
    }
}

// ---------------- softmax probs [1200,81] ----------------
__global__ void probs_kernel(const float* __restrict__ logits, float* __restrict__ probs) {
  int n = blockIdx.x;
  int l = threadIdx.x;
  const float* row = logits + n * NCLS;
  float v0 = row[l];
  bool has2 = (l + 64) < NCLS;
  float v1 = has2 ? row[l + 64] : -3.4e38f;
  float mx = fmaxf(v0, v1);
#pragma unroll
  for (int o = 1; o < 64; o <<= 1) mx = fmaxf(mx, __shfl_xor(mx, o, 64));
  float e0 = expf(v0 - mx);
  float e1 = has2 ? expf(v1 - mx) : 0.f;
  float sm = e0 + e1;
#pragma unroll
  for (int o = 1; o < 64; o <<= 1) sm += __shfl_xor(sm, o, 64);
  float inv = 1.f / sm;
  probs[n * NCLS + l] = e0 * inv;
  if (has2) probs[n * NCLS + l + 64] = e1 * inv;
}

// ---------------- final combine (bf16 partials, [n][kz][MPAD] layout) --------
// sump computed inline per block: each 256-thread block spans <=2 distinct n;
// 2 threads sum the 13 ones-column partials, broadcast via LDS.
__global__ void combine2(const ushort* __restrict__ part,
                         const float* __restrict__ SP,
                         const float* __restrict__ tsum, const float* __restrict__ probs,
                         const float* __restrict__ pboxes, const float* __restrict__ tboxes,
                         const int* __restrict__ tids, float* __restrict__ out) {
  int idx = blockIdx.x * 256 + threadIdx.x;   // < 480000
  int n = idx / M_TGT;
  int m = idx - n * M_TGT;

  __shared__ float s_sump[2];
  int nbase = (blockIdx.x * 256) / M_TGT;
  if (threadIdx.x < 2) {
    int nn = nbase + threadIdx.x;
    float s = 0.f;
    if (nn < N_PRED) {
      const ushort* q = part + (size_t)KZN * 1200 * MPAD + (size_t)nn * (KZN * MPAD) + 400;
#pragma unroll
      for (int kz = 0; kz < KZN; ++kz) s += bf2f(q[kz * MPAD]);
    }
    s_sump[threadIdx.x] = s;
  }
  __syncthreads();

  const ushort* p1 = part + (size_t)n * (KZN * MPAD) + m;
  const ushort* p2 = p1 + (size_t)KZN * 1200 * MPAD;
  float A1 = 0.f, A2 = 0.f;
#pragma unroll
  for (int kz = 0; kz < KZN; ++kz) {
    A1 += bf2f(p1[kz * MPAD]);
    A2 += bf2f(p2[kz * MPAD]);
  }
  float sumpn = s_sump[n - nbase];
  float cm = (SP[n] - A1) * (1.0f / (float)KDIM);
  float cd = 1.f - (2.f * A2 + 1e-5f) / (sumpn + tsum[m] + 1e-5f);
  float cc = -probs[n * NCLS + tids[m]];

  float4 pb = reinterpret_cast<const float4*>(pboxes)[n];
  float4 tb = reinterpret_cast<const float4*>(tboxes)[m];
  float l1 = fabsf(pb.x - tb.x) + fabsf(pb.y - tb.y) + fabsf(pb.z - tb.z) + fabsf(pb.w - tb.w);
  float px1 = pb.x - 0.5f * pb.z, py1 = pb.y - 0.5f * pb.w;
  float px2 = pb.x + 0.5f * pb.z, py2 = pb.y + 0.5f * pb.w;
  float tx1 = tb.x - 0.5f * tb.z, ty1 = tb.y - 0.5f * tb.w;
  float tx2 = tb.x + 0.5f * tb.z, ty2 = tb.y + 0.5f * tb.w;
  float a1 = (px2 - px1) * (py2 - py1);
  float a2 = (tx2 - tx1) * (ty2 - ty1);
  float iw = fmaxf(fminf(px2, tx2) - fmaxf(px1, tx1), 0.f);
  float ih = fmaxf(fminf(py2, ty2) - fmaxf(py1, ty1), 0.f);
  float inter = iw * ih;
  float uni = a1 + a2 - inter;
  float iou = inter / uni;
  float ew = fmaxf(fmaxf(px2, tx2) - fminf(px1, tx1), 0.f);
  float eh = fmaxf(fmaxf(py2, ty2) - fminf(py1, ty1), 0.f);
  float ae = ew * eh;
  float giou = iou - (ae - uni) / ae;

  out[idx] = 5.f * l1 + 2.f * (-giou) + 2.f * cc + 5.f * cm + 5.f * cd;
}

// =====================================================================
// FALLBACK PATH (only if ws too small)
// =====================================================================

__device__ __forceinline__ float sigf(float x) {
  return 1.f / (1.f + __expf(-x));
}

__global__ void resize_lin(const float* __restrict__ tm, ushort* __restrict__ T,
                           float* __restrict__ tsum) {
  int m = blockIdx.x;
  int p = blockIdx.y * 256 + threadIdx.x;
  int y = p / 160;
  int x = p - y * 160;
  float wy[4], wx[4];
  int jy0, jx0;
  {
    float s = (y + 0.5f) * 1.6f - 0.5f;
    jy0 = (int)ceilf(s - 1.6f);
    float ws = 0.f;
#pragma unroll
    for (int a = 0; a < 4; ++a) {
      int j = jy0 + a;
      float w = fmaxf(0.f, 1.f - fabsf((float)j - s) * 0.625f);
      if (j < 0 || j > 255) w = 0.f;
      wy[a] = w; ws += w;
    }
    float inv = 1.f / ws;
#pragma unroll
    for (int a = 0; a < 4; ++a) wy[a] *= inv;
  }
  {
    float s = (x + 0.5f) * 1.6f - 0.5f;
    jx0 = (int)ceilf(s - 1.6f);
    float ws = 0.f;
#pragma unroll
    for (int b = 0; b < 4; ++b) {
      int j = jx0 + b;
      float w = fmaxf(0.f, 1.f - fabsf((float)j - s) * 0.625f);
      if (j < 0 || j > 255) w = 0.f;
      wx[b] = w; ws += w;
    }
    float inv = 1.f / ws;
#pragma unroll
    for (int b = 0; b < 4; ++b) wx[b] *= inv;
  }
  const float* base = tm + (size_t)m * 65536;
  float acc = 0.f;
#pragma unroll
  for (int a = 0; a < 4; ++a) {
    int jy = min(max(jy0 + a, 0), 255);
    float wya = wy[a];
#pragma unroll
    for (int b = 0; b < 4; ++b) {
      int jx = min(max(jx0 + b, 0), 255);
      acc += wya * wx[b] * base[jy * 256 + jx];
    }
  }
  T[(size_t)m * KDIM + p] = f2bf(acc);
  float v = acc;
#pragma unroll
  for (int o = 32; o > 0; o >>= 1) v += __shfl_down(v, o, 64);
  __shared__ float red[4];
  int wid = threadIdx.x >> 6;
  if ((threadIdx.x & 63) == 0) red[wid] = v;
  __syncthreads();
  if (threadIdx.x == 0) atomicAdd(&tsum[m], red[0] + red[1] + red[2] + red[3]);
}

__global__ void stats_kernel(const float* __restrict__ pm, float* __restrict__ S,
                             float* __restrict__ sump) {
  int n = blockIdx.x;
  const float4* row = reinterpret_cast<const float4*>(pm + (size_t)n * KDIM);
  float ssp = 0.f, sp = 0.f;
  for (int i = threadIdx.x; i < KDIM / 4; i += 256) {
    float4 v = row[i];
    float xs[4] = {v.x, v.y, v.z, v.w};
#pragma unroll
    for (int j = 0; j < 4; ++j) {
      float x = xs[j];
      float e = __expf(-fabsf(x));
      float inv1pe = 1.f / (1.f + e);
      sp += (x >= 0.f) ? inv1pe : e * inv1pe;
      ssp += fmaxf(x, 0.f) + log1pf(e);
    }
  }
#pragma unroll
  for (int o = 32; o > 0; o >>= 1) {
    ssp += __shfl_down(ssp, o, 64);
    sp  += __shfl_down(sp, o, 64);
  }
  __shared__ float red[8];
  int wid = threadIdx.x >> 6;
  if ((threadIdx.x & 63) == 0) { red[wid] = ssp; red[4 + wid] = sp; }
  __syncthreads();
  if (threadIdx.x == 0) {
    S[n]    = -(red[0] + red[1] + red[2] + red[3]);
    sump[n] = red[4] + red[5] + red[6] + red[7];
  }
}

__device__ __forceinline__ bf16x8 load_frag_lin(const ushort* p) {
  union { ushort4 u[2]; bf16x8 f; } fr;
  fr.u[0] = *reinterpret_cast<const ushort4*>(p);
  fr.u[1] = *reinterpret_cast<const ushort4*>(p + 4);
  return fr.f;
}

__global__ __launch_bounds__(256) void gemm_fused(
    const float* __restrict__ pm, const ushort* __restrict__ T,
    ushort* __restrict__ part1, ushort* __restrict__ part2, int k_per) {
  __shared__ ushort Ax[64][40];
  __shared__ ushort Ap[64][40];
  __shared__ ushort Bs[64][40];
  int n0 = blockIdx.x * 64;
  int m0 = blockIdx.y * 64;
  int kz = blockIdx.z;
  int k_begin = kz * k_per;
  int t = threadIdx.x;
  int r = t >> 2;
  int q = t & 3;
  bool a_ok = (n0 + r) < N_PRED;
  bool b_ok = (m0 + r) < M_TGT;
  const float*  pA = pm + (size_t)(n0 + r) * KDIM + k_begin + q * 8;
  const ushort* pB = T  + (size_t)(m0 + r) * KDIM + k_begin + q * 8;
  int lane = t & 63;
  int w = t >> 6;
  int wr = (w >> 1) * 32;
  int wc = (w & 1) * 32;
  int lrow = lane & 15;
  int kc = (lane >> 4) * 8;
  f32x4 zero = {0.f, 0.f, 0.f, 0.f};
  f32x4 acc1[2][2] = {{zero, zero}, {zero, zero}};
  f32x4 acc2[2][2] = {{zero, zero}, {zero, zero}};
  int steps = k_per / 32;
  for (int kt = 0; kt < steps; ++kt) {
    __syncthreads();
    float4 f0 = {0.f,0.f,0.f,0.f}, f1 = {0.f,0.f,0.f,0.f};
    if (a_ok) {
      f0 = *reinterpret_cast<const float4*>(pA);
      f1 = *reinterpret_cast<const float4*>(pA + 4);
    }
    pA += 32;
    ushort4 xa, xb, pa, pb4;
    xa.x = f2bf(f0.x); xa.y = f2bf(f0.y); xa.z = f2bf(f0.z); xa.w = f2bf(f0.w);
    xb.x = f2bf(f1.x); xb.y = f2bf(f1.y); xb.z = f2bf(f1.z); xb.w = f2bf(f1.w);
    pa.x = f2bf(sigf(f0.x)); pa.y = f2bf(sigf(f0.y)); pa.z = f2bf(sigf(f0.z)); pa.w = f2bf(sigf(f0.w));
    pb4.x = f2bf(sigf(f1.x)); pb4.y = f2bf(sigf(f1.y)); pb4.z = f2bf(sigf(f1.z)); pb4.w = f2bf(sigf(f1.w));
    *reinterpret_cast<ushort4*>(&Ax[r][q * 8])     = xa;
    *reinterpret_cast<ushort4*>(&Ax[r][q * 8 + 4]) = xb;
    *reinterpret_cast<ushort4*>(&Ap[r][q * 8])     = pa;
    *reinterpret_cast<ushort4*>(&Ap[r][q * 8 + 4]) = pb4;
    union { uint4 u; ushort4 s[2]; } bv;
    bv.u = make_uint4(0, 0, 0, 0);
    if (b_ok) bv.u = *reinterpret_cast<const uint4*>(pB);
    pB += 32;
    *reinterpret_cast<ushort4*>(&Bs[r][q * 8])     = bv.s[0];
    *reinterpret_cast<ushort4*>(&Bs[r][q * 8 + 4]) = bv.s[1];
    __syncthreads();
    bf16x8 ax[2], ap[2], bb[2];
#pragma unroll
    for (int i = 0; i < 2; ++i) {
      ax[i] = load_frag_lin(&Ax[wr + i * 16 + lrow][kc]);
      ap[i] = load_frag_lin(&Ap[wr + i * 16 + lrow][kc]);
      bb[i] = load_frag_lin(&Bs[wc + i * 16 + lrow][kc]);
    }
#pragma unroll
    for (int i = 0; i < 2; ++i)
#pragma unroll
      for (int j = 0; j < 2; ++j) {
        acc1[i][j] = __builtin_amdgcn_mfma_f32_16x16x32_bf16(ax[i], bb[j], acc1[i][j], 0, 0, 0);
        acc2[i][j] = __builtin_amdgcn_mfma_f32_16x16x32_bf16(ap[i], bb[j], acc2[i][j], 0, 0, 0);
      }
  }
  int rowb = (lane >> 4) * 4;
  int col = lane & 15;
#pragma unroll
  for (int i = 0; i < 2; ++i)
#pragma unroll
    for (int j = 0; j < 2; ++j)
#pragma unroll
      for (int rr = 0; rr < 4; ++rr) {
        int gn = n0 + wr + i * 16 + rowb + rr;
        int gm = m0 + wc + j * 16 + col;
        if (gn < N_PRED && gm < M_TGT) {
          size_t o = (size_t)kz * 480000 + (size_t)gn * 400 + gm;
          part1[o] = f2bf(acc1[i][j][rr]);
          part2[o] = f2bf(acc2[i][j][rr]);
        }
      }
}

__global__ void combine_fb(const ushort* __restrict__ part1, const ushort* __restrict__ part2,
                           const float* __restrict__ S, const float* __restrict__ sump,
                           const float* __restrict__ tsum, const float* __restrict__ probs,
                           const float* __restrict__ pboxes, const float* __restrict__ tboxes,
                           const int* __restrict__ tids, float* __restrict__ out, int KZ) {
  int idx = blockIdx.x * 256 + threadIdx.x;
  int n = idx / M_TGT;
  int m = idx - n * M_TGT;
  float A1 = 0.f, A2 = 0.f;
  for (int kz = 0; kz < KZ; ++kz) {
    A1 += bf2f(part1[(size_t)kz * 480000 + idx]);
    A2 += bf2f(part2[(size_t)kz * 480000 + idx]);
  }
  float cm = -(A1 + S[n]) * (1.0f / (float)KDIM);
  float cd = 1.f - (2.f * A2 + 1e-5f) / (sump[n] + tsum[m] + 1e-5f);
  float cc = -probs[n * NCLS + tids[m]];
  float4 pb = reinterpret_cast<const float4*>(pboxes)[n];
  float4 tb = reinterpret_cast<const float4*>(tboxes)[m];
  float l1 = fabsf(pb.x - tb.x) + fabsf(pb.y - tb.y) + fabsf(pb.z - tb.z) + fabsf(pb.w - tb.w);
  float px1 = pb.x - 0.5f * pb.z, py1 = pb.y - 0.5f * pb.w;
  float px2 = pb.x + 0.5f * pb.z, py2 = pb.y + 0.5f * pb.w;
  float tx1 = tb.x - 0.5f * tb.z, ty1 = tb.y - 0.5f * tb.w;
  float tx2 = tb.x + 0.5f * tb.z, ty2 = tb.y + 0.5f * tb.w;
  float a1 = (px2 - px1) * (py2 - py1);
  float a2 = (tx2 - tx1) * (ty2 - ty1);
  float iw = fmaxf(fminf(px2, tx2) - fmaxf(px1, tx1), 0.f);
  float ih = fmaxf(fminf(py2, ty2) - fmaxf(py1, ty1), 0.f);
  float inter = iw * ih;
  float uni = a1 + a2 - inter;
  float iou = inter / uni;
  float ew = fmaxf(fmaxf(px2, tx2) - fminf(px1, tx1), 0.f);
  float eh = fmaxf(fmaxf(py2, ty2) - fminf(py1, ty1), 0.f);
  float ae = ew * eh;
  float giou = iou - (ae - uni) / ae;
  out[idx] = 5.f * l1 + 2.f * (-giou) + 2.f * cc + 5.f * cm + 5.f * cd;
}

// =====================================================================

extern "C" void kernel_launch(void* const* d_in, const int* in_sizes, int n_in,
                              void* d_out, int out_size, void* d_ws, size_t ws_size,
                              hipStream_t stream) {
  const float* logits = (const float*)d_in[0];
  const float* pboxes = (const float*)d_in[1];
  const float* pmasks = (const float*)d_in[2];
  const float* tboxes = (const float*)d_in[3];
  const float* tmasks = (const float*)d_in[4];
  const int*   tids   = (const int*)d_in[5];
  float* out = (float*)d_out;
  char* ws = (char*)d_ws;

  // new-path workspace layout
  const size_t offT     = 0;                         // 400*28672 = 11,468,800 (fp8)
  const size_t offPart  = 24371200;                  // 2*13*1200*448*2 = 27,955,200
  const size_t offProbs = offPart + 27955200;        // 388,800
  const size_t offStats = offProbs + 390400;         // SP 4800 | tsum 1600
  const size_t needNew  = offStats + 11200;

  if (ws_size >= needNew) {
    uchar* Tg    = (uchar*)(ws + offT);
    ushort* part = (ushort*)(ws + offPart);
    float* probs = (float*)(ws + offProbs);
    float* SP    = (float*)(ws + offStats);
    float* tsum  = (float*)(ws + offStats + 4800);

    hipMemsetAsync(SP, 0, 6400, stream);   // SP + tsum
    resize2<<<dim3(M_TGT, 20), 256, 0, stream>>>(tmasks, Tg, tsum);
    probs_kernel<<<N_PRED, 64, 0, stream>>>(logits, probs);
    gemm_mega<<<NBLK * KZN, 512, 0, stream>>>(pmasks, Tg, part, SP);
    combine2<<<1875, 256, 0, stream>>>(part, SP, tsum, probs,
                                       pboxes, tboxes, tids, out);
  } else {
    // fallback (R4 pipeline)
    ushort* T     = (ushort*)ws;
    float*  probs = (float*)(ws + 20480000);
    float*  S     = (float*)(ws + 20868800);
    float*  sump  = (float*)(ws + 20873600);
    float*  tsum  = (float*)(ws + 20878400);
    ushort* part1 = (ushort*)(ws + 20880000);
    size_t need8 = 20880000ull + 2ull * 8 * 480000 * 2;
    int KZf = (ws_size >= need8) ? 8 : 1;
    ushort* part2 = part1 + (size_t)KZf * 480000;

    hipMemsetAsync(tsum, 0, M_TGT * sizeof(float), stream);
    resize_lin<<<dim3(M_TGT, 100), 256, 0, stream>>>(tmasks, T, tsum);
    probs_kernel<<<N_PRED, 64, 0, stream>>>(logits, probs);
    stats_kernel<<<N_PRED, 256, 0, stream>>>(pmasks, S, sump);
    gemm_fused<<<dim3(19, 7, KZf), 256, 0, stream>>>(pmasks, T, part1, part2, KDIM / KZf);
    combine_fb<<<1875, 256, 0, stream>>>(part1, part2, S, sump, tsum, probs,
                                         pboxes, tboxes, tids, out, KZf);
  }
}

// Round 19
// 118.716 us; speedup vs baseline: 5.0206x; 1.0260x over previous
//
#include <hip/hip_runtime.h>
#include <cstdint>

#define N_PRED 1200
#define M_TGT  400
#define KDIM   25600   // 160*160
#define NCLS   81
#define MPAD   448     // padded target count (28 x 16)
#define KZN    13      // split-K factor (5 kz with 32 steps + 8 kz with 30)
#define NBLK   38      // row blocks of 32 (1216 >= 1200)
#define TSLICE 28672   // BYTES per BK=64 step: 4(kq) * 448 * 16 (h-paired fp8)

typedef __attribute__((ext_vector_type(8)))  short bf16x8;
typedef __attribute__((ext_vector_type(4)))  float f32x4;
typedef unsigned char uchar;

__device__ __forceinline__ ushort f2bf(float f) {
  union { float f; uint32_t u; } v; v.f = f;
  uint32_t u = v.u + 0x7fffu + ((v.u >> 16) & 1u);
  return (ushort)(u >> 16);
}

__device__ __forceinline__ float bf2f(ushort s) {
  union { uint32_t u; float f; } v; v.u = ((uint32_t)s) << 16;
  return v.f;
}

// pack 4 f32 -> 4 fp8 e4m3 (OCP, saturating) in one u32
__device__ __forceinline__ uint32_t pk_fp8(float a, float b, float c, float d) {
  uint32_t v = (uint32_t)__builtin_amdgcn_cvt_pk_fp8_f32(a, b, 0, false);
  v = (uint32_t)__builtin_amdgcn_cvt_pk_fp8_f32(c, d, (int)v, true);
  return v;
}

__device__ __forceinline__ void gll16(const void* g, void* l) {
  __builtin_amdgcn_global_load_lds(
      (const __attribute__((address_space(1))) void*)g,
      (__attribute__((address_space(3))) void*)l, 16, 0, 0);
}

// =====================================================================
// Resize tgt_masks [400,256,256] -> T fp8 h-paired fragment-major:
// element with k-chunk kql (0..7) of step kt stored at
//   kt*TSLICE + ((kql&3)*MPAD + m)*16 + (kql>>2)*8
// Block (0,0) additionally initializes the ones-column (m=400) so
// A2[:,400] = row-sum of p (free sump via GEMM).
__global__ __launch_bounds__(256) void resize2(const float* __restrict__ tm,
                                               uchar* __restrict__ T,
                                               float* __restrict__ tsum) {
  __shared__ float rows[16][256];
  __shared__ float vbuf[8][256];

  int m = blockIdx.x, yt = blockIdx.y;  // yt 0..19
  int y0 = yt * 8;
  int t = threadIdx.x;

  // fused ones_init (disjoint m=400 column; no race with resize writes)
  if (m == 0 && yt == 0) {
    for (int i = t; i < 3200; i += 256) {
      int kt = i >> 3, kql = i & 7;
      size_t a = (size_t)kt * TSLICE +
                 ((size_t)((kql & 3) * MPAD + 400)) * 16 + (kql >> 2) * 8;
      uint2 v; v.x = 0x38383838u; v.y = 0x38383838u;
      *reinterpret_cast<uint2*>(&T[a]) = v;
    }
  }

  int jbase = (int)ceilf((y0 + 0.5f) * 1.6f - 2.1f);

  const float* base = tm + (size_t)m * 65536;
  {
    int r = t >> 4;
    int c0 = (t & 15) * 16;
    int jr = min(max(jbase + r, 0), 255);
    const float4* src = reinterpret_cast<const float4*>(base + jr * 256 + c0);
#pragma unroll
    for (int i = 0; i < 4; ++i)
      *reinterpret_cast<float4*>(&rows[r][c0 + i * 4]) = src[i];
  }
  __syncthreads();

#pragma unroll
  for (int yy = 0; yy < 8; ++yy) {
    int y = y0 + yy;
    float s = (y + 0.5f) * 1.6f - 0.5f;
    int j0 = (int)ceilf(s - 1.6f);
    float w[4]; float wsum = 0.f;
#pragma unroll
    for (int a = 0; a < 4; ++a) {
      int j = j0 + a;
      float wv = fmaxf(0.f, 1.f - fabsf((float)j - s) * 0.625f);
      if (j < 0 || j > 255) wv = 0.f;
      w[a] = wv; wsum += wv;
    }
    float winv = __builtin_amdgcn_rcpf(wsum);
    float acc = 0.f;
    int rbase = j0 - jbase;
#pragma unroll
    for (int a = 0; a < 4; ++a) acc += w[a] * rows[rbase + a][t];
    vbuf[yy][t] = acc * winv;
  }
  __syncthreads();

  float bsum = 0.f;
  if (t < 160) {
    int yy = t / 20, ch = t - yy * 20;
    float o[8];
#pragma unroll
    for (int j = 0; j < 8; ++j) {
      int x = ch * 8 + j;
      float sx = (x + 0.5f) * 1.6f - 0.5f;
      int jx0 = (int)ceilf(sx - 1.6f);
      float wsum = 0.f, h = 0.f;
#pragma unroll
      for (int b = 0; b < 4; ++b) {
        int jj = jx0 + b;
        float wv = fmaxf(0.f, 1.f - fabsf((float)jj - sx) * 0.625f);
        if (jj < 0 || jj > 255) wv = 0.f;
        wsum += wv;
        h += wv * vbuf[yy][min(max(jj, 0), 255)];
      }
      h *= __builtin_amdgcn_rcpf(wsum);
      o[j] = h; bsum += h;
    }
    int p0 = (y0 + yy) * 160 + ch * 8;
    int kt = p0 >> 6, kql = (p0 >> 3) & 7;
    size_t a = (size_t)kt * TSLICE +
               ((size_t)((kql & 3) * MPAD + m)) * 16 + (kql >> 2) * 8;
    uint2 pk;
    pk.x = pk_fp8(o[0], o[1], o[2], o[3]);
    pk.y = pk_fp8(o[4], o[5], o[6], o[7]);
    *reinterpret_cast<uint2*>(&T[a]) = pk;
  }
#pragma unroll
  for (int o2 = 32; o2 > 0; o2 >>= 1) bsum += __shfl_down(bsum, o2, 64);
  __shared__ float red[4];
  int wid = t >> 6;
  if ((t & 63) == 0) red[wid] = bsum;
  __syncthreads();
  if (t == 0) atomicAdd(&tsum[m], red[0] + red[1] + red[2] + red[3]);
}

// =====================================================================
// Fused dual GEMM (fp8 e4m3) + conversion + softplus row-stats. BK=64,
// 1-barrier dbuf parity pipeline, h-paired layout: one ds_read_b128 per
// fragment PAIR. KZN=13 -> 494 blocks = one co-resident generation.
// CONVERT uses a single log per 4 elements: sum log(o_i) = log(prod o_i)
// (o_i in (1,2], product exact to ~2^-22 in f32) -> 9 trans ops vs 12.
__global__ __launch_bounds__(512, 4) void gemm_mega(
    const float* __restrict__ pm, const uchar* __restrict__ Tg,
    ushort* __restrict__ part, float* __restrict__ SP) {
  __shared__ uchar buf[2][TSLICE];        // 57,344 B
  __shared__ uchar abuf[2][2][2048];      //  8,192 B  [dbuf][x/p][kq(4)][row(32)][16]

  // bijective XCD swizzle for nwg=494 (m204): q=61, r=6; kz-major chunks
  int orig = blockIdx.x;
  int xcd = orig & 7, base = orig >> 3;
  int wgid = (xcd < 6 ? xcd * 62 : 372 + (xcd - 6) * 61) + base;
  int kz = wgid / NBLK;
  int bn = wgid - kz * NBLK;
  int koff  = (kz < 5) ? (32 * kz) : (160 + 30 * (kz - 5));   // in BK=64 units
  int steps = (kz < 5) ? 32 : 30;

  int t = threadIdx.x, lane = t & 63, w = t >> 6;
  int rg = w >> 2, cg = w & 3;
  int l15 = lane & 15, kq = lane >> 4;

  bool is_b = (t < 256);

  int arow = t >> 4, kc4 = t & 15;       // row 0..31, float4 chunk 0..15
  int rowA = bn * 32 + arow;
  int rowAc = min(rowA, N_PRED - 1);
  const float* apf = pm + (size_t)rowAc * KDIM + koff * 64 + kc4 * 4;
  int kqlw = kc4 >> 1;
  int awoff = ((kqlw & 3) * 32 + arow) * 16 + (kqlw >> 2) * 8 + (kc4 & 1) * 4;

  const uchar* tsrc = Tg + (size_t)koff * TSLICE;
  int bbase = (kq * MPAD + cg * 112 + l15) * 16;     // B frag-pair (byte), +j*256
  int afoff = (kq * 32 + rg * 16 + l15) * 16;        // A frag-pair (byte)

  f32x4 z = {0.f, 0.f, 0.f, 0.f};
  f32x4 acc1[7], acc2[7];
#pragma unroll
  for (int j = 0; j < 7; ++j) { acc1[j] = z; acc2[j] = z; }
  float stx = 0.f;

  union fragu4 { uint4 u; long long l[2]; };

#define WAITV(N) asm volatile("s_waitcnt vmcnt(" #N ")" ::: "memory")

#define STAGE_B(BI, ST)                                                        \
  do {                                                                         \
    const uchar* s_ = tsrc + (size_t)(ST) * TSLICE;                            \
    _Pragma("unroll")                                                          \
    for (int i_ = 0; i_ < 7; ++i_) {                                           \
      int c_ = w * 7 + i_;                                                     \
      gll16(s_ + c_ * 1024 + lane * 16, &buf[BI][c_ * 1024]);                  \
    }                                                                          \
  } while (0)

// convert 4 f32 -> fp8 x/p; softplus stat with ONE log via product trick.
#define CONVERT(NI, V)                                                         \
  do {                                                                         \
    float xs_[4] = {V.x, V.y, V.z, V.w};                                       \
    float sg_[4], o_[4];                                                       \
    _Pragma("unroll")                                                          \
    for (int q_ = 0; q_ < 4; ++q_) {                                           \
      float a_ = xs_[q_];                                                      \
      float e_ = __expf(-fabsf(a_));                                           \
      o_[q_] = 1.f + e_;                                                       \
      float i_ = __builtin_amdgcn_rcpf(o_[q_]);                                \
      sg_[q_] = (a_ >= 0.f) ? i_ : e_ * i_;                                    \
      stx += fmaxf(a_, 0.f);                                                   \
    }                                                                          \
    stx += __logf((o_[0] * o_[1]) * (o_[2] * o_[3]));                          \
    *reinterpret_cast<uint32_t*>(&abuf[NI][0][awoff]) =                        \
        pk_fp8(xs_[0], xs_[1], xs_[2], xs_[3]);                                \
    *reinterpret_cast<uint32_t*>(&abuf[NI][1][awoff]) =                        \
        pk_fp8(sg_[0], sg_[1], sg_[2], sg_[3]);                                \
  } while (0)

#define ITER(ACUR, S)                                                          \
  do {                                                                         \
    if (is_b) WAITV(0);             /* stage(S) issued a full step ago */      \
    if ((S) + 2 < steps) {          /* issue A load for S+2 (all threads) */   \
      float4 nv_ = *reinterpret_cast<const float4*>(apf + ((S) + 2) * 64);     \
      if (ACUR) fB = nv_; else fA = nv_;                                       \
    }                                                                          \
    __builtin_amdgcn_s_barrier();                                              \
    __builtin_amdgcn_sched_barrier(0);                                         \
    if ((S) + 1 < steps) {                                                     \
      if (is_b) STAGE_B(ACUR ^ 1, (S) + 1);                                    \
      if (ACUR) CONVERT(0, fA); else CONVERT(1, fB);                           \
    }                                                                          \
    {                                                                          \
      fragu4 ax_, ap_;                                                         \
      ax_.u = *reinterpret_cast<const uint4*>(&abuf[ACUR][0][afoff]);          \
      ap_.u = *reinterpret_cast<const uint4*>(&abuf[ACUR][1][afoff]);          \
      __builtin_amdgcn_s_setprio(1);                                           \
      _Pragma("unroll")                                                        \
      for (int j_ = 0; j_ < 7; ++j_) {                                         \
        fragu4 bv_;                                                            \
        bv_.u = *reinterpret_cast<const uint4*>(&buf[ACUR][bbase + j_ * 256]); \
        acc1[j_] = __builtin_amdgcn_mfma_f32_16x16x32_fp8_fp8(ax_.l[0], bv_.l[0], acc1[j_], 0, 0, 0); \
        acc2[j_] = __builtin_amdgcn_mfma_f32_16x16x32_fp8_fp8(ap_.l[0], bv_.l[0], acc2[j_], 0, 0, 0); \
        acc1[j_] = __builtin_amdgcn_mfma_f32_16x16x32_fp8_fp8(ax_.l[1], bv_.l[1], acc1[j_], 0, 0, 0); \
        acc2[j_] = __builtin_amdgcn_mfma_f32_16x16x32_fp8_fp8(ap_.l[1], bv_.l[1], acc2[j_], 0, 0, 0); \
      }                                                                        \
      __builtin_amdgcn_s_setprio(0);                                           \
    }                                                                          \
    asm volatile("s_waitcnt lgkmcnt(0)" ::: "memory");                         \
  } while (0)

  // ---- prologue: stage(0)->buf0; all: f(0) converted->abuf0, f(1)->fB ----
  float4 fA, fB;
  {
    float4 f0 = *reinterpret_cast<const float4*>(apf);
    fB = *reinterpret_cast<const float4*>(apf + 64);
    if (is_b) STAGE_B(0, 0);
    CONVERT(0, f0);
  }
  asm volatile("s_waitcnt lgkmcnt(0)" ::: "memory");

  for (int s = 0; s < steps; s += 2) {
    ITER(0, s);
    ITER(1, s + 1);
  }
#undef ITER
#undef CONVERT
#undef STAGE_B
#undef WAITV

  // ---- softplus row stats: 16 threads per row, xor-reduce width 16 ----
  stx += __shfl_xor(stx, 1, 16); stx += __shfl_xor(stx, 2, 16);
  stx += __shfl_xor(stx, 4, 16); stx += __shfl_xor(stx, 8, 16);
  if ((t & 15) == 0 && rowA < N_PRED)
    atomicAdd(SP + rowA, stx);

  // ---- store bf16 partials: part[arr][n][kz][MPAD] ----
  ushort* p1 = part;
  ushort* p2 = part + (size_t)KZN * 1200 * MPAD;
#pragma unroll
  for (int j = 0; j < 7; ++j)
#pragma unroll
    for (int rr = 0; rr < 4; ++rr) {
      int gn = bn * 32 + rg * 16 + kq * 4 + rr;   // C/D: row=(lane>>4)*4+reg
      if (gn < N_PRED) {
        int gm = cg * 112 + j * 16 + l15;         // col=lane&15
        size_t o = ((size_t)gn * KZN + kz) * MPAD + gm;
        p1[o] = f2bf(acc1[j][rr]);
        p2[o] = f2bf(acc2[j][rr]);
      }
    }
}

// ---------------- softmax probs [1200,81] ----------------
__global__ void probs_kernel(const float* __restrict__ logits, float* __restrict__ probs) {
  int n = blockIdx.x;
  int l = threadIdx.x;
  const float* row = logits + n * NCLS;
  float v0 = row[l];
  bool has2 = (l + 64) < NCLS;
  float v1 = has2 ? row[l + 64] : -3.4e38f;
  float mx = fmaxf(v0, v1);
#pragma unroll
  for (int o = 1; o < 64; o <<= 1) mx = fmaxf(mx, __shfl_xor(mx, o, 64));
  float e0 = expf(v0 - mx);
  float e1 = has2 ? expf(v1 - mx) : 0.f;
  float sm = e0 + e1;
#pragma unroll
  for (int o = 1; o < 64; o <<= 1) sm += __shfl_xor(sm, o, 64);
  float inv = 1.f / sm;
  probs[n * NCLS + l] = e0 * inv;
  if (has2) probs[n * NCLS + l + 64] = e1 * inv;
}

// ---------------- final combine (bf16 partials, [n][kz][MPAD] layout) --------
// sump computed inline per block: each 256-thread block spans <=2 distinct n;
// 2 threads sum the 13 ones-column partials, broadcast via LDS.
__global__ void combine2(const ushort* __restrict__ part,
                         const float* __restrict__ SP,
                         const float* __restrict__ tsum, const float* __restrict__ probs,
                         const float* __restrict__ pboxes, const float* __restrict__ tboxes,
                         const int* __restrict__ tids, float* __restrict__ out) {
  int idx = blockIdx.x * 256 + threadIdx.x;   // < 480000
  int n = idx / M_TGT;
  int m = idx - n * M_TGT;

  __shared__ float s_sump[2];
  int nbase = (blockIdx.x * 256) / M_TGT;
  if (threadIdx.x < 2) {
    int nn = nbase + threadIdx.x;
    float s = 0.f;
    if (nn < N_PRED) {
      const ushort* q = part + (size_t)KZN * 1200 * MPAD + (size_t)nn * (KZN * MPAD) + 400;
#pragma unroll
      for (int kz = 0; kz < KZN; ++kz) s += bf2f(q[kz * MPAD]);
    }
    s_sump[threadIdx.x] = s;
  }
  __syncthreads();

  const ushort* p1 = part + (size_t)n * (KZN * MPAD) + m;
  const ushort* p2 = p1 + (size_t)KZN * 1200 * MPAD;
  float A1 = 0.f, A2 = 0.f;
#pragma unroll
  for (int kz = 0; kz < KZN; ++kz) {
    A1 += bf2f(p1[kz * MPAD]);
    A2 += bf2f(p2[kz * MPAD]);
  }
  float sumpn = s_sump[n - nbase];
  float cm = (SP[n] - A1) * (1.0f / (float)KDIM);
  float cd = 1.f - (2.f * A2 + 1e-5f) / (sumpn + tsum[m] + 1e-5f);
  float cc = -probs[n * NCLS + tids[m]];

  float4 pb = reinterpret_cast<const float4*>(pboxes)[n];
  float4 tb = reinterpret_cast<const float4*>(tboxes)[m];
  float l1 = fabsf(pb.x - tb.x) + fabsf(pb.y - tb.y) + fabsf(pb.z - tb.z) + fabsf(pb.w - tb.w);
  float px1 = pb.x - 0.5f * pb.z, py1 = pb.y - 0.5f * pb.w;
  float px2 = pb.x + 0.5f * pb.z, py2 = pb.y + 0.5f * pb.w;
  float tx1 = tb.x - 0.5f * tb.z, ty1 = tb.y - 0.5f * tb.w;
  float tx2 = tb.x + 0.5f * tb.z, ty2 = tb.y + 0.5f * tb.w;
  float a1 = (px2 - px1) * (py2 - py1);
  float a2 = (tx2 - tx1) * (ty2 - ty1);
  float iw = fmaxf(fminf(px2, tx2) - fmaxf(px1, tx1), 0.f);
  float ih = fmaxf(fminf(py2, ty2) - fmaxf(py1, ty1), 0.f);
  float inter = iw * ih;
  float uni = a1 + a2 - inter;
  float iou = inter / uni;
  float ew = fmaxf(fmaxf(px2, tx2) - fminf(px1, tx1), 0.f);
  float eh = fmaxf(fmaxf(py2, ty2) - fminf(py1, ty1), 0.f);
  float ae = ew * eh;
  float giou = iou - (ae - uni) / ae;

  out[idx] = 5.f * l1 + 2.f * (-giou) + 2.f * cc + 5.f * cm + 5.f * cd;
}

// =====================================================================
// FALLBACK PATH (only if ws too small)
// =====================================================================

__device__ __forceinline__ float sigf(float x) {
  return 1.f / (1.f + __expf(-x));
}

__global__ void resize_lin(const float* __restrict__ tm, ushort* __restrict__ T,
                           float* __restrict__ tsum) {
  int m = blockIdx.x;
  int p = blockIdx.y * 256 + threadIdx.x;
  int y = p / 160;
  int x = p - y * 160;
  float wy[4], wx[4];
  int jy0, jx0;
  {
    float s = (y + 0.5f) * 1.6f - 0.5f;
    jy0 = (int)ceilf(s - 1.6f);
    float ws = 0.f;
#pragma unroll
    for (int a = 0; a < 4; ++a) {
      int j = jy0 + a;
      float w = fmaxf(0.f, 1.f - fabsf((float)j - s) * 0.625f);
      if (j < 0 || j > 255) w = 0.f;
      wy[a] = w; ws += w;
    }
    float inv = 1.f / ws;
#pragma unroll
    for (int a = 0; a < 4; ++a) wy[a] *= inv;
  }
  {
    float s = (x + 0.5f) * 1.6f - 0.5f;
    jx0 = (int)ceilf(s - 1.6f);
    float ws = 0.f;
#pragma unroll
    for (int b = 0; b < 4; ++b) {
      int j = jx0 + b;
      float w = fmaxf(0.f, 1.f - fabsf((float)j - s) * 0.625f);
      if (j < 0 || j > 255) w = 0.f;
      wx[b] = w; ws += w;
    }
    float inv = 1.f / ws;
#pragma unroll
    for (int b = 0; b < 4; ++b) wx[b] *= inv;
  }
  const float* base = tm + (size_t)m * 65536;
  float acc = 0.f;
#pragma unroll
  for (int a = 0; a < 4; ++a) {
    int jy = min(max(jy0 + a, 0), 255);
    float wya = wy[a];
#pragma unroll
    for (int b = 0; b < 4; ++b) {
      int jx = min(max(jx0 + b, 0), 255);
      acc += wya * wx[b] * base[jy * 256 + jx];
    }
  }
  T[(size_t)m * KDIM + p] = f2bf(acc);
  float v = acc;
#pragma unroll
  for (int o = 32; o > 0; o >>= 1) v += __shfl_down(v, o, 64);
  __shared__ float red[4];
  int wid = threadIdx.x >> 6;
  if ((threadIdx.x & 63) == 0) red[wid] = v;
  __syncthreads();
  if (threadIdx.x == 0) atomicAdd(&tsum[m], red[0] + red[1] + red[2] + red[3]);
}

__global__ void stats_kernel(const float* __restrict__ pm, float* __restrict__ S,
                             float* __restrict__ sump) {
  int n = blockIdx.x;
  const float4* row = reinterpret_cast<const float4*>(pm + (size_t)n * KDIM);
  float ssp = 0.f, sp = 0.f;
  for (int i = threadIdx.x; i < KDIM / 4; i += 256) {
    float4 v = row[i];
    float xs[4] = {v.x, v.y, v.z, v.w};
#pragma unroll
    for (int j = 0; j < 4; ++j) {
      float x = xs[j];
      float e = __expf(-fabsf(x));
      float inv1pe = 1.f / (1.f + e);
      sp += (x >= 0.f) ? inv1pe : e * inv1pe;
      ssp += fmaxf(x, 0.f) + log1pf(e);
    }
  }
#pragma unroll
  for (int o = 32; o > 0; o >>= 1) {
    ssp += __shfl_down(ssp, o, 64);
    sp  += __shfl_down(sp, o, 64);
  }
  __shared__ float red[8];
  int wid = threadIdx.x >> 6;
  if ((threadIdx.x & 63) == 0) { red[wid] = ssp; red[4 + wid] = sp; }
  __syncthreads();
  if (threadIdx.x == 0) {
    S[n]    = -(red[0] + red[1] + red[2] + red[3]);
    sump[n] = red[4] + red[5] + red[6] + red[7];
  }
}

__device__ __forceinline__ bf16x8 load_frag_lin(const ushort* p) {
  union { ushort4 u[2]; bf16x8 f; } fr;
  fr.u[0] = *reinterpret_cast<const ushort4*>(p);
  fr.u[1] = *reinterpret_cast<const ushort4*>(p + 4);
  return fr.f;
}

__global__ __launch_bounds__(256) void gemm_fused(
    const float* __restrict__ pm, const ushort* __restrict__ T,
    ushort* __restrict__ part1, ushort* __restrict__ part2, int k_per) {
  __shared__ ushort Ax[64][40];
  __shared__ ushort Ap[64][40];
  __shared__ ushort Bs[64][40];
  int n0 = blockIdx.x * 64;
  int m0 = blockIdx.y * 64;
  int kz = blockIdx.z;
  int k_begin = kz * k_per;
  int t = threadIdx.x;
  int r = t >> 2;
  int q = t & 3;
  bool a_ok = (n0 + r) < N_PRED;
  bool b_ok = (m0 + r) < M_TGT;
  const float*  pA = pm + (size_t)(n0 + r) * KDIM + k_begin + q * 8;
  const ushort* pB = T  + (size_t)(m0 + r) * KDIM + k_begin + q * 8;
  int lane = t & 63;
  int w = t >> 6;
  int wr = (w >> 1) * 32;
  int wc = (w & 1) * 32;
  int lrow = lane & 15;
  int kc = (lane >> 4) * 8;
  f32x4 zero = {0.f, 0.f, 0.f, 0.f};
  f32x4 acc1[2][2] = {{zero, zero}, {zero, zero}};
  f32x4 acc2[2][2] = {{zero, zero}, {zero, zero}};
  int steps = k_per / 32;
  for (int kt = 0; kt < steps; ++kt) {
    __syncthreads();
    float4 f0 = {0.f,0.f,0.f,0.f}, f1 = {0.f,0.f,0.f,0.f};
    if (a_ok) {
      f0 = *reinterpret_cast<const float4*>(pA);
      f1 = *reinterpret_cast<const float4*>(pA + 4);
    }
    pA += 32;
    ushort4 xa, xb, pa, pb4;
    xa.x = f2bf(f0.x); xa.y = f2bf(f0.y); xa.z = f2bf(f0.z); xa.w = f2bf(f0.w);
    xb.x = f2bf(f1.x); xb.y = f2bf(f1.y); xb.z = f2bf(f1.z); xb.w = f2bf(f1.w);
    pa.x = f2bf(sigf(f0.x)); pa.y = f2bf(sigf(f0.y)); pa.z = f2bf(sigf(f0.z)); pa.w = f2bf(sigf(f0.w));
    pb4.x = f2bf(sigf(f1.x)); pb4.y = f2bf(sigf(f1.y)); pb4.z = f2bf(sigf(f1.z)); pb4.w = f2bf(sigf(f1.w));
    *reinterpret_cast<ushort4*>(&Ax[r][q * 8])     = xa;
    *reinterpret_cast<ushort4*>(&Ax[r][q * 8 + 4]) = xb;
    *reinterpret_cast<ushort4*>(&Ap[r][q * 8])     = pa;
    *reinterpret_cast<ushort4*>(&Ap[r][q * 8 + 4]) = pb4;
    union { uint4 u; ushort4 s[2]; } bv;
    bv.u = make_uint4(0, 0, 0, 0);
    if (b_ok) bv.u = *reinterpret_cast<const uint4*>(pB);
    pB += 32;
    *reinterpret_cast<ushort4*>(&Bs[r][q * 8])     = bv.s[0];
    *reinterpret_cast<ushort4*>(&Bs[r][q * 8 + 4]) = bv.s[1];
    __syncthreads();
    bf16x8 ax[2], ap[2], bb[2];
#pragma unroll
    for (int i = 0; i < 2; ++i) {
      ax[i] = load_frag_lin(&Ax[wr + i * 16 + lrow][kc]);
      ap[i] = load_frag_lin(&Ap[wr + i * 16 + lrow][kc]);
      bb[i] = load_frag_lin(&Bs[wc + i * 16 + lrow][kc]);
    }
#pragma unroll
    for (int i = 0; i < 2; ++i)
#pragma unroll
      for (int j = 0; j < 2; ++j) {
        acc1[i][j] = __builtin_amdgcn_mfma_f32_16x16x32_bf16(ax[i], bb[j], acc1[i][j], 0, 0, 0);
        acc2[i][j] = __builtin_amdgcn_mfma_f32_16x16x32_bf16(ap[i], bb[j], acc2[i][j], 0, 0, 0);
      }
  }
  int rowb = (lane >> 4) * 4;
  int col = lane & 15;
#pragma unroll
  for (int i = 0; i < 2; ++i)
#pragma unroll
    for (int j = 0; j < 2; ++j)
#pragma unroll
      for (int rr = 0; rr < 4; ++rr) {
        int gn = n0 + wr + i * 16 + rowb + rr;
        int gm = m0 + wc + j * 16 + col;
        if (gn < N_PRED && gm < M_TGT) {
          size_t o = (size_t)kz * 480000 + (size_t)gn * 400 + gm;
          part1[o] = f2bf(acc1[i][j][rr]);
          part2[o] = f2bf(acc2[i][j][rr]);
        }
      }
}

__global__ void combine_fb(const ushort* __restrict__ part1, const ushort* __restrict__ part2,
                           const float* __restrict__ S, const float* __restrict__ sump,
                           const float* __restrict__ tsum, const float* __restrict__ probs,
                           const float* __restrict__ pboxes, const float* __restrict__ tboxes,
                           const int* __restrict__ tids, float* __restrict__ out, int KZ) {
  int idx = blockIdx.x * 256 + threadIdx.x;
  int n = idx / M_TGT;
  int m = idx - n * M_TGT;
  float A1 = 0.f, A2 = 0.f;
  for (int kz = 0; kz < KZ; ++kz) {
    A1 += bf2f(part1[(size_t)kz * 480000 + idx]);
    A2 += bf2f(part2[(size_t)kz * 480000 + idx]);
  }
  float cm = -(A1 + S[n]) * (1.0f / (float)KDIM);
  float cd = 1.f - (2.f * A2 + 1e-5f) / (sump[n] + tsum[m] + 1e-5f);
  float cc = -probs[n * NCLS + tids[m]];
  float4 pb = reinterpret_cast<const float4*>(pboxes)[n];
  float4 tb = reinterpret_cast<const float4*>(tboxes)[m];
  float l1 = fabsf(pb.x - tb.x) + fabsf(pb.y - tb.y) + fabsf(pb.z - tb.z) + fabsf(pb.w - tb.w);
  float px1 = pb.x - 0.5f * pb.z, py1 = pb.y - 0.5f * pb.w;
  float px2 = pb.x + 0.5f * pb.z, py2 = pb.y + 0.5f * pb.w;
  float tx1 = tb.x - 0.5f * tb.z, ty1 = tb.y - 0.5f * tb.w;
  float tx2 = tb.x + 0.5f * tb.z, ty2 = tb.y + 0.5f * tb.w;
  float a1 = (px2 - px1) * (py2 - py1);
  float a2 = (tx2 - tx1) * (ty2 - ty1);
  float iw = fmaxf(fminf(px2, tx2) - fmaxf(px1, tx1), 0.f);
  float ih = fmaxf(fminf(py2, ty2) - fmaxf(py1, ty1), 0.f);
  float inter = iw * ih;
  float uni = a1 + a2 - inter;
  float iou = inter / uni;
  float ew = fmaxf(fmaxf(px2, tx2) - fminf(px1, tx1), 0.f);
  float eh = fmaxf(fmaxf(py2, ty2) - fminf(py1, ty1), 0.f);
  float ae = ew * eh;
  float giou = iou - (ae - uni) / ae;
  out[idx] = 5.f * l1 + 2.f * (-giou) + 2.f * cc + 5.f * cm + 5.f * cd;
}

// =====================================================================

extern "C" void kernel_launch(void* const* d_in, const int* in_sizes, int n_in,
                              void* d_out, int out_size, void* d_ws, size_t ws_size,
                              hipStream_t stream) {
  const float* logits = (const float*)d_in[0];
  const float* pboxes = (const float*)d_in[1];
  const float* pmasks = (const float*)d_in[2];
  const float* tboxes = (const float*)d_in[3];
  const float* tmasks = (const float*)d_in[4];
  const int*   tids   = (const int*)d_in[5];
  float* out = (float*)d_out;
  char* ws = (char*)d_ws;

  // new-path workspace layout
  const size_t offT     = 0;                         // 400*28672 = 11,468,800 (fp8)
  const size_t offPart  = 24371200;                  // 2*13*1200*448*2 = 27,955,200
  const size_t offProbs = offPart + 27955200;        // 388,800
  const size_t offStats = offProbs + 390400;         // SP 4800 | tsum 1600
  const size_t needNew  = offStats + 11200;

  if (ws_size >= needNew) {
    uchar* Tg    = (uchar*)(ws + offT);
    ushort* part = (ushort*)(ws + offPart);
    float* probs = (float*)(ws + offProbs);
    float* SP    = (float*)(ws + offStats);
    float* tsum  = (float*)(ws + offStats + 4800);

    hipMemsetAsync(SP, 0, 6400, stream);   // SP + tsum
    resize2<<<dim3(M_TGT, 20), 256, 0, stream>>>(tmasks, Tg, tsum);
    probs_kernel<<<N_PRED, 64, 0, stream>>>(logits, probs);
    gemm_mega<<<NBLK * KZN, 512, 0, stream>>>(pmasks, Tg, part, SP);
    combine2<<<1875, 256, 0, stream>>>(part, SP, tsum, probs,
                                       pboxes, tboxes, tids, out);
  } else {
    // fallback (R4 pipeline)
    ushort* T     = (ushort*)ws;
    float*  probs = (float*)(ws + 20480000);
    float*  S     = (float*)(ws + 20868800);
    float*  sump  = (float*)(ws + 20873600);
    float*  tsum  = (float*)(ws + 20878400);
    ushort* part1 = (ushort*)(ws + 20880000);
    size_t need8 = 20880000ull + 2ull * 8 * 480000 * 2;
    int KZf = (ws_size >= need8) ? 8 : 1;
    ushort* part2 = part1 + (size_t)KZf * 480000;

    hipMemsetAsync(tsum, 0, M_TGT * sizeof(float), stream);
    resize_lin<<<dim3(M_TGT, 100), 256, 0, stream>>>(tmasks, T, tsum);
    probs_kernel<<<N_PRED, 64, 0, stream>>>(logits, probs);
    stats_kernel<<<N_PRED, 256, 0, stream>>>(pmasks, S, sump);
    gemm_fused<<<dim3(19, 7, KZf), 256, 0, stream>>>(pmasks, T, part1, part2, KDIM / KZf);
    combine_fb<<<1875, 256, 0, stream>>>(part1, part2, S, sump, tsum, probs,
                                         pboxes, tboxes, tids, out, KZf);
  }
}